// Round 13
// baseline (1008.594 us; speedup 1.0000x reference)
//
#include <hip/hip_runtime.h>
#include <hip/hip_bf16.h>

// ---------------------------------------------------------------------------
// ExpandAndContractBottleneck.  R13: R12 with mconvU's global-atomic stats
// storm replaced by LDS reduction -> per-block partials -> redstats_k reduce.
// ---------------------------------------------------------------------------

#define DEV_INLINE __device__ __forceinline__

constexpr int NB   = 8;
constexpr int NC   = 128;
constexpr int NH   = 1024;
constexpr int LFULL= 8192;
constexpr int KSEL = 512;
constexpr int CAP  = 32768;

typedef __attribute__((ext_vector_type(4))) float f32x4;
typedef __attribute__((ext_vector_type(8))) short bf16x8;

DEV_INLINE unsigned monoKey(float f) {
    unsigned u = __float_as_uint(f);
    return (u & 0x80000000u) ? ~u : (u | 0x80000000u);
}
DEV_INLINE float keyToF(unsigned k) {
    unsigned u = (k & 0x80000000u) ? (k ^ 0x80000000u) : ~k;
    return __uint_as_float(u);
}
DEV_INLINE unsigned monoKey16(unsigned u) {
    return (u & 0x8000u) ? ((~u) & 0xFFFFu) : (u | 0x8000u);
}
DEV_INLINE unsigned bf16r(float f) {
    unsigned u = __float_as_uint(f);
    return (u + 0x7FFFu + ((u >> 16) & 1u)) >> 16;
}
DEV_INLINE float lrelu(float v) { return v >= 0.f ? v : 0.2f * v; }
DEV_INLINE float f4c(const float4& v, int k) {
    return k == 0 ? v.x : k == 1 ? v.y : k == 2 ? v.z : v.w;
}

DEV_INLINE void loadg4(const float* __restrict__ rowp, int g0, int L, float* e) {
    if (g0 >= 0 && g0 + 4 <= L) {
        float4 v = *(const float4*)(rowp + g0);
        e[0] = v.x; e[1] = v.y; e[2] = v.z; e[3] = v.w;
    } else {
#pragma unroll
        for (int t = 0; t < 4; t++) {
            int g = g0 + t;
            e[t] = (g >= 0 && g < L) ? rowp[g] : 0.f;
        }
    }
}

// ---------------------------------------------------------------------------
// prep_k: VALU dn weights [c][tap][128 oc].
// ---------------------------------------------------------------------------
__global__ __launch_bounds__(256) void prep_k(
    const float* __restrict__ up_w, const float* __restrict__ up_out_w,
    const float* __restrict__ dn_w, float* __restrict__ wprep)
{
    int idx = blockIdx.x * 256 + threadIdx.x;
    if (idx < 393216) {
        int layer = idx >> 16;
        int r0 = idx & 65535;
        int c = r0 >> 9, r = (r0 >> 7) & 3, o = r0 & 127;
        const float* wsrc = up_w + ((size_t)layer * 128 + o) * 384 + c * 3;
        float w0 = wsrc[0], w1 = wsrc[1], w2 = wsrc[2];
        wprep[idx] = (r == 0) ? w0 : (r == 1) ? (w1 + w2) : (r == 2) ? (w0 + w1) : w2;
    } else if (idx < 442368) {
        int r0 = idx - 393216;
        int c = r0 / 384, k = (r0 / 128) % 3, o = r0 & 127;
        wprep[idx] = up_out_w[((size_t)o * 128 + c) * 3 + k];
    } else {
        int r0 = idx - 442368;
        int layer = r0 / 114688;
        int r1 = r0 - layer * 114688;
        int c = r1 / 896, k = (r1 / 128) % 7, o = r1 & 127;
        wprep[idx] = dn_w[((size_t)layer * 128 + o) * 896 + c * 7 + k];
    }
}

// ---------------------------------------------------------------------------
// prepA_k: MFMA A-operand fragment records (unchanged from R12).
// ---------------------------------------------------------------------------
__global__ __launch_bounds__(256) void prepA_k(
    const float* __restrict__ up_w, const float* __restrict__ up_out_w,
    unsigned short* __restrict__ afrag)
{
    int idx = blockIdx.x * 256 + threadIdx.x;
    if (idx >= 221184) return;
    int rid = idx >> 6, lane = idx & 63;
    const int r15 = lane & 15, g = lane >> 4;
    unsigned short vals[8];
    if (rid < 3072) {
        int L  = rid >> 9;
        int r0 = rid & 511;
        int f = r0 & 3, ks = (r0 >> 2) & 1, cc = (r0 >> 3) & 1;
        int wo = (r0 >> 4) & 1, half = (r0 >> 5) & 1, ptap = (r0 >> 6) & 3;
        int o = wo * 64 + f * 16 + r15;
        int cb = cc * 64 + ks * 32 + g * 8;
#pragma unroll
        for (int e = 0; e < 8; e++) {
            const float* ws = up_w + (((size_t)L * 128 + o) * 128 + (cb + e)) * 3;
            float w0 = ws[0], w1 = ws[1], w2 = ws[2];
            float v = (ptap == 0) ? w0 : (ptap == 1) ? (w1 + w2)
                    : (ptap == 2) ? (w0 + w1) : w2;
            unsigned hi = bf16r(v);
            if (half == 0) vals[e] = (unsigned short)hi;
            else vals[e] = (unsigned short)bf16r(v - __uint_as_float(hi << 16));
        }
    } else {
        int r2 = rid - 3072;
        int f = r2 & 3, ks = (r2 >> 2) & 1, cc = (r2 >> 3) & 1;
        int wo = (r2 >> 4) & 1, half = (r2 >> 5) & 1, tap = r2 >> 6;
        int o = wo * 64 + f * 16 + r15;
        int cb = cc * 64 + ks * 32 + g * 8;
#pragma unroll
        for (int e = 0; e < 8; e++) {
            float v = up_out_w[((size_t)o * 128 + (cb + e)) * 3 + tap];
            unsigned hi = bf16r(v);
            if (half == 0) vals[e] = (unsigned short)hi;
            else vals[e] = (unsigned short)bf16r(v - __uint_as_float(hi << 16));
        }
    }
    unsigned pk[4];
#pragma unroll
    for (int q = 0; q < 4; q++)
        pk[q] = (unsigned)vals[2*q] | ((unsigned)vals[2*q+1] << 16);
    *(uint4*)(afrag + (size_t)rid * 512 + lane * 8) = make_uint4(pk[0], pk[1], pk[2], pk[3]);
}

// ---------------------------------------------------------------------------
// redstats_k: reduce per-block partials [nb][256] -> stats[256].
// ---------------------------------------------------------------------------
__global__ __launch_bounds__(256) void redstats_k(
    const float* __restrict__ partial, int nb, float* __restrict__ stats)
{
    int c = threadIdx.x;
    float s = 0.f;
    for (int i = 0; i < nb; i++) s += partial[(size_t)i * 256 + c];
    stats[c] = s;
}

// ---------------------------------------------------------------------------
// mconvU_k: UPS MFMA conv.  Stats: LDS-reduce -> partials (NO global atomics).
// ---------------------------------------------------------------------------
template<int INMODE>
__global__ __launch_bounds__(256) void mconvU_k(
    const float* __restrict__ in, float* __restrict__ out,
    const unsigned short* __restrict__ afrag, const float* __restrict__ bias,
    const float* __restrict__ stp, const float* __restrict__ gp,
    const float* __restrict__ btp, float inv_n,
    float* __restrict__ partial, int L_in)
{
    __shared__ unsigned short Xh[66 * 64], Xl[66 * 64];
    __shared__ float scs[NC], shs[NC];
    __shared__ float sstat[256];

    const int b = blockIdx.y, tile0 = blockIdx.x * 64, tid = threadIdx.x;
    const int lane = tid & 63, wid = tid >> 6;
    const int wo = wid >> 1, par = wid & 1;
    const int r15 = lane & 15, g = lane >> 4;
    const int bid = b * gridDim.x + blockIdx.x;

    if (tid < 256) sstat[tid] = 0.f;
    if (INMODE > 0) {
        for (int c = tid; c < NC; c += 256) {
            float m  = stp[c] * inv_n;
            float va = stp[NC + c] * inv_n - m * m;
            float sc = gp[c] * rsqrtf(va + 1e-5f);
            scs[c] = sc;
            shs[c] = btp[c] - m * sc;
        }
    }

    f32x4 acc[4][4];
#pragma unroll
    for (int i = 0; i < 4; i++)
#pragma unroll
        for (int j = 0; j < 4; j++) acc[i][j] = (f32x4)(0.f);

    for (int cc = 0; cc < 2; cc++) {
        __syncthreads();
        {
            int r = tid & 63;
            int l = tile0 - 1 + r;
            for (int c0 = (tid >> 6); c0 < 64; c0 += 4) {
                int c = cc * 64 + c0;
                float v = 0.f;
                if (l >= 0 && l < L_in) {
                    v = in[((size_t)b * NC + c) * L_in + l];
                    if (INMODE > 0) v = lrelu(v * scs[c] + shs[c]);
                }
                unsigned hi = bf16r(v);
                unsigned lo = bf16r(v - __uint_as_float(hi << 16));
                unsigned bo = ((unsigned)(r * 128 + c0 * 2)) ^ (((unsigned)(r & 7)) << 4);
                *(unsigned short*)((char*)Xh + bo) = (unsigned short)hi;
                *(unsigned short*)((char*)Xl + bo) = (unsigned short)lo;
            }
            if (tid < 128) {
                int r2 = 64 + (tid >> 6);
                int l2 = tile0 - 1 + r2;
                int c0 = tid & 63;
                int c = cc * 64 + c0;
                float v = 0.f;
                if (l2 >= 0 && l2 < L_in) {
                    v = in[((size_t)b * NC + c) * L_in + l2];
                    if (INMODE > 0) v = lrelu(v * scs[c] + shs[c]);
                }
                unsigned hi = bf16r(v);
                unsigned lo = bf16r(v - __uint_as_float(hi << 16));
                unsigned bo = ((unsigned)(r2 * 128 + c0 * 2)) ^ (((unsigned)(r2 & 7)) << 4);
                *(unsigned short*)((char*)Xh + bo) = (unsigned short)hi;
                *(unsigned short*)((char*)Xl + bo) = (unsigned short)lo;
            }
        }
        __syncthreads();
#pragma unroll
        for (int pt = 0; pt < 2; pt++) {
            const int ptap = par * 2 + pt;
            const int roff = (ptap == 0) ? 0 : (ptap == 3) ? 2 : 1;
#pragma unroll
            for (int combo = 0; combo < 3; combo++) {
                const int ah = (combo == 2) ? 1 : 0;
                const unsigned short* Xs = (combo == 1) ? Xl : Xh;
                bf16x8 af[8];
#pragma unroll
                for (int ks = 0; ks < 2; ks++)
#pragma unroll
                    for (int f = 0; f < 4; f++) {
                        int rec = ((((ptap * 2 + ah) * 2 + wo) * 2 + cc) * 2 + ks) * 4 + f;
                        af[ks * 4 + f] = *(const bf16x8*)(afrag + (size_t)rec * 512 + lane * 8);
                    }
#pragma unroll
                for (int ks = 0; ks < 2; ks++) {
                    bf16x8 bf_[4];
#pragma unroll
                    for (int j = 0; j < 4; j++) {
                        int row = j * 16 + r15 + roff;
                        unsigned bo = ((unsigned)(row * 128 + ks * 64 + g * 16))
                                    ^ (((unsigned)(row & 7)) << 4);
                        bf_[j] = *(const bf16x8*)((const char*)Xs + bo);
                    }
#pragma unroll
                    for (int i = 0; i < 4; i++)
#pragma unroll
                        for (int j = 0; j < 4; j++)
                            acc[i][j] = __builtin_amdgcn_mfma_f32_16x16x32_bf16(
                                af[ks * 4 + i], bf_[j], acc[i][j], 0, 0, 0);
                }
            }
        }
    }

    // epilogue: bias + store (interleaved) + LDS-reduced stats
    const int L_out = 2 * L_in;
#pragma unroll
    for (int i = 0; i < 4; i++) {
#pragma unroll
        for (int r = 0; r < 4; r++) {
            const int o = wo * 64 + i * 16 + g * 4 + r;
            const float bv = bias[o];
            float s1 = 0.f, s2 = 0.f;
#pragma unroll
            for (int j = 0; j < 4; j++) {
                float v = acc[i][j][r] + bv;
                int lout = 2 * (tile0 + j * 16 + r15) + par;
                out[((size_t)b * NC + o) * L_out + lout] = v;
                s1 += v; s2 += v * v;
            }
#pragma unroll
            for (int m = 1; m < 16; m <<= 1) {
                s1 += __shfl_xor(s1, m);
                s2 += __shfl_xor(s2, m);
            }
            if (r15 == 0) {
                atomicAdd(&sstat[o], s1);        // LDS atomic (cheap)
                atomicAdd(&sstat[NC + o], s2);
            }
        }
    }
    __syncthreads();
    if (tid < 256) partial[(size_t)bid * 256 + tid] = sstat[tid];
}

// ---------------------------------------------------------------------------
// mconvF_k: final k3 s1 conv as MFMA (unchanged from R12; no stats).
// ---------------------------------------------------------------------------
__global__ __launch_bounds__(256) void mconvF_k(
    const float* __restrict__ in, float* __restrict__ out,
    const unsigned short* __restrict__ afrag, const float* __restrict__ bias,
    const float* __restrict__ stp, const float* __restrict__ gp,
    const float* __restrict__ btp, float inv_n,
    unsigned short* __restrict__ xtout)
{
    __shared__ unsigned short Xh[130 * 64], Xl[130 * 64];
    __shared__ float scs[NC], shs[NC];

    const int b = blockIdx.y, l0 = blockIdx.x * 128, tid = threadIdx.x;
    const int lane = tid & 63, wid = tid >> 6;
    const int wo = wid >> 1, wl = (wid & 1) * 64;
    const int r15 = lane & 15, g = lane >> 4;

    for (int c = tid; c < NC; c += 256) {
        float m  = stp[c] * inv_n;
        float va = stp[NC + c] * inv_n - m * m;
        float sc = gp[c] * rsqrtf(va + 1e-5f);
        scs[c] = sc;
        shs[c] = btp[c] - m * sc;
    }

    f32x4 acc[4][4];
#pragma unroll
    for (int i = 0; i < 4; i++)
#pragma unroll
        for (int j = 0; j < 4; j++) acc[i][j] = (f32x4)(0.f);

    for (int cc = 0; cc < 2; cc++) {
        __syncthreads();
        {
#pragma unroll
            for (int p = 0; p < 2; p++) {
                int r = p * 64 + (tid & 63);
                int l = l0 - 1 + r;
                for (int c0 = (tid >> 6); c0 < 64; c0 += 4) {
                    int c = cc * 64 + c0;
                    float v = 0.f;
                    if (l >= 0 && l < LFULL) {
                        v = in[((size_t)b * NC + c) * LFULL + l];
                        v = lrelu(v * scs[c] + shs[c]);
                    }
                    unsigned hi = bf16r(v);
                    unsigned lo = bf16r(v - __uint_as_float(hi << 16));
                    unsigned bo = ((unsigned)(r * 128 + c0 * 2)) ^ (((unsigned)(r & 7)) << 4);
                    *(unsigned short*)((char*)Xh + bo) = (unsigned short)hi;
                    *(unsigned short*)((char*)Xl + bo) = (unsigned short)lo;
                }
            }
            if (tid < 128) {
                int r2 = 128 + (tid >> 6);
                int l2 = l0 - 1 + r2;
                int c0 = tid & 63;
                int c = cc * 64 + c0;
                float v = 0.f;
                if (l2 >= 0 && l2 < LFULL) {
                    v = in[((size_t)b * NC + c) * LFULL + l2];
                    v = lrelu(v * scs[c] + shs[c]);
                }
                unsigned hi = bf16r(v);
                unsigned lo = bf16r(v - __uint_as_float(hi << 16));
                unsigned bo = ((unsigned)(r2 * 128 + c0 * 2)) ^ (((unsigned)(r2 & 7)) << 4);
                *(unsigned short*)((char*)Xh + bo) = (unsigned short)hi;
                *(unsigned short*)((char*)Xl + bo) = (unsigned short)lo;
            }
        }
        __syncthreads();
#pragma unroll
        for (int tap = 0; tap < 3; tap++) {
#pragma unroll
            for (int combo = 0; combo < 3; combo++) {
                const int ah = (combo == 2) ? 1 : 0;
                const unsigned short* Xs = (combo == 1) ? Xl : Xh;
                bf16x8 af[8];
#pragma unroll
                for (int ks = 0; ks < 2; ks++)
#pragma unroll
                    for (int f = 0; f < 4; f++) {
                        int rec = 3072 + ((((tap * 2 + ah) * 2 + wo) * 2 + cc) * 2 + ks) * 4 + f;
                        af[ks * 4 + f] = *(const bf16x8*)(afrag + (size_t)rec * 512 + lane * 8);
                    }
#pragma unroll
                for (int ks = 0; ks < 2; ks++) {
                    bf16x8 bf_[4];
#pragma unroll
                    for (int j = 0; j < 4; j++) {
                        int row = wl + j * 16 + r15 + tap;
                        unsigned bo = ((unsigned)(row * 128 + ks * 64 + g * 16))
                                    ^ (((unsigned)(row & 7)) << 4);
                        bf_[j] = *(const bf16x8*)((const char*)Xs + bo);
                    }
#pragma unroll
                    for (int i = 0; i < 4; i++)
#pragma unroll
                        for (int j = 0; j < 4; j++)
                            acc[i][j] = __builtin_amdgcn_mfma_f32_16x16x32_bf16(
                                af[ks * 4 + i], bf_[j], acc[i][j], 0, 0, 0);
                }
            }
        }
    }

#pragma unroll
    for (int i = 0; i < 4; i++) {
#pragma unroll
        for (int r = 0; r < 4; r++) {
            const int o = wo * 64 + i * 16 + g * 4 + r;
            const float bv = bias[o];
#pragma unroll
            for (int j = 0; j < 4; j++) {
                float v = acc[i][j][r] + bv;
                int l = l0 + wl + j * 16 + r15;
                out[((size_t)b * NC + o) * LFULL + l] = v;
                xtout[((size_t)b * LFULL + l) * NC + o] = (unsigned short)bf16r(v);
            }
        }
    }
}

// ---------------------------------------------------------------------------
// conv7: VALU conv for the dn stack (unchanged from R12).
// ---------------------------------------------------------------------------
template<int KW, int STRIDE, int PAD, bool UPS, int INMODE, bool OUTACT, bool STATS, int TT, bool XPOSE>
__global__ __launch_bounds__(256) void conv7_k(
    const float* __restrict__ in, float* __restrict__ out,
    const float* __restrict__ wp, const float* __restrict__ bias,
    const float* __restrict__ stp, const float* __restrict__ gp,
    const float* __restrict__ btp, float inv_n,
    float* __restrict__ stats, unsigned short* __restrict__ xtout,
    int L_in, int L_out)
{
    constexpr int CC    = (KW == 7) ? 8 : 16;
    constexpr int PT    = 64 * TT;
    constexpr int TTO   = UPS ? 2 * TT : TT;
    constexpr int NWR   = UPS ? 4 : KW;
    constexpr int SPAN  = UPS ? (PT + 2) : ((PT - 1) * STRIDE + KW);
    constexpr int NCH   = (SPAN + 3) / 4;
    constexpr int XROW  = 4 * NCH + 4;
    constexpr int NLD   = (CC * NCH + 255) / 256;
    constexpr int XSPAN = UPS ? (TT + 2) : ((TT - 1) * STRIDE + KW);
    constexpr int STEP  = UPS ? TT : TT * STRIDE;
    constexpr int NWQ   = CC * NWR * 8;

    __shared__ float xs[CC][XROW];
    __shared__ float wls[CC * NWR * 32];
    __shared__ float scs[NC], shs[NC];

    const int b = blockIdx.z, ocb = blockIdx.y, tid = threadIdx.x;
    const int t0 = blockIdx.x * PT, lane = tid & 63;
    const int wid = tid >> 6;
    const int oc0 = ocb * 32 + wid * 8;
    const int gb = UPS ? (t0 - 1) : (t0 * STRIDE - PAD);

    if (INMODE > 0) {
        for (int c = tid; c < NC; c += 256) {
            float m  = stp[c] * inv_n;
            float va = stp[NC + c] * inv_n - m * m;
            float sc = gp[c] * rsqrtf(va + 1e-5f);
            scs[c] = sc;
            shs[c] = btp[c] - m * sc;
        }
        __syncthreads();
    }

    float acc[8][TTO];
#pragma unroll
    for (int i = 0; i < 8; i++)
#pragma unroll
        for (int j = 0; j < TTO; j++) acc[i][j] = 0.f;

    float pre[NLD][4];

#define C7_STAGEW(CCBASE) do {                                              \
    for (int _u = tid; _u < NWQ; _u += 256) {                               \
        int _row = _u >> 3, _g8 = _u & 7;                                   \
        int _cl = _row / NWR, _t = _row % NWR;                              \
        ((float4*)wls)[_u] = *(const float4*)(wp +                          \
            ((size_t)((CCBASE) + _cl) * NWR + _t) * 128 + ocb * 32 + _g8 * 4); \
    }                                                                       \
} while (0)

#define C7_COMPCI(CI) do {                                                  \
    float _q[XSPAN];                                                        \
    const int _qb = lane * STEP;                                            \
    if constexpr ((STEP & 3) == 0) {                                        \
        _Pragma("unroll")                                                   \
        for (int _u = 0; _u < XSPAN / 4; _u++) {                            \
            float4 _v = *(const float4*)&xs[CI][_qb + 4 * _u];              \
            _q[4*_u] = _v.x; _q[4*_u+1] = _v.y;                             \
            _q[4*_u+2] = _v.z; _q[4*_u+3] = _v.w;                           \
        }                                                                   \
        if constexpr ((XSPAN & 3) >= 2) {                                   \
            float2 _v = *(const float2*)&xs[CI][_qb + (XSPAN & ~3)];        \
            _q[(XSPAN & ~3)] = _v.x; _q[(XSPAN & ~3) + 1] = _v.y;           \
        }                                                                   \
        if constexpr (XSPAN & 1) _q[XSPAN - 1] = xs[CI][_qb + XSPAN - 1];   \
    } else if constexpr ((STEP & 1) == 0) {                                 \
        _Pragma("unroll")                                                   \
        for (int _u = 0; _u < XSPAN / 2; _u++) {                            \
            float2 _v = *(const float2*)&xs[CI][_qb + 2 * _u];              \
            _q[2*_u] = _v.x; _q[2*_u+1] = _v.y;                             \
        }                                                                   \
        if constexpr (XSPAN & 1) _q[XSPAN - 1] = xs[CI][_qb + XSPAN - 1];   \
    } else {                                                                \
        _Pragma("unroll")                                                   \
        for (int _u = 0; _u < XSPAN; _u++) _q[_u] = xs[CI][_qb + _u];       \
    }                                                                       \
    {                                                                       \
        _Pragma("unroll")                                                   \
        for (int _k = 0; _k < KW; _k++) {                                   \
            const float4 _w0 = *(const float4*)&wls[((CI) * NWR + _k) * 32 + wid * 8];     \
            const float4 _w1 = *(const float4*)&wls[((CI) * NWR + _k) * 32 + wid * 8 + 4]; \
            _Pragma("unroll")                                               \
            for (int _i = 0; _i < 8; _i++) {                                \
                float _wv = f4c(_i < 4 ? _w0 : _w1, _i & 3);                \
                _Pragma("unroll")                                           \
                for (int _j = 0; _j < TT; _j++)                             \
                    acc[_i][_j] = fmaf(_wv, _q[_j * STRIDE + _k], acc[_i][_j]); \
            }                                                               \
        }                                                                   \
    }                                                                       \
} while (0)

#pragma unroll
    for (int u = 0; u < NLD; u++) {
        int idx = tid + u * 256;
        if (idx < CC * NCH) {
            int cl = idx / NCH, q = idx - cl * NCH;
            loadg4(in + ((size_t)b * NC + cl) * L_in, gb + 4 * q, L_in, pre[u]);
        }
    }
#pragma unroll
    for (int u = 0; u < NLD; u++) {
        int idx = tid + u * 256;
        if (idx < CC * NCH) {
            int cl = idx / NCH, q = idx - cl * NCH;
            int g0 = gb + 4 * q;
            float e[4];
#pragma unroll
            for (int t = 0; t < 4; t++) {
                float v = pre[u][t];
                if (INMODE > 0) {
                    int gg = g0 + t;
                    if (gg >= 0 && gg < L_in) {
                        float s = v * scs[cl] + shs[cl];
                        v = (INMODE == 2) ? lrelu(s) : s;
                    }
                }
                e[t] = v;
            }
            *(float4*)&xs[cl][4 * q] = make_float4(e[0], e[1], e[2], e[3]);
        }
    }
    C7_STAGEW(0);
    __syncthreads();

    for (int cc = 0; cc < NC; cc += CC) {
        if (cc + CC < NC) {
#pragma unroll
            for (int u = 0; u < NLD; u++) {
                int idx = tid + u * 256;
                if (idx < CC * NCH) {
                    int cl = idx / NCH, q = idx - cl * NCH;
                    loadg4(in + ((size_t)b * NC + cc + CC + cl) * L_in,
                           gb + 4 * q, L_in, pre[u]);
                }
            }
        }
#pragma unroll
        for (int ci = 0; ci < CC; ci++) {
            C7_COMPCI(ci);
        }
        __syncthreads();
        if (cc + CC < NC) {
#pragma unroll
            for (int u = 0; u < NLD; u++) {
                int idx = tid + u * 256;
                if (idx < CC * NCH) {
                    int cl = idx / NCH, q = idx - cl * NCH;
                    int g0 = gb + 4 * q;
                    int c = cc + CC + cl;
                    float e[4];
#pragma unroll
                    for (int t = 0; t < 4; t++) {
                        float v = pre[u][t];
                        if (INMODE > 0) {
                            int gg = g0 + t;
                            if (gg >= 0 && gg < L_in) {
                                float s = v * scs[c] + shs[c];
                                v = (INMODE == 2) ? lrelu(s) : s;
                            }
                        }
                        e[t] = v;
                    }
                    *(float4*)&xs[cl][4 * q] = make_float4(e[0], e[1], e[2], e[3]);
                }
            }
            C7_STAGEW(cc + CC);
            __syncthreads();
        }
    }
#undef C7_STAGEW
#undef C7_COMPCI

    const int po = t0 + lane * TTO;
#pragma unroll
    for (int i = 0; i < 8; i++) {
        const int o = oc0 + i;
        const float bv = bias[o];
        float s1 = 0.f, s2 = 0.f;
        float tmpm[TTO];
#pragma unroll
        for (int j = 0; j < TTO; j++) {
            float v = acc[i][j] + bv;
            if (OUTACT) v = lrelu(v);
            tmpm[j] = v;
            if (STATS) { s1 += v; s2 += v * v; }
        }
        float* orow = out + ((size_t)b * NC + o) * L_out + po;
        if constexpr (TTO == 4)
            *(float4*)orow = make_float4(tmpm[0], tmpm[1], tmpm[2], tmpm[3]);
        else if constexpr (TTO == 2)
            *(float2*)orow = make_float2(tmpm[0], tmpm[1]);
        else
            orow[0] = tmpm[0];
        if (STATS) {
#pragma unroll
            for (int m = 1; m < 64; m <<= 1) {
                s1 += __shfl_xor(s1, m);
                s2 += __shfl_xor(s2, m);
            }
            if (lane == 0) {
                atomicAdd(&stats[o], s1);
                atomicAdd(&stats[NC + o], s2);
            }
        }
    }
}

// ---------------------------------------------------------------------------
__global__ __launch_bounds__(256) void cvtW_k(const float* __restrict__ W,
                                              unsigned short* __restrict__ Wbf)
{
    int i = blockIdx.x * 256 + threadIdx.x;
    const float4 a = *(const float4*)&W[i * 8];
    const float4 b = *(const float4*)&W[i * 8 + 4];
    unsigned pk[4];
    pk[0] = bf16r(a.x) | (bf16r(a.y) << 16);
    pk[1] = bf16r(a.z) | (bf16r(a.w) << 16);
    pk[2] = bf16r(b.x) | (bf16r(b.y) << 16);
    pk[3] = bf16r(b.z) | (bf16r(b.w) << 16);
    *(uint4*)&Wbf[i * 8] = make_uint4(pk[0], pk[1], pk[2], pk[3]);
}

// ---------------------------------------------------------------------------
// salM2: MFMA bf16 GEMM over (128h x 128l) tiles (unchanged).
// ---------------------------------------------------------------------------
template<int PHASE>
__global__ __launch_bounds__(256) void salM2_k(
    const unsigned short* __restrict__ xT, const unsigned short* __restrict__ Wbf,
    const float* __restrict__ bias, float* __restrict__ gsum,
    unsigned* __restrict__ ghist, const unsigned* __restrict__ thrv,
    unsigned* __restrict__ candcnt, unsigned* __restrict__ candI)
{
    __shared__ unsigned short Als[128 * 128];
    __shared__ unsigned short Bls[128 * 128];

    const int b  = blockIdx.z;
    const int h0 = blockIdx.y * 128;
    const int l0 = blockIdx.x * 128;
    const int tid = threadIdx.x;
    const int lane = tid & 63;
    const int wid = tid >> 6;
    const int wh = (wid >> 1) * 64;
    const int wl = (wid & 1) * 64;

    {
        const uint4* gA = (const uint4*)(Wbf + (size_t)h0 * NC);
        const uint4* gB = (const uint4*)(xT + ((size_t)b * LFULL + l0) * NC);
        char* cA = (char*)Als; char* cB = (char*)Bls;
        for (int i = tid; i < 2048; i += 256) {
            int row = i >> 4, q = i & 15;
            unsigned sw = (unsigned)(row * 256 + q * 16) ^ (((unsigned)(row & 7)) << 4);
            *(uint4*)(cA + sw) = gA[i];
        }
        for (int i = tid; i < 2048; i += 256) {
            int row = i >> 4, q = i & 15;
            unsigned sw = (unsigned)(row * 256 + q * 16) ^ (((unsigned)(row & 7)) << 4);
            *(uint4*)(cB + sw) = gB[i];
        }
    }
    __syncthreads();

    f32x4 acc[4][4];
#pragma unroll
    for (int i = 0; i < 4; i++)
#pragma unroll
        for (int j = 0; j < 4; j++) acc[i][j] = (f32x4)(0.f);

    const int r15 = lane & 15, g = lane >> 4;
#pragma unroll
    for (int ks = 0; ks < 4; ks++) {
        bf16x8 af[4], bfv[4];
#pragma unroll
        for (int f = 0; f < 4; f++) {
            int rowA = wh + f * 16 + r15;
            unsigned offA = (unsigned)(rowA * 256 + ks * 64 + g * 16)
                          ^ (((unsigned)(rowA & 7)) << 4);
            af[f] = *(const bf16x8*)((const char*)Als + offA);
            int rowB = wl + f * 16 + r15;
            unsigned offB = (unsigned)(rowB * 256 + ks * 64 + g * 16)
                          ^ (((unsigned)(rowB & 7)) << 4);
            bfv[f] = *(const bf16x8*)((const char*)Bls + offB);
        }
#pragma unroll
        for (int i = 0; i < 4; i++)
#pragma unroll
            for (int j = 0; j < 4; j++)
                acc[i][j] = __builtin_amdgcn_mfma_f32_16x16x32_bf16(
                    af[i], bfv[j], acc[i][j], 0, 0, 0);
    }

    if constexpr (PHASE == 0) {
        __syncthreads();
        unsigned* lhist = (unsigned*)Als;
        for (int i = tid; i < 8192; i += 256) lhist[i] = 0;
        __syncthreads();
        unsigned* myh = lhist + (tid & 1) * 4096;
        float expsum = 0.f;
#pragma unroll
        for (int i = 0; i < 4; i++) {
#pragma unroll
            for (int r = 0; r < 4; r++) {
                const int h = h0 + wh + i * 16 + g * 4 + r;
                const float bv = bias[h];
#pragma unroll
                for (int j = 0; j < 4; j++) {
                    float v = acc[i][j][r] + bv;
                    expsum += expf(v);
                    atomicAdd(&myh[monoKey16(bf16r(v)) >> 4], 1u);
                }
            }
        }
#pragma unroll
        for (int m = 1; m < 64; m <<= 1) expsum += __shfl_xor(expsum, m);
        float* red = (float*)Bls;
        if (lane == 0) red[wid] = expsum;
        __syncthreads();
        for (int i = tid; i < 4096; i += 256) {
            unsigned s = lhist[i] + lhist[4096 + i];
            if (s) atomicAdd(&ghist[b * 4096 + i], s);
        }
        if (tid == 0) atomicAdd(&gsum[b], red[0] + red[1] + red[2] + red[3]);
    } else {
        const unsigned thr = thrv[b * 2];
#pragma unroll
        for (int i = 0; i < 4; i++) {
#pragma unroll
            for (int r = 0; r < 4; r++) {
                const int h = h0 + wh + i * 16 + g * 4 + r;
                const float bv = bias[h];
#pragma unroll
                for (int j = 0; j < 4; j++) {
                    float v = acc[i][j][r] + bv;
                    bool pr = monoKey16(bf16r(v)) >= thr;
                    unsigned long long m = __ballot(pr);
                    if (m) {
                        int leader = __ffsll((unsigned long long)m) - 1;
                        int cnt = __popcll(m);
                        unsigned basepos = 0;
                        if (lane == leader)
                            basepos = atomicAdd(&candcnt[b], (unsigned)cnt);
                        basepos = __shfl(basepos, leader);
                        if (pr) {
                            int rr = __popcll(m & ((1ull << lane) - 1ull));
                            unsigned pos = basepos + (unsigned)rr;
                            if (pos < CAP) {
                                int l = l0 + wl + j * 16 + r15;
                                candI[b * CAP + pos] = (unsigned)((h << 13) | l);
                            }
                        }
                    }
                }
            }
        }
    }
}

// ---------------------------------------------------------------------------
__global__ __launch_bounds__(256) void scan2_k(
    const unsigned* __restrict__ ghist, unsigned* __restrict__ thrv)
{
    const int b = blockIdx.x, tid = threadIdx.x;
    __shared__ unsigned part[256];
    unsigned s = 0;
#pragma unroll
    for (int i = 0; i < 16; i++) s += ghist[b * 4096 + tid * 16 + i];
    part[tid] = s;
    __syncthreads();
    if (tid == 0) {
        unsigned cum = 0; int ch;
        for (ch = 255; ch >= 0; ch--) {
            if (cum + part[ch] >= KSEL) break;
            cum += part[ch];
        }
        int bin = 0;
        if (ch >= 0) {
            for (bin = ch * 16 + 15; bin > ch * 16; bin--) {
                unsigned c = ghist[b * 4096 + bin];
                if (cum + c >= KSEL) break;
                cum += c;
            }
        }
        int bcol = bin > 0 ? bin - 1 : 0;
        thrv[b * 2] = (unsigned)bcol << 4;
    }
}

__global__ __launch_bounds__(128) void recompute_k(
    const unsigned* __restrict__ candcnt, const unsigned* __restrict__ candI,
    const float* __restrict__ xu, const float* __restrict__ W,
    const float* __restrict__ bias, unsigned* __restrict__ candK)
{
    const int b = blockIdx.y;
    const unsigned cnt = min(candcnt[b], (unsigned)CAP);
    const int t = threadIdx.x;
    __shared__ float wsum[2];
    for (unsigned k = blockIdx.x; k < cnt; k += 1024) {
        unsigned e = candI[b * CAP + k];
        int h = e >> 13, l = e & 8191;
        float prod = W[h * NC + t] * xu[(b * NC + t) * LFULL + l];
#pragma unroll
        for (int m = 1; m < 64; m <<= 1) prod += __shfl_xor(prod, m);
        if ((t & 63) == 0) wsum[t >> 6] = prod;
        __syncthreads();
        if (t == 0) candK[b * CAP + k] = monoKey(wsum[0] + wsum[1] + bias[h]);
        __syncthreads();
    }
}

__global__ __launch_bounds__(256) void select2_k(
    const unsigned* __restrict__ candcnt, const unsigned* __restrict__ candK,
    const unsigned* __restrict__ candI,
    uint2* __restrict__ selected, unsigned* __restrict__ selcnt)
{
    const int b = blockIdx.x, tid = threadIdx.x;
    __shared__ unsigned h1[4096];
    __shared__ unsigned l2k[2048], l2i[2048];
    __shared__ unsigned part[256];
    __shared__ unsigned sh[8];

    const unsigned Nc = min(candcnt[b], (unsigned)CAP);
    const unsigned* kk = candK + b * CAP;
    const unsigned* ii = candI + b * CAP;
    uint2* sel = selected + b * KSEL;

    for (int i = tid; i < 4096; i += 256) h1[i] = 0;
    if (tid < 8) sh[tid] = 0;
    __syncthreads();
    for (unsigned i = tid; i < Nc; i += 256) atomicAdd(&h1[kk[i] >> 20], 1u);
    __syncthreads();
    {
        unsigned s = 0;
#pragma unroll
        for (int i = 0; i < 16; i++) s += h1[tid * 16 + i];
        part[tid] = s;
        __syncthreads();
        if (tid == 0) {
            unsigned cum = 0; int ch;
            for (ch = 255; ch >= 0; ch--) { if (cum + part[ch] >= KSEL) break; cum += part[ch]; }
            int bin = 0;
            if (ch >= 0)
                for (bin = ch * 16 + 15; bin > ch * 16; bin--) {
                    unsigned c = h1[bin];
                    if (cum + c >= KSEL) break;
                    cum += c;
                }
            sh[2] = (unsigned)bin; sh[3] = KSEL - cum;
        }
    }
    __syncthreads();
    const unsigned b1 = sh[2], need1 = sh[3];
    for (int i = tid; i < 1024; i += 256) h1[i] = 0;
    __syncthreads();
    for (unsigned i = tid; i < Nc; i += 256) {
        unsigned k = kk[i], bin = k >> 20;
        if (bin > b1) {
            unsigned p = atomicAdd(&sh[0], 1u);
            if (p < KSEL) sel[p] = make_uint2(k, ii[i]);
        } else if (bin == b1) {
            atomicAdd(&h1[(k >> 10) & 1023], 1u);
        }
    }
    __syncthreads();
    {
        unsigned s = 0;
#pragma unroll
        for (int i = 0; i < 4; i++) s += h1[tid * 4 + i];
        part[tid] = s;
        __syncthreads();
        if (tid == 0) {
            unsigned cum = 0; int ch;
            for (ch = 255; ch >= 0; ch--) { if (cum + part[ch] >= need1) break; cum += part[ch]; }
            int bin = 0;
            if (ch >= 0)
                for (bin = ch * 4 + 3; bin > ch * 4; bin--) {
                    unsigned c = h1[bin];
                    if (cum + c >= need1) break;
                    cum += c;
                }
            sh[4] = (unsigned)bin; sh[5] = need1 - cum;
        }
    }
    __syncthreads();
    const unsigned b2 = sh[4], need2 = sh[5];
    for (int i = tid; i < 1024; i += 256) h1[i] = 0;
    __syncthreads();
    for (unsigned i = tid; i < Nc; i += 256) {
        unsigned k = kk[i];
        if ((k >> 20) != b1) continue;
        unsigned mb = (k >> 10) & 1023;
        if (mb > b2) {
            unsigned p = atomicAdd(&sh[0], 1u);
            if (p < KSEL) sel[p] = make_uint2(k, ii[i]);
        } else if (mb == b2) {
            unsigned j = atomicAdd(&sh[1], 1u);
            if (j < 2048) { l2k[j] = k; l2i[j] = ii[i]; atomicAdd(&h1[k & 1023], 1u); }
        }
    }
    __syncthreads();
    const unsigned m2 = min(sh[1], 2048u);
    {
        unsigned s = 0;
#pragma unroll
        for (int i = 0; i < 4; i++) s += h1[tid * 4 + i];
        part[tid] = s;
        __syncthreads();
        if (tid == 0) {
            unsigned cum = 0; int ch;
            for (ch = 255; ch >= 0; ch--) { if (cum + part[ch] >= need2) break; cum += part[ch]; }
            int bin = 0;
            if (ch >= 0)
                for (bin = ch * 4 + 3; bin > ch * 4; bin--) {
                    unsigned c = h1[bin];
                    if (cum + c >= need2) break;
                    cum += c;
                }
            sh[6] = (unsigned)bin; sh[7] = need2 - cum;
        }
    }
    __syncthreads();
    const unsigned b3 = sh[6], need3 = sh[7];
    if (tid == 0) sh[1] = 0;
    __syncthreads();
    for (unsigned i = tid; i < m2; i += 256) {
        unsigned k = l2k[i], lb = k & 1023;
        if (lb > b3) {
            unsigned p = atomicAdd(&sh[0], 1u);
            if (p < KSEL) sel[p] = make_uint2(k, l2i[i]);
        } else if (lb == b3) {
            unsigned t = atomicAdd(&sh[1], 1u);
            if (t < need3) {
                unsigned p = atomicAdd(&sh[0], 1u);
                if (p < KSEL) sel[p] = make_uint2(k, l2i[i]);
            }
        }
    }
    __syncthreads();
    if (tid == 0) selcnt[b] = min(sh[0], (unsigned)KSEL);
}

// ---------------------------------------------------------------------------
__global__ void inity_k(float* __restrict__ y, const float* __restrict__ bias)
{
    int i = blockIdx.x * 256 + threadIdx.x;
    float bv = bias[(i >> 11) & 127];
    ((float4*)y)[i] = make_float4(bv, bv, bv, bv);
}

__global__ __launch_bounds__(128) void scatter_k(
    const uint2* __restrict__ selected, const unsigned* __restrict__ selcnt,
    const float* __restrict__ gsum, const float* __restrict__ xu,
    const float* __restrict__ upw, const float* __restrict__ upb,
    const float* __restrict__ dww, float* __restrict__ y)
{
    const int b = blockIdx.y, kidx = blockIdx.x;
    if (kidx >= (int)selcnt[b]) return;
    const uint2 s = selected[b * KSEL + kidx];
    const float salv = keyToF(s.x);
    const unsigned idx = s.y;
    const int h = idx >> 13, l = idx & 8191;
    const int t = threadIdx.x;

    float prod = upw[h * NC + t] * xu[(b * NC + t) * LFULL + l];
#pragma unroll
    for (int m = 1; m < 64; m <<= 1) prod += __shfl_xor(prod, m);
    __shared__ float wsum[2];
    if ((t & 63) == 0) wsum[t >> 6] = prod;
    __syncthreads();
    const float sig = wsum[0] + wsum[1] + upb[h];
    const float val = expf(salv) / gsum[b];
    const float g = sig * val;
    atomicAdd(&y[(b * NC + t) * LFULL + l], dww[t * NH + h] * g);
}

__global__ void apply_k(const float* __restrict__ in, const float* __restrict__ stats,
                        const float* __restrict__ g, const float* __restrict__ bt,
                        float* __restrict__ out, float inv_n)
{
    int i = blockIdx.x * 256 + threadIdx.x;
    int c = (i >> 7) & 127;
    float m  = stats[c] * inv_n;
    float va = stats[NC + c] * inv_n - m * m;
    float sc = g[c] * rsqrtf(va + 1e-5f);
    out[i] = in[i] * sc + (bt[c] - m * sc);
}

// ---------------------------------------------------------------------------
extern "C" void kernel_launch(void* const* d_in, const int* in_sizes, int n_in,
                              void* d_out, int out_size, void* d_ws, size_t ws_size,
                              hipStream_t stream)
{
    const float* x        = (const float*)d_in[0];
    const float* up_w     = (const float*)d_in[1];
    const float* up_b     = (const float*)d_in[2];
    const float* up_g     = (const float*)d_in[3];
    const float* up_beta  = (const float*)d_in[4];
    const float* up_out_w = (const float*)d_in[5];
    const float* up_out_b = (const float*)d_in[6];
    const float* sb_up_w  = (const float*)d_in[7];
    const float* sb_up_b  = (const float*)d_in[8];
    const float* sal_w    = (const float*)d_in[9];
    const float* sal_b    = (const float*)d_in[10];
    const float* sb_dn_w  = (const float*)d_in[11];
    const float* sb_dn_b  = (const float*)d_in[12];
    const float* dn_w     = (const float*)d_in[13];
    const float* dn_b     = (const float*)d_in[14];
    const float* dn_g     = (const float*)d_in[15];
    const float* dn_beta  = (const float*)d_in[16];

    char* ws = (char*)d_ws;
    float*          stats    = (float*)(ws + 0);
    float*          gsum     = (float*)(ws + 16384);
    unsigned*       thrv     = (unsigned*)(ws + 16416);
    unsigned*       candcnt  = (unsigned*)(ws + 16480);
    unsigned*       selcnt   = (unsigned*)(ws + 16512);
    uint2*          selected = (uint2*)(ws + 16640);
    unsigned*       ghist    = (unsigned*)(ws + 49408);
    unsigned*       candK    = (unsigned*)(ws + 180480);
    unsigned*       candI    = (unsigned*)(ws + 1229056);
    unsigned short* Wbf      = (unsigned short*)(ws + 2277632);
    float*          wprep    = (float*)(ws + 2539776);
    float*          B0       = (float*)(ws + 5685504);
    float*          B1       = (float*)(ws + 39239936);
    unsigned short* xT       = (unsigned short*)(ws + 72794368);
    float*          y        = (float*)(ws + 72794368);
    unsigned short* Afrag    = (unsigned short*)(ws + 117440512); // 3.54MB
    float*          partial  = (float*)(ws + 121634816);          // 512KB

    hipMemsetAsync(d_ws, 0, 16544, stream);
    hipMemsetAsync(ws + 49408, 0, 131072, stream);

    cvtW_k<<<64,256,0,stream>>>(sal_w, Wbf);
    prep_k<<<3072,256,0,stream>>>(up_w, up_out_w, dn_w, wprep);
    prepA_k<<<864,256,0,stream>>>(up_w, up_out_w, Afrag);

    // ---- ConvUpsample (MFMA): 128 -> 8192 frames ----
    mconvU_k<0><<<dim3(2,NB),256,0,stream>>>(
        x, B0, Afrag, up_b, nullptr, nullptr, nullptr, 0.f, partial, 128);
    redstats_k<<<1,256,0,stream>>>(partial, 2*NB, stats);
    mconvU_k<2><<<dim3(4,NB),256,0,stream>>>(
        B0, B1, Afrag + 1*262144, up_b + NC,
        stats, up_g, up_beta, 1.f/(float)(NB*256), partial, 256);
    redstats_k<<<1,256,0,stream>>>(partial, 4*NB, stats + 256);
    mconvU_k<2><<<dim3(8,NB),256,0,stream>>>(
        B1, B0, Afrag + 2*262144, up_b + 2*NC,
        stats + 256, up_g + NC, up_beta + NC, 1.f/(float)(NB*512), partial, 512);
    redstats_k<<<1,256,0,stream>>>(partial, 8*NB, stats + 2*256);
    mconvU_k<2><<<dim3(16,NB),256,0,stream>>>(
        B0, B1, Afrag + 3*262144, up_b + 3*NC,
        stats + 2*256, up_g + 2*NC, up_beta + 2*NC, 1.f/(float)(NB*1024), partial, 1024);
    redstats_k<<<1,256,0,stream>>>(partial, 16*NB, stats + 3*256);
    mconvU_k<2><<<dim3(32,NB),256,0,stream>>>(
        B1, B0, Afrag + 4*262144, up_b + 4*NC,
        stats + 3*256, up_g + 3*NC, up_beta + 3*NC, 1.f/(float)(NB*2048), partial, 2048);
    redstats_k<<<1,256,0,stream>>>(partial, 32*NB, stats + 4*256);
    mconvU_k<2><<<dim3(64,NB),256,0,stream>>>(
        B0, B1, Afrag + 5*262144, up_b + 5*NC,
        stats + 4*256, up_g + 4*NC, up_beta + 4*NC, 1.f/(float)(NB*4096), partial, 4096);
    redstats_k<<<1,256,0,stream>>>(partial, 64*NB, stats + 5*256);
    // final k3 conv (MFMA): B1 -> B0 (f32 x_up) + xT (bf16 transposed)
    mconvF_k<<<dim3(64,NB),256,0,stream>>>(
        B1, B0, Afrag, up_out_b,
        stats + 5*256, up_g + 5*NC, up_beta + 5*NC, 1.f/(float)(NB*LFULL), xT);

    // ---- SparseBottleneck ----
    salM2_k<0><<<dim3(64,8,NB),256,0,stream>>>(xT, Wbf, sal_b, gsum, ghist,
                                               nullptr, nullptr, nullptr);
    scan2_k<<<NB,256,0,stream>>>(ghist, thrv);
    salM2_k<1><<<dim3(64,8,NB),256,0,stream>>>(xT, Wbf, sal_b, nullptr, nullptr,
                                               thrv, candcnt, candI);
    recompute_k<<<dim3(1024,NB),128,0,stream>>>(candcnt, candI, B0, sal_w, sal_b, candK);
    select2_k<<<NB,256,0,stream>>>(candcnt, candK, candI, selected, selcnt);
    inity_k<<<(NB*NC*LFULL/4)/256,256,0,stream>>>(y, sb_dn_b);
    scatter_k<<<dim3(KSEL,NB),128,0,stream>>>(selected, selcnt, gsum, B0,
                                              sb_up_w, sb_up_b, sb_dn_w, y);

    // ---- down stack (VALU): 8192 -> 128 ----
    conv7_k<7,4,3,false,0,true,true,4,false><<<dim3(8,4,NB),256,0,stream>>>(
        y, B1, wprep + 442368, dn_b, nullptr, nullptr, nullptr, 0.f,
        stats + 6*256, nullptr, 8192, 2048);
    conv7_k<7,4,3,false,1,true,true,2,false><<<dim3(4,4,NB),256,0,stream>>>(
        B1, B0, wprep + 442368 + 114688, dn_b + NC,
        stats + 6*256, dn_g, dn_beta, 1.f/(float)(NB*2048),
        stats + 7*256, nullptr, 2048, 512);
    conv7_k<7,4,3,false,1,true,true,1,false><<<dim3(2,4,NB),256,0,stream>>>(
        B0, B1, wprep + 442368 + 2*114688, dn_b + 2*NC,
        stats + 7*256, dn_g + NC, dn_beta + NC, 1.f/(float)(NB*512),
        stats + 8*256, nullptr, 512, 128);

    apply_k<<<(out_size + 255)/256,256,0,stream>>>(
        B1, stats + 8*256, dn_g + 2*NC, dn_beta + 2*NC, (float*)d_out,
        1.f/(float)(NB*128));
}

// Round 14
// 1001.522 us; speedup vs baseline: 1.0071x; 1.0071x over previous
//
#include <hip/hip_runtime.h>
#include <hip/hip_bf16.h>

// ---------------------------------------------------------------------------
// ExpandAndContractBottleneck.  R14: mconvU/mconvF widened to 512-thread /
// 8-wave blocks (2x waves per CU) to hide the stage+afrag latency chains.
// ---------------------------------------------------------------------------

#define DEV_INLINE __device__ __forceinline__

constexpr int NB   = 8;
constexpr int NC   = 128;
constexpr int NH   = 1024;
constexpr int LFULL= 8192;
constexpr int KSEL = 512;
constexpr int CAP  = 32768;

typedef __attribute__((ext_vector_type(4))) float f32x4;
typedef __attribute__((ext_vector_type(8))) short bf16x8;

DEV_INLINE unsigned monoKey(float f) {
    unsigned u = __float_as_uint(f);
    return (u & 0x80000000u) ? ~u : (u | 0x80000000u);
}
DEV_INLINE float keyToF(unsigned k) {
    unsigned u = (k & 0x80000000u) ? (k ^ 0x80000000u) : ~k;
    return __uint_as_float(u);
}
DEV_INLINE unsigned monoKey16(unsigned u) {
    return (u & 0x8000u) ? ((~u) & 0xFFFFu) : (u | 0x8000u);
}
DEV_INLINE unsigned bf16r(float f) {
    unsigned u = __float_as_uint(f);
    return (u + 0x7FFFu + ((u >> 16) & 1u)) >> 16;
}
DEV_INLINE float lrelu(float v) { return v >= 0.f ? v : 0.2f * v; }
DEV_INLINE float f4c(const float4& v, int k) {
    return k == 0 ? v.x : k == 1 ? v.y : k == 2 ? v.z : v.w;
}

DEV_INLINE void loadg4(const float* __restrict__ rowp, int g0, int L, float* e) {
    if (g0 >= 0 && g0 + 4 <= L) {
        float4 v = *(const float4*)(rowp + g0);
        e[0] = v.x; e[1] = v.y; e[2] = v.z; e[3] = v.w;
    } else {
#pragma unroll
        for (int t = 0; t < 4; t++) {
            int g = g0 + t;
            e[t] = (g >= 0 && g < L) ? rowp[g] : 0.f;
        }
    }
}

// ---------------------------------------------------------------------------
// prep_k: VALU dn weights [c][tap][128 oc].
// ---------------------------------------------------------------------------
__global__ __launch_bounds__(256) void prep_k(
    const float* __restrict__ up_w, const float* __restrict__ up_out_w,
    const float* __restrict__ dn_w, float* __restrict__ wprep)
{
    int idx = blockIdx.x * 256 + threadIdx.x;
    if (idx < 393216) {
        int layer = idx >> 16;
        int r0 = idx & 65535;
        int c = r0 >> 9, r = (r0 >> 7) & 3, o = r0 & 127;
        const float* wsrc = up_w + ((size_t)layer * 128 + o) * 384 + c * 3;
        float w0 = wsrc[0], w1 = wsrc[1], w2 = wsrc[2];
        wprep[idx] = (r == 0) ? w0 : (r == 1) ? (w1 + w2) : (r == 2) ? (w0 + w1) : w2;
    } else if (idx < 442368) {
        int r0 = idx - 393216;
        int c = r0 / 384, k = (r0 / 128) % 3, o = r0 & 127;
        wprep[idx] = up_out_w[((size_t)o * 128 + c) * 3 + k];
    } else {
        int r0 = idx - 442368;
        int layer = r0 / 114688;
        int r1 = r0 - layer * 114688;
        int c = r1 / 896, k = (r1 / 128) % 7, o = r1 & 127;
        wprep[idx] = dn_w[((size_t)layer * 128 + o) * 896 + c * 7 + k];
    }
}

// ---------------------------------------------------------------------------
// prepA_k: MFMA A-operand fragment records (unchanged).
// ---------------------------------------------------------------------------
__global__ __launch_bounds__(256) void prepA_k(
    const float* __restrict__ up_w, const float* __restrict__ up_out_w,
    unsigned short* __restrict__ afrag)
{
    int idx = blockIdx.x * 256 + threadIdx.x;
    if (idx >= 221184) return;
    int rid = idx >> 6, lane = idx & 63;
    const int r15 = lane & 15, g = lane >> 4;
    unsigned short vals[8];
    if (rid < 3072) {
        int L  = rid >> 9;
        int r0 = rid & 511;
        int f = r0 & 3, ks = (r0 >> 2) & 1, cc = (r0 >> 3) & 1;
        int wo = (r0 >> 4) & 1, half = (r0 >> 5) & 1, ptap = (r0 >> 6) & 3;
        int o = wo * 64 + f * 16 + r15;
        int cb = cc * 64 + ks * 32 + g * 8;
#pragma unroll
        for (int e = 0; e < 8; e++) {
            const float* ws = up_w + (((size_t)L * 128 + o) * 128 + (cb + e)) * 3;
            float w0 = ws[0], w1 = ws[1], w2 = ws[2];
            float v = (ptap == 0) ? w0 : (ptap == 1) ? (w1 + w2)
                    : (ptap == 2) ? (w0 + w1) : w2;
            unsigned hi = bf16r(v);
            if (half == 0) vals[e] = (unsigned short)hi;
            else vals[e] = (unsigned short)bf16r(v - __uint_as_float(hi << 16));
        }
    } else {
        int r2 = rid - 3072;
        int f = r2 & 3, ks = (r2 >> 2) & 1, cc = (r2 >> 3) & 1;
        int wo = (r2 >> 4) & 1, half = (r2 >> 5) & 1, tap = r2 >> 6;
        int o = wo * 64 + f * 16 + r15;
        int cb = cc * 64 + ks * 32 + g * 8;
#pragma unroll
        for (int e = 0; e < 8; e++) {
            float v = up_out_w[((size_t)o * 128 + (cb + e)) * 3 + tap];
            unsigned hi = bf16r(v);
            if (half == 0) vals[e] = (unsigned short)hi;
            else vals[e] = (unsigned short)bf16r(v - __uint_as_float(hi << 16));
        }
    }
    unsigned pk[4];
#pragma unroll
    for (int q = 0; q < 4; q++)
        pk[q] = (unsigned)vals[2*q] | ((unsigned)vals[2*q+1] << 16);
    *(uint4*)(afrag + (size_t)rid * 512 + lane * 8) = make_uint4(pk[0], pk[1], pk[2], pk[3]);
}

// ---------------------------------------------------------------------------
// redstats_k: reduce per-block partials [nb][256] -> stats[256].
// ---------------------------------------------------------------------------
__global__ __launch_bounds__(256) void redstats_k(
    const float* __restrict__ partial, int nb, float* __restrict__ stats)
{
    int c = threadIdx.x;
    float s = 0.f;
    for (int i = 0; i < nb; i++) s += partial[(size_t)i * 256 + c];
    stats[c] = s;
}

// ---------------------------------------------------------------------------
// mconvU_k: UPS MFMA conv, 512 threads / 8 waves: (wo, par, jh).
// Per wave acc[4][2].  Stats via LDS -> partials.
// ---------------------------------------------------------------------------
template<int INMODE>
__global__ __launch_bounds__(512) void mconvU_k(
    const float* __restrict__ in, float* __restrict__ out,
    const unsigned short* __restrict__ afrag, const float* __restrict__ bias,
    const float* __restrict__ stp, const float* __restrict__ gp,
    const float* __restrict__ btp, float inv_n,
    float* __restrict__ partial, int L_in)
{
    __shared__ unsigned short Xh[66 * 64], Xl[66 * 64];
    __shared__ float scs[NC], shs[NC];
    __shared__ float sstat[256];

    const int b = blockIdx.y, tile0 = blockIdx.x * 64, tid = threadIdx.x;
    const int lane = tid & 63, wid = tid >> 6;
    const int wo = wid >> 2, par = (wid >> 1) & 1, jh = wid & 1;
    const int r15 = lane & 15, g = lane >> 4;
    const int bid = b * gridDim.x + blockIdx.x;

    if (tid < 256) sstat[tid] = 0.f;
    if (INMODE > 0) {
        for (int c = tid; c < NC; c += 512) {
            float m  = stp[c] * inv_n;
            float va = stp[NC + c] * inv_n - m * m;
            float sc = gp[c] * rsqrtf(va + 1e-5f);
            scs[c] = sc;
            shs[c] = btp[c] - m * sc;
        }
    }

    f32x4 acc[4][2];
#pragma unroll
    for (int i = 0; i < 4; i++)
#pragma unroll
        for (int j = 0; j < 2; j++) acc[i][j] = (f32x4)(0.f);

    for (int cc = 0; cc < 2; cc++) {
        __syncthreads();
        {
            int r = tid & 63;
            int l = tile0 - 1 + r;
            for (int c0 = (tid >> 6); c0 < 64; c0 += 8) {
                int c = cc * 64 + c0;
                float v = 0.f;
                if (l >= 0 && l < L_in) {
                    v = in[((size_t)b * NC + c) * L_in + l];
                    if (INMODE > 0) v = lrelu(v * scs[c] + shs[c]);
                }
                unsigned hi = bf16r(v);
                unsigned lo = bf16r(v - __uint_as_float(hi << 16));
                unsigned bo = ((unsigned)(r * 128 + c0 * 2)) ^ (((unsigned)(r & 7)) << 4);
                *(unsigned short*)((char*)Xh + bo) = (unsigned short)hi;
                *(unsigned short*)((char*)Xl + bo) = (unsigned short)lo;
            }
            if (tid < 128) {
                int r2 = 64 + (tid >> 6);
                int l2 = tile0 - 1 + r2;
                int c0 = tid & 63;
                int c = cc * 64 + c0;
                float v = 0.f;
                if (l2 >= 0 && l2 < L_in) {
                    v = in[((size_t)b * NC + c) * L_in + l2];
                    if (INMODE > 0) v = lrelu(v * scs[c] + shs[c]);
                }
                unsigned hi = bf16r(v);
                unsigned lo = bf16r(v - __uint_as_float(hi << 16));
                unsigned bo = ((unsigned)(r2 * 128 + c0 * 2)) ^ (((unsigned)(r2 & 7)) << 4);
                *(unsigned short*)((char*)Xh + bo) = (unsigned short)hi;
                *(unsigned short*)((char*)Xl + bo) = (unsigned short)lo;
            }
        }
        __syncthreads();
#pragma unroll
        for (int pt = 0; pt < 2; pt++) {
            const int ptap = par * 2 + pt;
            const int roff = (ptap == 0) ? 0 : (ptap == 3) ? 2 : 1;
#pragma unroll
            for (int combo = 0; combo < 3; combo++) {
                const int ah = (combo == 2) ? 1 : 0;
                const unsigned short* Xs = (combo == 1) ? Xl : Xh;
                bf16x8 af[8];
#pragma unroll
                for (int ks = 0; ks < 2; ks++)
#pragma unroll
                    for (int f = 0; f < 4; f++) {
                        int rec = ((((ptap * 2 + ah) * 2 + wo) * 2 + cc) * 2 + ks) * 4 + f;
                        af[ks * 4 + f] = *(const bf16x8*)(afrag + (size_t)rec * 512 + lane * 8);
                    }
#pragma unroll
                for (int ks = 0; ks < 2; ks++) {
                    bf16x8 bf_[2];
#pragma unroll
                    for (int j = 0; j < 2; j++) {
                        int row = (jh * 2 + j) * 16 + r15 + roff;
                        unsigned bo = ((unsigned)(row * 128 + ks * 64 + g * 16))
                                    ^ (((unsigned)(row & 7)) << 4);
                        bf_[j] = *(const bf16x8*)((const char*)Xs + bo);
                    }
#pragma unroll
                    for (int i = 0; i < 4; i++)
#pragma unroll
                        for (int j = 0; j < 2; j++)
                            acc[i][j] = __builtin_amdgcn_mfma_f32_16x16x32_bf16(
                                af[ks * 4 + i], bf_[j], acc[i][j], 0, 0, 0);
                }
            }
        }
    }

    // epilogue: bias + interleaved store + LDS-reduced stats
    const int L_out = 2 * L_in;
#pragma unroll
    for (int i = 0; i < 4; i++) {
#pragma unroll
        for (int r = 0; r < 4; r++) {
            const int o = wo * 64 + i * 16 + g * 4 + r;
            const float bv = bias[o];
            float s1 = 0.f, s2 = 0.f;
#pragma unroll
            for (int j = 0; j < 2; j++) {
                float v = acc[i][j][r] + bv;
                int lout = 2 * (tile0 + (jh * 2 + j) * 16 + r15) + par;
                out[((size_t)b * NC + o) * L_out + lout] = v;
                s1 += v; s2 += v * v;
            }
#pragma unroll
            for (int m = 1; m < 16; m <<= 1) {
                s1 += __shfl_xor(s1, m);
                s2 += __shfl_xor(s2, m);
            }
            if (r15 == 0) {
                atomicAdd(&sstat[o], s1);
                atomicAdd(&sstat[NC + o], s2);
            }
        }
    }
    __syncthreads();
    if (tid < 256) partial[(size_t)bid * 256 + tid] = sstat[tid];
}

// ---------------------------------------------------------------------------
// mconvF_k: final k3 conv as MFMA, 512 threads / 8 waves: (wo, wl in 4x32).
// ---------------------------------------------------------------------------
__global__ __launch_bounds__(512) void mconvF_k(
    const float* __restrict__ in, float* __restrict__ out,
    const unsigned short* __restrict__ afrag, const float* __restrict__ bias,
    const float* __restrict__ stp, const float* __restrict__ gp,
    const float* __restrict__ btp, float inv_n,
    unsigned short* __restrict__ xtout)
{
    __shared__ unsigned short Xh[130 * 64], Xl[130 * 64];
    __shared__ float scs[NC], shs[NC];

    const int b = blockIdx.y, l0 = blockIdx.x * 128, tid = threadIdx.x;
    const int lane = tid & 63, wid = tid >> 6;
    const int wo = wid >> 2, wl = (wid & 3) * 32;
    const int r15 = lane & 15, g = lane >> 4;

    for (int c = tid; c < NC; c += 512) {
        float m  = stp[c] * inv_n;
        float va = stp[NC + c] * inv_n - m * m;
        float sc = gp[c] * rsqrtf(va + 1e-5f);
        scs[c] = sc;
        shs[c] = btp[c] - m * sc;
    }

    f32x4 acc[4][2];
#pragma unroll
    for (int i = 0; i < 4; i++)
#pragma unroll
        for (int j = 0; j < 2; j++) acc[i][j] = (f32x4)(0.f);

    for (int cc = 0; cc < 2; cc++) {
        __syncthreads();
        {
            int r = tid & 127;
            int l = l0 - 1 + r;
            for (int c0 = (tid >> 7); c0 < 64; c0 += 4) {
                int c = cc * 64 + c0;
                float v = 0.f;
                if (l >= 0 && l < LFULL) {
                    v = in[((size_t)b * NC + c) * LFULL + l];
                    v = lrelu(v * scs[c] + shs[c]);
                }
                unsigned hi = bf16r(v);
                unsigned lo = bf16r(v - __uint_as_float(hi << 16));
                unsigned bo = ((unsigned)(r * 128 + c0 * 2)) ^ (((unsigned)(r & 7)) << 4);
                *(unsigned short*)((char*)Xh + bo) = (unsigned short)hi;
                *(unsigned short*)((char*)Xl + bo) = (unsigned short)lo;
            }
            if (tid < 128) {
                int r2 = 128 + (tid >> 6);
                int l2 = l0 - 1 + r2;
                int c0 = tid & 63;
                int c = cc * 64 + c0;
                float v = 0.f;
                if (l2 >= 0 && l2 < LFULL) {
                    v = in[((size_t)b * NC + c) * LFULL + l2];
                    v = lrelu(v * scs[c] + shs[c]);
                }
                unsigned hi = bf16r(v);
                unsigned lo = bf16r(v - __uint_as_float(hi << 16));
                unsigned bo = ((unsigned)(r2 * 128 + c0 * 2)) ^ (((unsigned)(r2 & 7)) << 4);
                *(unsigned short*)((char*)Xh + bo) = (unsigned short)hi;
                *(unsigned short*)((char*)Xl + bo) = (unsigned short)lo;
            }
        }
        __syncthreads();
#pragma unroll
        for (int tap = 0; tap < 3; tap++) {
#pragma unroll
            for (int combo = 0; combo < 3; combo++) {
                const int ah = (combo == 2) ? 1 : 0;
                const unsigned short* Xs = (combo == 1) ? Xl : Xh;
                bf16x8 af[8];
#pragma unroll
                for (int ks = 0; ks < 2; ks++)
#pragma unroll
                    for (int f = 0; f < 4; f++) {
                        int rec = 3072 + ((((tap * 2 + ah) * 2 + wo) * 2 + cc) * 2 + ks) * 4 + f;
                        af[ks * 4 + f] = *(const bf16x8*)(afrag + (size_t)rec * 512 + lane * 8);
                    }
#pragma unroll
                for (int ks = 0; ks < 2; ks++) {
                    bf16x8 bf_[2];
#pragma unroll
                    for (int j = 0; j < 2; j++) {
                        int row = wl + j * 16 + r15 + tap;
                        unsigned bo = ((unsigned)(row * 128 + ks * 64 + g * 16))
                                    ^ (((unsigned)(row & 7)) << 4);
                        bf_[j] = *(const bf16x8*)((const char*)Xs + bo);
                    }
#pragma unroll
                    for (int i = 0; i < 4; i++)
#pragma unroll
                        for (int j = 0; j < 2; j++)
                            acc[i][j] = __builtin_amdgcn_mfma_f32_16x16x32_bf16(
                                af[ks * 4 + i], bf_[j], acc[i][j], 0, 0, 0);
                }
            }
        }
    }

#pragma unroll
    for (int i = 0; i < 4; i++) {
#pragma unroll
        for (int r = 0; r < 4; r++) {
            const int o = wo * 64 + i * 16 + g * 4 + r;
            const float bv = bias[o];
#pragma unroll
            for (int j = 0; j < 2; j++) {
                float v = acc[i][j][r] + bv;
                int l = l0 + wl + j * 16 + r15;
                out[((size_t)b * NC + o) * LFULL + l] = v;
                xtout[((size_t)b * LFULL + l) * NC + o] = (unsigned short)bf16r(v);
            }
        }
    }
}

// ---------------------------------------------------------------------------
// conv7: VALU conv for the dn stack (unchanged).
// ---------------------------------------------------------------------------
template<int KW, int STRIDE, int PAD, bool UPS, int INMODE, bool OUTACT, bool STATS, int TT, bool XPOSE>
__global__ __launch_bounds__(256) void conv7_k(
    const float* __restrict__ in, float* __restrict__ out,
    const float* __restrict__ wp, const float* __restrict__ bias,
    const float* __restrict__ stp, const float* __restrict__ gp,
    const float* __restrict__ btp, float inv_n,
    float* __restrict__ stats, unsigned short* __restrict__ xtout,
    int L_in, int L_out)
{
    constexpr int CC    = (KW == 7) ? 8 : 16;
    constexpr int PT    = 64 * TT;
    constexpr int TTO   = UPS ? 2 * TT : TT;
    constexpr int NWR   = UPS ? 4 : KW;
    constexpr int SPAN  = UPS ? (PT + 2) : ((PT - 1) * STRIDE + KW);
    constexpr int NCH   = (SPAN + 3) / 4;
    constexpr int XROW  = 4 * NCH + 4;
    constexpr int NLD   = (CC * NCH + 255) / 256;
    constexpr int XSPAN = UPS ? (TT + 2) : ((TT - 1) * STRIDE + KW);
    constexpr int STEP  = UPS ? TT : TT * STRIDE;
    constexpr int NWQ   = CC * NWR * 8;

    __shared__ float xs[CC][XROW];
    __shared__ float wls[CC * NWR * 32];
    __shared__ float scs[NC], shs[NC];

    const int b = blockIdx.z, ocb = blockIdx.y, tid = threadIdx.x;
    const int t0 = blockIdx.x * PT, lane = tid & 63;
    const int wid = tid >> 6;
    const int oc0 = ocb * 32 + wid * 8;
    const int gb = UPS ? (t0 - 1) : (t0 * STRIDE - PAD);

    if (INMODE > 0) {
        for (int c = tid; c < NC; c += 256) {
            float m  = stp[c] * inv_n;
            float va = stp[NC + c] * inv_n - m * m;
            float sc = gp[c] * rsqrtf(va + 1e-5f);
            scs[c] = sc;
            shs[c] = btp[c] - m * sc;
        }
        __syncthreads();
    }

    float acc[8][TTO];
#pragma unroll
    for (int i = 0; i < 8; i++)
#pragma unroll
        for (int j = 0; j < TTO; j++) acc[i][j] = 0.f;

    float pre[NLD][4];

#define C7_STAGEW(CCBASE) do {                                              \
    for (int _u = tid; _u < NWQ; _u += 256) {                               \
        int _row = _u >> 3, _g8 = _u & 7;                                   \
        int _cl = _row / NWR, _t = _row % NWR;                              \
        ((float4*)wls)[_u] = *(const float4*)(wp +                          \
            ((size_t)((CCBASE) + _cl) * NWR + _t) * 128 + ocb * 32 + _g8 * 4); \
    }                                                                       \
} while (0)

#define C7_COMPCI(CI) do {                                                  \
    float _q[XSPAN];                                                        \
    const int _qb = lane * STEP;                                            \
    if constexpr ((STEP & 3) == 0) {                                        \
        _Pragma("unroll")                                                   \
        for (int _u = 0; _u < XSPAN / 4; _u++) {                            \
            float4 _v = *(const float4*)&xs[CI][_qb + 4 * _u];              \
            _q[4*_u] = _v.x; _q[4*_u+1] = _v.y;                             \
            _q[4*_u+2] = _v.z; _q[4*_u+3] = _v.w;                           \
        }                                                                   \
        if constexpr ((XSPAN & 3) >= 2) {                                   \
            float2 _v = *(const float2*)&xs[CI][_qb + (XSPAN & ~3)];        \
            _q[(XSPAN & ~3)] = _v.x; _q[(XSPAN & ~3) + 1] = _v.y;           \
        }                                                                   \
        if constexpr (XSPAN & 1) _q[XSPAN - 1] = xs[CI][_qb + XSPAN - 1];   \
    } else if constexpr ((STEP & 1) == 0) {                                 \
        _Pragma("unroll")                                                   \
        for (int _u = 0; _u < XSPAN / 2; _u++) {                            \
            float2 _v = *(const float2*)&xs[CI][_qb + 2 * _u];              \
            _q[2*_u] = _v.x; _q[2*_u+1] = _v.y;                             \
        }                                                                   \
        if constexpr (XSPAN & 1) _q[XSPAN - 1] = xs[CI][_qb + XSPAN - 1];   \
    } else {                                                                \
        _Pragma("unroll")                                                   \
        for (int _u = 0; _u < XSPAN; _u++) _q[_u] = xs[CI][_qb + _u];       \
    }                                                                       \
    {                                                                       \
        _Pragma("unroll")                                                   \
        for (int _k = 0; _k < KW; _k++) {                                   \
            const float4 _w0 = *(const float4*)&wls[((CI) * NWR + _k) * 32 + wid * 8];     \
            const float4 _w1 = *(const float4*)&wls[((CI) * NWR + _k) * 32 + wid * 8 + 4]; \
            _Pragma("unroll")                                               \
            for (int _i = 0; _i < 8; _i++) {                                \
                float _wv = f4c(_i < 4 ? _w0 : _w1, _i & 3);                \
                _Pragma("unroll")                                           \
                for (int _j = 0; _j < TT; _j++)                             \
                    acc[_i][_j] = fmaf(_wv, _q[_j * STRIDE + _k], acc[_i][_j]); \
            }                                                               \
        }                                                                   \
    }                                                                       \
} while (0)

#pragma unroll
    for (int u = 0; u < NLD; u++) {
        int idx = tid + u * 256;
        if (idx < CC * NCH) {
            int cl = idx / NCH, q = idx - cl * NCH;
            loadg4(in + ((size_t)b * NC + cl) * L_in, gb + 4 * q, L_in, pre[u]);
        }
    }
#pragma unroll
    for (int u = 0; u < NLD; u++) {
        int idx = tid + u * 256;
        if (idx < CC * NCH) {
            int cl = idx / NCH, q = idx - cl * NCH;
            int g0 = gb + 4 * q;
            float e[4];
#pragma unroll
            for (int t = 0; t < 4; t++) {
                float v = pre[u][t];
                if (INMODE > 0) {
                    int gg = g0 + t;
                    if (gg >= 0 && gg < L_in) {
                        float s = v * scs[cl] + shs[cl];
                        v = (INMODE == 2) ? lrelu(s) : s;
                    }
                }
                e[t] = v;
            }
            *(float4*)&xs[cl][4 * q] = make_float4(e[0], e[1], e[2], e[3]);
        }
    }
    C7_STAGEW(0);
    __syncthreads();

    for (int cc = 0; cc < NC; cc += CC) {
        if (cc + CC < NC) {
#pragma unroll
            for (int u = 0; u < NLD; u++) {
                int idx = tid + u * 256;
                if (idx < CC * NCH) {
                    int cl = idx / NCH, q = idx - cl * NCH;
                    loadg4(in + ((size_t)b * NC + cc + CC + cl) * L_in,
                           gb + 4 * q, L_in, pre[u]);
                }
            }
        }
#pragma unroll
        for (int ci = 0; ci < CC; ci++) {
            C7_COMPCI(ci);
        }
        __syncthreads();
        if (cc + CC < NC) {
#pragma unroll
            for (int u = 0; u < NLD; u++) {
                int idx = tid + u * 256;
                if (idx < CC * NCH) {
                    int cl = idx / NCH, q = idx - cl * NCH;
                    int g0 = gb + 4 * q;
                    int c = cc + CC + cl;
                    float e[4];
#pragma unroll
                    for (int t = 0; t < 4; t++) {
                        float v = pre[u][t];
                        if (INMODE > 0) {
                            int gg = g0 + t;
                            if (gg >= 0 && gg < L_in) {
                                float s = v * scs[c] + shs[c];
                                v = (INMODE == 2) ? lrelu(s) : s;
                            }
                        }
                        e[t] = v;
                    }
                    *(float4*)&xs[cl][4 * q] = make_float4(e[0], e[1], e[2], e[3]);
                }
            }
            C7_STAGEW(cc + CC);
            __syncthreads();
        }
    }
#undef C7_STAGEW
#undef C7_COMPCI

    const int po = t0 + lane * TTO;
#pragma unroll
    for (int i = 0; i < 8; i++) {
        const int o = oc0 + i;
        const float bv = bias[o];
        float s1 = 0.f, s2 = 0.f;
        float tmpm[TTO];
#pragma unroll
        for (int j = 0; j < TTO; j++) {
            float v = acc[i][j] + bv;
            if (OUTACT) v = lrelu(v);
            tmpm[j] = v;
            if (STATS) { s1 += v; s2 += v * v; }
        }
        float* orow = out + ((size_t)b * NC + o) * L_out + po;
        if constexpr (TTO == 4)
            *(float4*)orow = make_float4(tmpm[0], tmpm[1], tmpm[2], tmpm[3]);
        else if constexpr (TTO == 2)
            *(float2*)orow = make_float2(tmpm[0], tmpm[1]);
        else
            orow[0] = tmpm[0];
        if (STATS) {
#pragma unroll
            for (int m = 1; m < 64; m <<= 1) {
                s1 += __shfl_xor(s1, m);
                s2 += __shfl_xor(s2, m);
            }
            if (lane == 0) {
                atomicAdd(&stats[o], s1);
                atomicAdd(&stats[NC + o], s2);
            }
        }
    }
}

// ---------------------------------------------------------------------------
__global__ __launch_bounds__(256) void cvtW_k(const float* __restrict__ W,
                                              unsigned short* __restrict__ Wbf)
{
    int i = blockIdx.x * 256 + threadIdx.x;
    const float4 a = *(const float4*)&W[i * 8];
    const float4 b = *(const float4*)&W[i * 8 + 4];
    unsigned pk[4];
    pk[0] = bf16r(a.x) | (bf16r(a.y) << 16);
    pk[1] = bf16r(a.z) | (bf16r(a.w) << 16);
    pk[2] = bf16r(b.x) | (bf16r(b.y) << 16);
    pk[3] = bf16r(b.z) | (bf16r(b.w) << 16);
    *(uint4*)&Wbf[i * 8] = make_uint4(pk[0], pk[1], pk[2], pk[3]);
}

// ---------------------------------------------------------------------------
// salM2: MFMA bf16 GEMM over (128h x 128l) tiles (unchanged).
// ---------------------------------------------------------------------------
template<int PHASE>
__global__ __launch_bounds__(256) void salM2_k(
    const unsigned short* __restrict__ xT, const unsigned short* __restrict__ Wbf,
    const float* __restrict__ bias, float* __restrict__ gsum,
    unsigned* __restrict__ ghist, const unsigned* __restrict__ thrv,
    unsigned* __restrict__ candcnt, unsigned* __restrict__ candI)
{
    __shared__ unsigned short Als[128 * 128];
    __shared__ unsigned short Bls[128 * 128];

    const int b  = blockIdx.z;
    const int h0 = blockIdx.y * 128;
    const int l0 = blockIdx.x * 128;
    const int tid = threadIdx.x;
    const int lane = tid & 63;
    const int wid = tid >> 6;
    const int wh = (wid >> 1) * 64;
    const int wl = (wid & 1) * 64;

    {
        const uint4* gA = (const uint4*)(Wbf + (size_t)h0 * NC);
        const uint4* gB = (const uint4*)(xT + ((size_t)b * LFULL + l0) * NC);
        char* cA = (char*)Als; char* cB = (char*)Bls;
        for (int i = tid; i < 2048; i += 256) {
            int row = i >> 4, q = i & 15;
            unsigned sw = (unsigned)(row * 256 + q * 16) ^ (((unsigned)(row & 7)) << 4);
            *(uint4*)(cA + sw) = gA[i];
        }
        for (int i = tid; i < 2048; i += 256) {
            int row = i >> 4, q = i & 15;
            unsigned sw = (unsigned)(row * 256 + q * 16) ^ (((unsigned)(row & 7)) << 4);
            *(uint4*)(cB + sw) = gB[i];
        }
    }
    __syncthreads();

    f32x4 acc[4][4];
#pragma unroll
    for (int i = 0; i < 4; i++)
#pragma unroll
        for (int j = 0; j < 4; j++) acc[i][j] = (f32x4)(0.f);

    const int r15 = lane & 15, g = lane >> 4;
#pragma unroll
    for (int ks = 0; ks < 4; ks++) {
        bf16x8 af[4], bfv[4];
#pragma unroll
        for (int f = 0; f < 4; f++) {
            int rowA = wh + f * 16 + r15;
            unsigned offA = (unsigned)(rowA * 256 + ks * 64 + g * 16)
                          ^ (((unsigned)(rowA & 7)) << 4);
            af[f] = *(const bf16x8*)((const char*)Als + offA);
            int rowB = wl + f * 16 + r15;
            unsigned offB = (unsigned)(rowB * 256 + ks * 64 + g * 16)
                          ^ (((unsigned)(rowB & 7)) << 4);
            bfv[f] = *(const bf16x8*)((const char*)Bls + offB);
        }
#pragma unroll
        for (int i = 0; i < 4; i++)
#pragma unroll
            for (int j = 0; j < 4; j++)
                acc[i][j] = __builtin_amdgcn_mfma_f32_16x16x32_bf16(
                    af[i], bfv[j], acc[i][j], 0, 0, 0);
    }

    if constexpr (PHASE == 0) {
        __syncthreads();
        unsigned* lhist = (unsigned*)Als;
        for (int i = tid; i < 8192; i += 256) lhist[i] = 0;
        __syncthreads();
        unsigned* myh = lhist + (tid & 1) * 4096;
        float expsum = 0.f;
#pragma unroll
        for (int i = 0; i < 4; i++) {
#pragma unroll
            for (int r = 0; r < 4; r++) {
                const int h = h0 + wh + i * 16 + g * 4 + r;
                const float bv = bias[h];
#pragma unroll
                for (int j = 0; j < 4; j++) {
                    float v = acc[i][j][r] + bv;
                    expsum += expf(v);
                    atomicAdd(&myh[monoKey16(bf16r(v)) >> 4], 1u);
                }
            }
        }
#pragma unroll
        for (int m = 1; m < 64; m <<= 1) expsum += __shfl_xor(expsum, m);
        float* red = (float*)Bls;
        if (lane == 0) red[wid] = expsum;
        __syncthreads();
        for (int i = tid; i < 4096; i += 256) {
            unsigned s = lhist[i] + lhist[4096 + i];
            if (s) atomicAdd(&ghist[b * 4096 + i], s);
        }
        if (tid == 0) atomicAdd(&gsum[b], red[0] + red[1] + red[2] + red[3]);
    } else {
        const unsigned thr = thrv[b * 2];
#pragma unroll
        for (int i = 0; i < 4; i++) {
#pragma unroll
            for (int r = 0; r < 4; r++) {
                const int h = h0 + wh + i * 16 + g * 4 + r;
                const float bv = bias[h];
#pragma unroll
                for (int j = 0; j < 4; j++) {
                    float v = acc[i][j][r] + bv;
                    bool pr = monoKey16(bf16r(v)) >= thr;
                    unsigned long long m = __ballot(pr);
                    if (m) {
                        int leader = __ffsll((unsigned long long)m) - 1;
                        int cnt = __popcll(m);
                        unsigned basepos = 0;
                        if (lane == leader)
                            basepos = atomicAdd(&candcnt[b], (unsigned)cnt);
                        basepos = __shfl(basepos, leader);
                        if (pr) {
                            int rr = __popcll(m & ((1ull << lane) - 1ull));
                            unsigned pos = basepos + (unsigned)rr;
                            if (pos < CAP) {
                                int l = l0 + wl + j * 16 + r15;
                                candI[b * CAP + pos] = (unsigned)((h << 13) | l);
                            }
                        }
                    }
                }
            }
        }
    }
}

// ---------------------------------------------------------------------------
__global__ __launch_bounds__(256) void scan2_k(
    const unsigned* __restrict__ ghist, unsigned* __restrict__ thrv)
{
    const int b = blockIdx.x, tid = threadIdx.x;
    __shared__ unsigned part[256];
    unsigned s = 0;
#pragma unroll
    for (int i = 0; i < 16; i++) s += ghist[b * 4096 + tid * 16 + i];
    part[tid] = s;
    __syncthreads();
    if (tid == 0) {
        unsigned cum = 0; int ch;
        for (ch = 255; ch >= 0; ch--) {
            if (cum + part[ch] >= KSEL) break;
            cum += part[ch];
        }
        int bin = 0;
        if (ch >= 0) {
            for (bin = ch * 16 + 15; bin > ch * 16; bin--) {
                unsigned c = ghist[b * 4096 + bin];
                if (cum + c >= KSEL) break;
                cum += c;
            }
        }
        int bcol = bin > 0 ? bin - 1 : 0;
        thrv[b * 2] = (unsigned)bcol << 4;
    }
}

__global__ __launch_bounds__(128) void recompute_k(
    const unsigned* __restrict__ candcnt, const unsigned* __restrict__ candI,
    const float* __restrict__ xu, const float* __restrict__ W,
    const float* __restrict__ bias, unsigned* __restrict__ candK)
{
    const int b = blockIdx.y;
    const unsigned cnt = min(candcnt[b], (unsigned)CAP);
    const int t = threadIdx.x;
    __shared__ float wsum[2];
    for (unsigned k = blockIdx.x; k < cnt; k += 1024) {
        unsigned e = candI[b * CAP + k];
        int h = e >> 13, l = e & 8191;
        float prod = W[h * NC + t] * xu[(b * NC + t) * LFULL + l];
#pragma unroll
        for (int m = 1; m < 64; m <<= 1) prod += __shfl_xor(prod, m);
        if ((t & 63) == 0) wsum[t >> 6] = prod;
        __syncthreads();
        if (t == 0) candK[b * CAP + k] = monoKey(wsum[0] + wsum[1] + bias[h]);
        __syncthreads();
    }
}

__global__ __launch_bounds__(256) void select2_k(
    const unsigned* __restrict__ candcnt, const unsigned* __restrict__ candK,
    const unsigned* __restrict__ candI,
    uint2* __restrict__ selected, unsigned* __restrict__ selcnt)
{
    const int b = blockIdx.x, tid = threadIdx.x;
    __shared__ unsigned h1[4096];
    __shared__ unsigned l2k[2048], l2i[2048];
    __shared__ unsigned part[256];
    __shared__ unsigned sh[8];

    const unsigned Nc = min(candcnt[b], (unsigned)CAP);
    const unsigned* kk = candK + b * CAP;
    const unsigned* ii = candI + b * CAP;
    uint2* sel = selected + b * KSEL;

    for (int i = tid; i < 4096; i += 256) h1[i] = 0;
    if (tid < 8) sh[tid] = 0;
    __syncthreads();
    for (unsigned i = tid; i < Nc; i += 256) atomicAdd(&h1[kk[i] >> 20], 1u);
    __syncthreads();
    {
        unsigned s = 0;
#pragma unroll
        for (int i = 0; i < 16; i++) s += h1[tid * 16 + i];
        part[tid] = s;
        __syncthreads();
        if (tid == 0) {
            unsigned cum = 0; int ch;
            for (ch = 255; ch >= 0; ch--) { if (cum + part[ch] >= KSEL) break; cum += part[ch]; }
            int bin = 0;
            if (ch >= 0)
                for (bin = ch * 16 + 15; bin > ch * 16; bin--) {
                    unsigned c = h1[bin];
                    if (cum + c >= KSEL) break;
                    cum += c;
                }
            sh[2] = (unsigned)bin; sh[3] = KSEL - cum;
        }
    }
    __syncthreads();
    const unsigned b1 = sh[2], need1 = sh[3];
    for (int i = tid; i < 1024; i += 256) h1[i] = 0;
    __syncthreads();
    for (unsigned i = tid; i < Nc; i += 256) {
        unsigned k = kk[i], bin = k >> 20;
        if (bin > b1) {
            unsigned p = atomicAdd(&sh[0], 1u);
            if (p < KSEL) sel[p] = make_uint2(k, ii[i]);
        } else if (bin == b1) {
            atomicAdd(&h1[(k >> 10) & 1023], 1u);
        }
    }
    __syncthreads();
    {
        unsigned s = 0;
#pragma unroll
        for (int i = 0; i < 4; i++) s += h1[tid * 4 + i];
        part[tid] = s;
        __syncthreads();
        if (tid == 0) {
            unsigned cum = 0; int ch;
            for (ch = 255; ch >= 0; ch--) { if (cum + part[ch] >= need1) break; cum += part[ch]; }
            int bin = 0;
            if (ch >= 0)
                for (bin = ch * 4 + 3; bin > ch * 4; bin--) {
                    unsigned c = h1[bin];
                    if (cum + c >= need1) break;
                    cum += c;
                }
            sh[4] = (unsigned)bin; sh[5] = need1 - cum;
        }
    }
    __syncthreads();
    const unsigned b2 = sh[4], need2 = sh[5];
    for (int i = tid; i < 1024; i += 256) h1[i] = 0;
    __syncthreads();
    for (unsigned i = tid; i < Nc; i += 256) {
        unsigned k = kk[i];
        if ((k >> 20) != b1) continue;
        unsigned mb = (k >> 10) & 1023;
        if (mb > b2) {
            unsigned p = atomicAdd(&sh[0], 1u);
            if (p < KSEL) sel[p] = make_uint2(k, ii[i]);
        } else if (mb == b2) {
            unsigned j = atomicAdd(&sh[1], 1u);
            if (j < 2048) { l2k[j] = k; l2i[j] = ii[i]; atomicAdd(&h1[k & 1023], 1u); }
        }
    }
    __syncthreads();
    const unsigned m2 = min(sh[1], 2048u);
    {
        unsigned s = 0;
#pragma unroll
        for (int i = 0; i < 4; i++) s += h1[tid * 4 + i];
        part[tid] = s;
        __syncthreads();
        if (tid == 0) {
            unsigned cum = 0; int ch;
            for (ch = 255; ch >= 0; ch--) { if (cum + part[ch] >= need2) break; cum += part[ch]; }
            int bin = 0;
            if (ch >= 0)
                for (bin = ch * 4 + 3; bin > ch * 4; bin--) {
                    unsigned c = h1[bin];
                    if (cum + c >= need2) break;
                    cum += c;
                }
            sh[6] = (unsigned)bin; sh[7] = need2 - cum;
        }
    }
    __syncthreads();
    const unsigned b3 = sh[6], need3 = sh[7];
    if (tid == 0) sh[1] = 0;
    __syncthreads();
    for (unsigned i = tid; i < m2; i += 256) {
        unsigned k = l2k[i], lb = k & 1023;
        if (lb > b3) {
            unsigned p = atomicAdd(&sh[0], 1u);
            if (p < KSEL) sel[p] = make_uint2(k, l2i[i]);
        } else if (lb == b3) {
            unsigned t = atomicAdd(&sh[1], 1u);
            if (t < need3) {
                unsigned p = atomicAdd(&sh[0], 1u);
                if (p < KSEL) sel[p] = make_uint2(k, l2i[i]);
            }
        }
    }
    __syncthreads();
    if (tid == 0) selcnt[b] = min(sh[0], (unsigned)KSEL);
}

// ---------------------------------------------------------------------------
__global__ void inity_k(float* __restrict__ y, const float* __restrict__ bias)
{
    int i = blockIdx.x * 256 + threadIdx.x;
    float bv = bias[(i >> 11) & 127];
    ((float4*)y)[i] = make_float4(bv, bv, bv, bv);
}

__global__ __launch_bounds__(128) void scatter_k(
    const uint2* __restrict__ selected, const unsigned* __restrict__ selcnt,
    const float* __restrict__ gsum, const float* __restrict__ xu,
    const float* __restrict__ upw, const float* __restrict__ upb,
    const float* __restrict__ dww, float* __restrict__ y)
{
    const int b = blockIdx.y, kidx = blockIdx.x;
    if (kidx >= (int)selcnt[b]) return;
    const uint2 s = selected[b * KSEL + kidx];
    const float salv = keyToF(s.x);
    const unsigned idx = s.y;
    const int h = idx >> 13, l = idx & 8191;
    const int t = threadIdx.x;

    float prod = upw[h * NC + t] * xu[(b * NC + t) * LFULL + l];
#pragma unroll
    for (int m = 1; m < 64; m <<= 1) prod += __shfl_xor(prod, m);
    __shared__ float wsum[2];
    if ((t & 63) == 0) wsum[t >> 6] = prod;
    __syncthreads();
    const float sig = wsum[0] + wsum[1] + upb[h];
    const float val = expf(salv) / gsum[b];
    const float g = sig * val;
    atomicAdd(&y[(b * NC + t) * LFULL + l], dww[t * NH + h] * g);
}

__global__ void apply_k(const float* __restrict__ in, const float* __restrict__ stats,
                        const float* __restrict__ g, const float* __restrict__ bt,
                        float* __restrict__ out, float inv_n)
{
    int i = blockIdx.x * 256 + threadIdx.x;
    int c = (i >> 7) & 127;
    float m  = stats[c] * inv_n;
    float va = stats[NC + c] * inv_n - m * m;
    float sc = g[c] * rsqrtf(va + 1e-5f);
    out[i] = in[i] * sc + (bt[c] - m * sc);
}

// ---------------------------------------------------------------------------
extern "C" void kernel_launch(void* const* d_in, const int* in_sizes, int n_in,
                              void* d_out, int out_size, void* d_ws, size_t ws_size,
                              hipStream_t stream)
{
    const float* x        = (const float*)d_in[0];
    const float* up_w     = (const float*)d_in[1];
    const float* up_b     = (const float*)d_in[2];
    const float* up_g     = (const float*)d_in[3];
    const float* up_beta  = (const float*)d_in[4];
    const float* up_out_w = (const float*)d_in[5];
    const float* up_out_b = (const float*)d_in[6];
    const float* sb_up_w  = (const float*)d_in[7];
    const float* sb_up_b  = (const float*)d_in[8];
    const float* sal_w    = (const float*)d_in[9];
    const float* sal_b    = (const float*)d_in[10];
    const float* sb_dn_w  = (const float*)d_in[11];
    const float* sb_dn_b  = (const float*)d_in[12];
    const float* dn_w     = (const float*)d_in[13];
    const float* dn_b     = (const float*)d_in[14];
    const float* dn_g     = (const float*)d_in[15];
    const float* dn_beta  = (const float*)d_in[16];

    char* ws = (char*)d_ws;
    float*          stats    = (float*)(ws + 0);
    float*          gsum     = (float*)(ws + 16384);
    unsigned*       thrv     = (unsigned*)(ws + 16416);
    unsigned*       candcnt  = (unsigned*)(ws + 16480);
    unsigned*       selcnt   = (unsigned*)(ws + 16512);
    uint2*          selected = (uint2*)(ws + 16640);
    unsigned*       ghist    = (unsigned*)(ws + 49408);
    unsigned*       candK    = (unsigned*)(ws + 180480);
    unsigned*       candI    = (unsigned*)(ws + 1229056);
    unsigned short* Wbf      = (unsigned short*)(ws + 2277632);
    float*          wprep    = (float*)(ws + 2539776);
    float*          B0       = (float*)(ws + 5685504);
    float*          B1       = (float*)(ws + 39239936);
    unsigned short* xT       = (unsigned short*)(ws + 72794368);
    float*          y        = (float*)(ws + 72794368);
    unsigned short* Afrag    = (unsigned short*)(ws + 117440512); // 3.54MB
    float*          partial  = (float*)(ws + 121634816);          // 512KB

    hipMemsetAsync(d_ws, 0, 16544, stream);
    hipMemsetAsync(ws + 49408, 0, 131072, stream);

    cvtW_k<<<64,256,0,stream>>>(sal_w, Wbf);
    prep_k<<<3072,256,0,stream>>>(up_w, up_out_w, dn_w, wprep);
    prepA_k<<<864,256,0,stream>>>(up_w, up_out_w, Afrag);

    // ---- ConvUpsample (MFMA, 8-wave blocks): 128 -> 8192 frames ----
    mconvU_k<0><<<dim3(2,NB),512,0,stream>>>(
        x, B0, Afrag, up_b, nullptr, nullptr, nullptr, 0.f, partial, 128);
    redstats_k<<<1,256,0,stream>>>(partial, 2*NB, stats);
    mconvU_k<2><<<dim3(4,NB),512,0,stream>>>(
        B0, B1, Afrag + 1*262144, up_b + NC,
        stats, up_g, up_beta, 1.f/(float)(NB*256), partial, 256);
    redstats_k<<<1,256,0,stream>>>(partial, 4*NB, stats + 256);
    mconvU_k<2><<<dim3(8,NB),512,0,stream>>>(
        B1, B0, Afrag + 2*262144, up_b + 2*NC,
        stats + 256, up_g + NC, up_beta + NC, 1.f/(float)(NB*512), partial, 512);
    redstats_k<<<1,256,0,stream>>>(partial, 8*NB, stats + 2*256);
    mconvU_k<2><<<dim3(16,NB),512,0,stream>>>(
        B0, B1, Afrag + 3*262144, up_b + 3*NC,
        stats + 2*256, up_g + 2*NC, up_beta + 2*NC, 1.f/(float)(NB*1024), partial, 1024);
    redstats_k<<<1,256,0,stream>>>(partial, 16*NB, stats + 3*256);
    mconvU_k<2><<<dim3(32,NB),512,0,stream>>>(
        B1, B0, Afrag + 4*262144, up_b + 4*NC,
        stats + 3*256, up_g + 3*NC, up_beta + 3*NC, 1.f/(float)(NB*2048), partial, 2048);
    redstats_k<<<1,256,0,stream>>>(partial, 32*NB, stats + 4*256);
    mconvU_k<2><<<dim3(64,NB),512,0,stream>>>(
        B0, B1, Afrag + 5*262144, up_b + 5*NC,
        stats + 4*256, up_g + 4*NC, up_beta + 4*NC, 1.f/(float)(NB*4096), partial, 4096);
    redstats_k<<<1,256,0,stream>>>(partial, 64*NB, stats + 5*256);
    // final k3 conv (MFMA): B1 -> B0 (f32 x_up) + xT (bf16 transposed)
    mconvF_k<<<dim3(64,NB),512,0,stream>>>(
        B1, B0, Afrag, up_out_b,
        stats + 5*256, up_g + 5*NC, up_beta + 5*NC, 1.f/(float)(NB*LFULL), xT);

    // ---- SparseBottleneck ----
    salM2_k<0><<<dim3(64,8,NB),256,0,stream>>>(xT, Wbf, sal_b, gsum, ghist,
                                               nullptr, nullptr, nullptr);
    scan2_k<<<NB,256,0,stream>>>(ghist, thrv);
    salM2_k<1><<<dim3(64,8,NB),256,0,stream>>>(xT, Wbf, sal_b, nullptr, nullptr,
                                               thrv, candcnt, candI);
    recompute_k<<<dim3(1024,NB),128,0,stream>>>(candcnt, candI, B0, sal_w, sal_b, candK);
    select2_k<<<NB,256,0,stream>>>(candcnt, candK, candI, selected, selcnt);
    inity_k<<<(NB*NC*LFULL/4)/256,256,0,stream>>>(y, sb_dn_b);
    scatter_k<<<dim3(KSEL,NB),128,0,stream>>>(selected, selcnt, gsum, B0,
                                              sb_up_w, sb_up_b, sb_dn_w, y);

    // ---- down stack (VALU): 8192 -> 128 ----
    conv7_k<7,4,3,false,0,true,true,4,false><<<dim3(8,4,NB),256,0,stream>>>(
        y, B1, wprep + 442368, dn_b, nullptr, nullptr, nullptr, 0.f,
        stats + 6*256, nullptr, 8192, 2048);
    conv7_k<7,4,3,false,1,true,true,2,false><<<dim3(4,4,NB),256,0,stream>>>(
        B1, B0, wprep + 442368 + 114688, dn_b + NC,
        stats + 6*256, dn_g, dn_beta, 1.f/(float)(NB*2048),
        stats + 7*256, nullptr, 2048, 512);
    conv7_k<7,4,3,false,1,true,true,1,false><<<dim3(2,4,NB),256,0,stream>>>(
        B0, B1, wprep + 442368 + 2*114688, dn_b + 2*NC,
        stats + 7*256, dn_g + NC, dn_beta + NC, 1.f/(float)(NB*512),
        stats + 8*256, nullptr, 512, 128);

    apply_k<<<(out_size + 255)/256,256,0,stream>>>(
        B1, stats + 8*256, dn_g + 2*NC, dn_beta + 2*NC, (float*)d_out,
        1.f/(float)(NB*128));
}

// Round 15
// 960.260 us; speedup vs baseline: 1.0503x; 1.0430x over previous
//
#include <hip/hip_runtime.h>
#include <hip/hip_bf16.h>

// ---------------------------------------------------------------------------
// ExpandAndContractBottleneck.  R15: conv7 x-tile gets an address-XOR bank
// swizzle (kills the 3e7-cycle LDS conflicts at strided reads); dn0 at TT2
// for 2 blocks/CU.  Everything else unchanged from R14.
// ---------------------------------------------------------------------------

#define DEV_INLINE __device__ __forceinline__

constexpr int NB   = 8;
constexpr int NC   = 128;
constexpr int NH   = 1024;
constexpr int LFULL= 8192;
constexpr int KSEL = 512;
constexpr int CAP  = 32768;

typedef __attribute__((ext_vector_type(4))) float f32x4;
typedef __attribute__((ext_vector_type(8))) short bf16x8;

DEV_INLINE unsigned monoKey(float f) {
    unsigned u = __float_as_uint(f);
    return (u & 0x80000000u) ? ~u : (u | 0x80000000u);
}
DEV_INLINE float keyToF(unsigned k) {
    unsigned u = (k & 0x80000000u) ? (k ^ 0x80000000u) : ~k;
    return __uint_as_float(u);
}
DEV_INLINE unsigned monoKey16(unsigned u) {
    return (u & 0x8000u) ? ((~u) & 0xFFFFu) : (u | 0x8000u);
}
DEV_INLINE unsigned bf16r(float f) {
    unsigned u = __float_as_uint(f);
    return (u + 0x7FFFu + ((u >> 16) & 1u)) >> 16;
}
DEV_INLINE float lrelu(float v) { return v >= 0.f ? v : 0.2f * v; }
DEV_INLINE float f4c(const float4& v, int k) {
    return k == 0 ? v.x : k == 1 ? v.y : k == 2 ? v.z : v.w;
}
DEV_INLINE int swz4(int p) { return p ^ ((p >> 3) & 7); }   // f4-index swizzle

DEV_INLINE void loadg4(const float* __restrict__ rowp, int g0, int L, float* e) {
    if (g0 >= 0 && g0 + 4 <= L) {
        float4 v = *(const float4*)(rowp + g0);
        e[0] = v.x; e[1] = v.y; e[2] = v.z; e[3] = v.w;
    } else {
#pragma unroll
        for (int t = 0; t < 4; t++) {
            int g = g0 + t;
            e[t] = (g >= 0 && g < L) ? rowp[g] : 0.f;
        }
    }
}

// ---------------------------------------------------------------------------
// prep_k: VALU dn weights [c][tap][128 oc].
// ---------------------------------------------------------------------------
__global__ __launch_bounds__(256) void prep_k(
    const float* __restrict__ up_w, const float* __restrict__ up_out_w,
    const float* __restrict__ dn_w, float* __restrict__ wprep)
{
    int idx = blockIdx.x * 256 + threadIdx.x;
    if (idx < 393216) {
        int layer = idx >> 16;
        int r0 = idx & 65535;
        int c = r0 >> 9, r = (r0 >> 7) & 3, o = r0 & 127;
        const float* wsrc = up_w + ((size_t)layer * 128 + o) * 384 + c * 3;
        float w0 = wsrc[0], w1 = wsrc[1], w2 = wsrc[2];
        wprep[idx] = (r == 0) ? w0 : (r == 1) ? (w1 + w2) : (r == 2) ? (w0 + w1) : w2;
    } else if (idx < 442368) {
        int r0 = idx - 393216;
        int c = r0 / 384, k = (r0 / 128) % 3, o = r0 & 127;
        wprep[idx] = up_out_w[((size_t)o * 128 + c) * 3 + k];
    } else {
        int r0 = idx - 442368;
        int layer = r0 / 114688;
        int r1 = r0 - layer * 114688;
        int c = r1 / 896, k = (r1 / 128) % 7, o = r1 & 127;
        wprep[idx] = dn_w[((size_t)layer * 128 + o) * 896 + c * 7 + k];
    }
}

// ---------------------------------------------------------------------------
// prepA_k: MFMA A-operand fragment records (unchanged).
// ---------------------------------------------------------------------------
__global__ __launch_bounds__(256) void prepA_k(
    const float* __restrict__ up_w, const float* __restrict__ up_out_w,
    unsigned short* __restrict__ afrag)
{
    int idx = blockIdx.x * 256 + threadIdx.x;
    if (idx >= 221184) return;
    int rid = idx >> 6, lane = idx & 63;
    const int r15 = lane & 15, g = lane >> 4;
    unsigned short vals[8];
    if (rid < 3072) {
        int L  = rid >> 9;
        int r0 = rid & 511;
        int f = r0 & 3, ks = (r0 >> 2) & 1, cc = (r0 >> 3) & 1;
        int wo = (r0 >> 4) & 1, half = (r0 >> 5) & 1, ptap = (r0 >> 6) & 3;
        int o = wo * 64 + f * 16 + r15;
        int cb = cc * 64 + ks * 32 + g * 8;
#pragma unroll
        for (int e = 0; e < 8; e++) {
            const float* ws = up_w + (((size_t)L * 128 + o) * 128 + (cb + e)) * 3;
            float w0 = ws[0], w1 = ws[1], w2 = ws[2];
            float v = (ptap == 0) ? w0 : (ptap == 1) ? (w1 + w2)
                    : (ptap == 2) ? (w0 + w1) : w2;
            unsigned hi = bf16r(v);
            if (half == 0) vals[e] = (unsigned short)hi;
            else vals[e] = (unsigned short)bf16r(v - __uint_as_float(hi << 16));
        }
    } else {
        int r2 = rid - 3072;
        int f = r2 & 3, ks = (r2 >> 2) & 1, cc = (r2 >> 3) & 1;
        int wo = (r2 >> 4) & 1, half = (r2 >> 5) & 1, tap = r2 >> 6;
        int o = wo * 64 + f * 16 + r15;
        int cb = cc * 64 + ks * 32 + g * 8;
#pragma unroll
        for (int e = 0; e < 8; e++) {
            float v = up_out_w[((size_t)o * 128 + (cb + e)) * 3 + tap];
            unsigned hi = bf16r(v);
            if (half == 0) vals[e] = (unsigned short)hi;
            else vals[e] = (unsigned short)bf16r(v - __uint_as_float(hi << 16));
        }
    }
    unsigned pk[4];
#pragma unroll
    for (int q = 0; q < 4; q++)
        pk[q] = (unsigned)vals[2*q] | ((unsigned)vals[2*q+1] << 16);
    *(uint4*)(afrag + (size_t)rid * 512 + lane * 8) = make_uint4(pk[0], pk[1], pk[2], pk[3]);
}

// ---------------------------------------------------------------------------
// redstats_k: reduce per-block partials [nb][256] -> stats[256].
// ---------------------------------------------------------------------------
__global__ __launch_bounds__(256) void redstats_k(
    const float* __restrict__ partial, int nb, float* __restrict__ stats)
{
    int c = threadIdx.x;
    float s = 0.f;
    for (int i = 0; i < nb; i++) s += partial[(size_t)i * 256 + c];
    stats[c] = s;
}

// ---------------------------------------------------------------------------
// mconvU_k: UPS MFMA conv, 512 threads / 8 waves (unchanged from R14).
// ---------------------------------------------------------------------------
template<int INMODE>
__global__ __launch_bounds__(512) void mconvU_k(
    const float* __restrict__ in, float* __restrict__ out,
    const unsigned short* __restrict__ afrag, const float* __restrict__ bias,
    const float* __restrict__ stp, const float* __restrict__ gp,
    const float* __restrict__ btp, float inv_n,
    float* __restrict__ partial, int L_in)
{
    __shared__ unsigned short Xh[66 * 64], Xl[66 * 64];
    __shared__ float scs[NC], shs[NC];
    __shared__ float sstat[256];

    const int b = blockIdx.y, tile0 = blockIdx.x * 64, tid = threadIdx.x;
    const int lane = tid & 63, wid = tid >> 6;
    const int wo = wid >> 2, par = (wid >> 1) & 1, jh = wid & 1;
    const int r15 = lane & 15, g = lane >> 4;
    const int bid = b * gridDim.x + blockIdx.x;

    if (tid < 256) sstat[tid] = 0.f;
    if (INMODE > 0) {
        for (int c = tid; c < NC; c += 512) {
            float m  = stp[c] * inv_n;
            float va = stp[NC + c] * inv_n - m * m;
            float sc = gp[c] * rsqrtf(va + 1e-5f);
            scs[c] = sc;
            shs[c] = btp[c] - m * sc;
        }
    }

    f32x4 acc[4][2];
#pragma unroll
    for (int i = 0; i < 4; i++)
#pragma unroll
        for (int j = 0; j < 2; j++) acc[i][j] = (f32x4)(0.f);

    for (int cc = 0; cc < 2; cc++) {
        __syncthreads();
        {
            int r = tid & 63;
            int l = tile0 - 1 + r;
            for (int c0 = (tid >> 6); c0 < 64; c0 += 8) {
                int c = cc * 64 + c0;
                float v = 0.f;
                if (l >= 0 && l < L_in) {
                    v = in[((size_t)b * NC + c) * L_in + l];
                    if (INMODE > 0) v = lrelu(v * scs[c] + shs[c]);
                }
                unsigned hi = bf16r(v);
                unsigned lo = bf16r(v - __uint_as_float(hi << 16));
                unsigned bo = ((unsigned)(r * 128 + c0 * 2)) ^ (((unsigned)(r & 7)) << 4);
                *(unsigned short*)((char*)Xh + bo) = (unsigned short)hi;
                *(unsigned short*)((char*)Xl + bo) = (unsigned short)lo;
            }
            if (tid < 128) {
                int r2 = 64 + (tid >> 6);
                int l2 = tile0 - 1 + r2;
                int c0 = tid & 63;
                int c = cc * 64 + c0;
                float v = 0.f;
                if (l2 >= 0 && l2 < L_in) {
                    v = in[((size_t)b * NC + c) * L_in + l2];
                    if (INMODE > 0) v = lrelu(v * scs[c] + shs[c]);
                }
                unsigned hi = bf16r(v);
                unsigned lo = bf16r(v - __uint_as_float(hi << 16));
                unsigned bo = ((unsigned)(r2 * 128 + c0 * 2)) ^ (((unsigned)(r2 & 7)) << 4);
                *(unsigned short*)((char*)Xh + bo) = (unsigned short)hi;
                *(unsigned short*)((char*)Xl + bo) = (unsigned short)lo;
            }
        }
        __syncthreads();
#pragma unroll
        for (int pt = 0; pt < 2; pt++) {
            const int ptap = par * 2 + pt;
            const int roff = (ptap == 0) ? 0 : (ptap == 3) ? 2 : 1;
#pragma unroll
            for (int combo = 0; combo < 3; combo++) {
                const int ah = (combo == 2) ? 1 : 0;
                const unsigned short* Xs = (combo == 1) ? Xl : Xh;
                bf16x8 af[8];
#pragma unroll
                for (int ks = 0; ks < 2; ks++)
#pragma unroll
                    for (int f = 0; f < 4; f++) {
                        int rec = ((((ptap * 2 + ah) * 2 + wo) * 2 + cc) * 2 + ks) * 4 + f;
                        af[ks * 4 + f] = *(const bf16x8*)(afrag + (size_t)rec * 512 + lane * 8);
                    }
#pragma unroll
                for (int ks = 0; ks < 2; ks++) {
                    bf16x8 bf_[2];
#pragma unroll
                    for (int j = 0; j < 2; j++) {
                        int row = (jh * 2 + j) * 16 + r15 + roff;
                        unsigned bo = ((unsigned)(row * 128 + ks * 64 + g * 16))
                                    ^ (((unsigned)(row & 7)) << 4);
                        bf_[j] = *(const bf16x8*)((const char*)Xs + bo);
                    }
#pragma unroll
                    for (int i = 0; i < 4; i++)
#pragma unroll
                        for (int j = 0; j < 2; j++)
                            acc[i][j] = __builtin_amdgcn_mfma_f32_16x16x32_bf16(
                                af[ks * 4 + i], bf_[j], acc[i][j], 0, 0, 0);
                }
            }
        }
    }

    const int L_out = 2 * L_in;
#pragma unroll
    for (int i = 0; i < 4; i++) {
#pragma unroll
        for (int r = 0; r < 4; r++) {
            const int o = wo * 64 + i * 16 + g * 4 + r;
            const float bv = bias[o];
            float s1 = 0.f, s2 = 0.f;
#pragma unroll
            for (int j = 0; j < 2; j++) {
                float v = acc[i][j][r] + bv;
                int lout = 2 * (tile0 + (jh * 2 + j) * 16 + r15) + par;
                out[((size_t)b * NC + o) * L_out + lout] = v;
                s1 += v; s2 += v * v;
            }
#pragma unroll
            for (int m = 1; m < 16; m <<= 1) {
                s1 += __shfl_xor(s1, m);
                s2 += __shfl_xor(s2, m);
            }
            if (r15 == 0) {
                atomicAdd(&sstat[o], s1);
                atomicAdd(&sstat[NC + o], s2);
            }
        }
    }
    __syncthreads();
    if (tid < 256) partial[(size_t)bid * 256 + tid] = sstat[tid];
}

// ---------------------------------------------------------------------------
// mconvF_k: final k3 conv as MFMA, 512 threads / 8 waves (unchanged).
// ---------------------------------------------------------------------------
__global__ __launch_bounds__(512) void mconvF_k(
    const float* __restrict__ in, float* __restrict__ out,
    const unsigned short* __restrict__ afrag, const float* __restrict__ bias,
    const float* __restrict__ stp, const float* __restrict__ gp,
    const float* __restrict__ btp, float inv_n,
    unsigned short* __restrict__ xtout)
{
    __shared__ unsigned short Xh[130 * 64], Xl[130 * 64];
    __shared__ float scs[NC], shs[NC];

    const int b = blockIdx.y, l0 = blockIdx.x * 128, tid = threadIdx.x;
    const int lane = tid & 63, wid = tid >> 6;
    const int wo = wid >> 2, wl = (wid & 3) * 32;
    const int r15 = lane & 15, g = lane >> 4;

    for (int c = tid; c < NC; c += 512) {
        float m  = stp[c] * inv_n;
        float va = stp[NC + c] * inv_n - m * m;
        float sc = gp[c] * rsqrtf(va + 1e-5f);
        scs[c] = sc;
        shs[c] = btp[c] - m * sc;
    }

    f32x4 acc[4][2];
#pragma unroll
    for (int i = 0; i < 4; i++)
#pragma unroll
        for (int j = 0; j < 2; j++) acc[i][j] = (f32x4)(0.f);

    for (int cc = 0; cc < 2; cc++) {
        __syncthreads();
        {
            int r = tid & 127;
            int l = l0 - 1 + r;
            for (int c0 = (tid >> 7); c0 < 64; c0 += 4) {
                int c = cc * 64 + c0;
                float v = 0.f;
                if (l >= 0 && l < LFULL) {
                    v = in[((size_t)b * NC + c) * LFULL + l];
                    v = lrelu(v * scs[c] + shs[c]);
                }
                unsigned hi = bf16r(v);
                unsigned lo = bf16r(v - __uint_as_float(hi << 16));
                unsigned bo = ((unsigned)(r * 128 + c0 * 2)) ^ (((unsigned)(r & 7)) << 4);
                *(unsigned short*)((char*)Xh + bo) = (unsigned short)hi;
                *(unsigned short*)((char*)Xl + bo) = (unsigned short)lo;
            }
            if (tid < 128) {
                int r2 = 128 + (tid >> 6);
                int l2 = l0 - 1 + r2;
                int c0 = tid & 63;
                int c = cc * 64 + c0;
                float v = 0.f;
                if (l2 >= 0 && l2 < LFULL) {
                    v = in[((size_t)b * NC + c) * LFULL + l2];
                    v = lrelu(v * scs[c] + shs[c]);
                }
                unsigned hi = bf16r(v);
                unsigned lo = bf16r(v - __uint_as_float(hi << 16));
                unsigned bo = ((unsigned)(r2 * 128 + c0 * 2)) ^ (((unsigned)(r2 & 7)) << 4);
                *(unsigned short*)((char*)Xh + bo) = (unsigned short)hi;
                *(unsigned short*)((char*)Xl + bo) = (unsigned short)lo;
            }
        }
        __syncthreads();
#pragma unroll
        for (int tap = 0; tap < 3; tap++) {
#pragma unroll
            for (int combo = 0; combo < 3; combo++) {
                const int ah = (combo == 2) ? 1 : 0;
                const unsigned short* Xs = (combo == 1) ? Xl : Xh;
                bf16x8 af[8];
#pragma unroll
                for (int ks = 0; ks < 2; ks++)
#pragma unroll
                    for (int f = 0; f < 4; f++) {
                        int rec = 3072 + ((((tap * 2 + ah) * 2 + wo) * 2 + cc) * 2 + ks) * 4 + f;
                        af[ks * 4 + f] = *(const bf16x8*)(afrag + (size_t)rec * 512 + lane * 8);
                    }
#pragma unroll
                for (int ks = 0; ks < 2; ks++) {
                    bf16x8 bf_[2];
#pragma unroll
                    for (int j = 0; j < 2; j++) {
                        int row = wl + j * 16 + r15 + tap;
                        unsigned bo = ((unsigned)(row * 128 + ks * 64 + g * 16))
                                    ^ (((unsigned)(row & 7)) << 4);
                        bf_[j] = *(const bf16x8*)((const char*)Xs + bo);
                    }
#pragma unroll
                    for (int i = 0; i < 4; i++)
#pragma unroll
                        for (int j = 0; j < 2; j++)
                            acc[i][j] = __builtin_amdgcn_mfma_f32_16x16x32_bf16(
                                af[ks * 4 + i], bf_[j], acc[i][j], 0, 0, 0);
                }
            }
        }
    }

#pragma unroll
    for (int i = 0; i < 4; i++) {
#pragma unroll
        for (int r = 0; r < 4; r++) {
            const int o = wo * 64 + i * 16 + g * 4 + r;
            const float bv = bias[o];
#pragma unroll
            for (int j = 0; j < 2; j++) {
                float v = acc[i][j][r] + bv;
                int l = l0 + wl + j * 16 + r15;
                out[((size_t)b * NC + o) * LFULL + l] = v;
                xtout[((size_t)b * LFULL + l) * NC + o] = (unsigned short)bf16r(v);
            }
        }
    }
}

// ---------------------------------------------------------------------------
// conv7: VALU conv for the dn stack, with address-XOR swizzled x tile.
// ---------------------------------------------------------------------------
template<int KW, int STRIDE, int PAD, bool UPS, int INMODE, bool OUTACT, bool STATS, int TT, bool XPOSE>
__global__ __launch_bounds__(256) void conv7_k(
    const float* __restrict__ in, float* __restrict__ out,
    const float* __restrict__ wp, const float* __restrict__ bias,
    const float* __restrict__ stp, const float* __restrict__ gp,
    const float* __restrict__ btp, float inv_n,
    float* __restrict__ stats, unsigned short* __restrict__ xtout,
    int L_in, int L_out)
{
    constexpr int CC    = (KW == 7) ? 8 : 16;
    constexpr int PT    = 64 * TT;
    constexpr int TTO   = UPS ? 2 * TT : TT;
    constexpr int NWR   = UPS ? 4 : KW;
    constexpr int SPAN  = UPS ? (PT + 2) : ((PT - 1) * STRIDE + KW);
    constexpr int NCH   = (SPAN + 3) / 4;
    constexpr int NCH8  = (NCH + 7) & ~7;       // swizzle group padding
    constexpr int XROW  = 4 * NCH8 + 4;
    constexpr int NLD   = (CC * NCH + 255) / 256;
    constexpr int XSPAN = UPS ? (TT + 2) : ((TT - 1) * STRIDE + KW);
    constexpr int STEP  = UPS ? TT : TT * STRIDE;
    constexpr int NWQ   = CC * NWR * 8;
    static_assert((STEP & 3) == 0, "conv7 swizzle path requires STEP%4==0");

    __shared__ float xs[CC][XROW];
    __shared__ float wls[CC * NWR * 32];
    __shared__ float scs[NC], shs[NC];

    const int b = blockIdx.z, ocb = blockIdx.y, tid = threadIdx.x;
    const int t0 = blockIdx.x * PT, lane = tid & 63;
    const int wid = tid >> 6;
    const int oc0 = ocb * 32 + wid * 8;
    const int gb = UPS ? (t0 - 1) : (t0 * STRIDE - PAD);

    if (INMODE > 0) {
        for (int c = tid; c < NC; c += 256) {
            float m  = stp[c] * inv_n;
            float va = stp[NC + c] * inv_n - m * m;
            float sc = gp[c] * rsqrtf(va + 1e-5f);
            scs[c] = sc;
            shs[c] = btp[c] - m * sc;
        }
        __syncthreads();
    }

    float acc[8][TTO];
#pragma unroll
    for (int i = 0; i < 8; i++)
#pragma unroll
        for (int j = 0; j < TTO; j++) acc[i][j] = 0.f;

    float pre[NLD][4];

#define C7_STAGEW(CCBASE) do {                                              \
    for (int _u = tid; _u < NWQ; _u += 256) {                               \
        int _row = _u >> 3, _g8 = _u & 7;                                   \
        int _cl = _row / NWR, _t = _row % NWR;                              \
        ((float4*)wls)[_u] = *(const float4*)(wp +                          \
            ((size_t)((CCBASE) + _cl) * NWR + _t) * 128 + ocb * 32 + _g8 * 4); \
    }                                                                       \
} while (0)

#define C7_COMPCI(CI) do {                                                  \
    float _q[XSPAN];                                                        \
    const int _qb4 = lane * (STEP / 4);                                     \
    _Pragma("unroll")                                                       \
    for (int _u = 0; _u < XSPAN / 4; _u++) {                                \
        float4 _v = *(const float4*)&xs[CI][4 * swz4(_qb4 + _u)];           \
        _q[4*_u] = _v.x; _q[4*_u+1] = _v.y;                                 \
        _q[4*_u+2] = _v.z; _q[4*_u+3] = _v.w;                               \
    }                                                                       \
    if constexpr ((XSPAN & 3) != 0) {                                       \
        const int _pt = swz4(_qb4 + XSPAN / 4);                             \
        if constexpr ((XSPAN & 3) >= 2) {                                   \
            float2 _v = *(const float2*)&xs[CI][4 * _pt];                   \
            _q[(XSPAN & ~3)] = _v.x; _q[(XSPAN & ~3) + 1] = _v.y;           \
        }                                                                   \
        if constexpr ((XSPAN & 3) == 1)                                     \
            _q[XSPAN - 1] = xs[CI][4 * _pt];                                \
        else if constexpr ((XSPAN & 3) == 3)                                \
            _q[XSPAN - 1] = xs[CI][4 * _pt + 2];                            \
    }                                                                       \
    {                                                                       \
        _Pragma("unroll")                                                   \
        for (int _k = 0; _k < KW; _k++) {                                   \
            const float4 _w0 = *(const float4*)&wls[((CI) * NWR + _k) * 32 + wid * 8];     \
            const float4 _w1 = *(const float4*)&wls[((CI) * NWR + _k) * 32 + wid * 8 + 4]; \
            _Pragma("unroll")                                               \
            for (int _i = 0; _i < 8; _i++) {                                \
                float _wv = f4c(_i < 4 ? _w0 : _w1, _i & 3);                \
                _Pragma("unroll")                                           \
                for (int _j = 0; _j < TT; _j++)                             \
                    acc[_i][_j] = fmaf(_wv, _q[_j * STRIDE + _k], acc[_i][_j]); \
            }                                                               \
        }                                                                   \
    }                                                                       \
} while (0)

#pragma unroll
    for (int u = 0; u < NLD; u++) {
        int idx = tid + u * 256;
        if (idx < CC * NCH) {
            int cl = idx / NCH, q = idx - cl * NCH;
            loadg4(in + ((size_t)b * NC + cl) * L_in, gb + 4 * q, L_in, pre[u]);
        }
    }
#pragma unroll
    for (int u = 0; u < NLD; u++) {
        int idx = tid + u * 256;
        if (idx < CC * NCH) {
            int cl = idx / NCH, q = idx - cl * NCH;
            int g0 = gb + 4 * q;
            float e[4];
#pragma unroll
            for (int t = 0; t < 4; t++) {
                float v = pre[u][t];
                if (INMODE > 0) {
                    int gg = g0 + t;
                    if (gg >= 0 && gg < L_in) {
                        float s = v * scs[cl] + shs[cl];
                        v = (INMODE == 2) ? lrelu(s) : s;
                    }
                }
                e[t] = v;
            }
            *(float4*)&xs[cl][4 * swz4(q)] = make_float4(e[0], e[1], e[2], e[3]);
        }
    }
    C7_STAGEW(0);
    __syncthreads();

    for (int cc = 0; cc < NC; cc += CC) {
        if (cc + CC < NC) {
#pragma unroll
            for (int u = 0; u < NLD; u++) {
                int idx = tid + u * 256;
                if (idx < CC * NCH) {
                    int cl = idx / NCH, q = idx - cl * NCH;
                    loadg4(in + ((size_t)b * NC + cc + CC + cl) * L_in,
                           gb + 4 * q, L_in, pre[u]);
                }
            }
        }
#pragma unroll
        for (int ci = 0; ci < CC; ci++) {
            C7_COMPCI(ci);
        }
        __syncthreads();
        if (cc + CC < NC) {
#pragma unroll
            for (int u = 0; u < NLD; u++) {
                int idx = tid + u * 256;
                if (idx < CC * NCH) {
                    int cl = idx / NCH, q = idx - cl * NCH;
                    int g0 = gb + 4 * q;
                    int c = cc + CC + cl;
                    float e[4];
#pragma unroll
                    for (int t = 0; t < 4; t++) {
                        float v = pre[u][t];
                        if (INMODE > 0) {
                            int gg = g0 + t;
                            if (gg >= 0 && gg < L_in) {
                                float s = v * scs[c] + shs[c];
                                v = (INMODE == 2) ? lrelu(s) : s;
                            }
                        }
                        e[t] = v;
                    }
                    *(float4*)&xs[cl][4 * swz4(q)] = make_float4(e[0], e[1], e[2], e[3]);
                }
            }
            C7_STAGEW(cc + CC);
            __syncthreads();
        }
    }
#undef C7_STAGEW
#undef C7_COMPCI

    const int po = t0 + lane * TTO;
#pragma unroll
    for (int i = 0; i < 8; i++) {
        const int o = oc0 + i;
        const float bv = bias[o];
        float s1 = 0.f, s2 = 0.f;
        float tmpm[TTO];
#pragma unroll
        for (int j = 0; j < TTO; j++) {
            float v = acc[i][j] + bv;
            if (OUTACT) v = lrelu(v);
            tmpm[j] = v;
            if (STATS) { s1 += v; s2 += v * v; }
        }
        float* orow = out + ((size_t)b * NC + o) * L_out + po;
        if constexpr (TTO == 4)
            *(float4*)orow = make_float4(tmpm[0], tmpm[1], tmpm[2], tmpm[3]);
        else if constexpr (TTO == 2)
            *(float2*)orow = make_float2(tmpm[0], tmpm[1]);
        else
            orow[0] = tmpm[0];
        if (STATS) {
#pragma unroll
            for (int m = 1; m < 64; m <<= 1) {
                s1 += __shfl_xor(s1, m);
                s2 += __shfl_xor(s2, m);
            }
            if (lane == 0) {
                atomicAdd(&stats[o], s1);
                atomicAdd(&stats[NC + o], s2);
            }
        }
    }
}

// ---------------------------------------------------------------------------
__global__ __launch_bounds__(256) void cvtW_k(const float* __restrict__ W,
                                              unsigned short* __restrict__ Wbf)
{
    int i = blockIdx.x * 256 + threadIdx.x;
    const float4 a = *(const float4*)&W[i * 8];
    const float4 b = *(const float4*)&W[i * 8 + 4];
    unsigned pk[4];
    pk[0] = bf16r(a.x) | (bf16r(a.y) << 16);
    pk[1] = bf16r(a.z) | (bf16r(a.w) << 16);
    pk[2] = bf16r(b.x) | (bf16r(b.y) << 16);
    pk[3] = bf16r(b.z) | (bf16r(b.w) << 16);
    *(uint4*)&Wbf[i * 8] = make_uint4(pk[0], pk[1], pk[2], pk[3]);
}

// ---------------------------------------------------------------------------
// salM2: MFMA bf16 GEMM over (128h x 128l) tiles (unchanged).
// ---------------------------------------------------------------------------
template<int PHASE>
__global__ __launch_bounds__(256) void salM2_k(
    const unsigned short* __restrict__ xT, const unsigned short* __restrict__ Wbf,
    const float* __restrict__ bias, float* __restrict__ gsum,
    unsigned* __restrict__ ghist, const unsigned* __restrict__ thrv,
    unsigned* __restrict__ candcnt, unsigned* __restrict__ candI)
{
    __shared__ unsigned short Als[128 * 128];
    __shared__ unsigned short Bls[128 * 128];

    const int b  = blockIdx.z;
    const int h0 = blockIdx.y * 128;
    const int l0 = blockIdx.x * 128;
    const int tid = threadIdx.x;
    const int lane = tid & 63;
    const int wid = tid >> 6;
    const int wh = (wid >> 1) * 64;
    const int wl = (wid & 1) * 64;

    {
        const uint4* gA = (const uint4*)(Wbf + (size_t)h0 * NC);
        const uint4* gB = (const uint4*)(xT + ((size_t)b * LFULL + l0) * NC);
        char* cA = (char*)Als; char* cB = (char*)Bls;
        for (int i = tid; i < 2048; i += 256) {
            int row = i >> 4, q = i & 15;
            unsigned sw = (unsigned)(row * 256 + q * 16) ^ (((unsigned)(row & 7)) << 4);
            *(uint4*)(cA + sw) = gA[i];
        }
        for (int i = tid; i < 2048; i += 256) {
            int row = i >> 4, q = i & 15;
            unsigned sw = (unsigned)(row * 256 + q * 16) ^ (((unsigned)(row & 7)) << 4);
            *(uint4*)(cB + sw) = gB[i];
        }
    }
    __syncthreads();

    f32x4 acc[4][4];
#pragma unroll
    for (int i = 0; i < 4; i++)
#pragma unroll
        for (int j = 0; j < 4; j++) acc[i][j] = (f32x4)(0.f);

    const int r15 = lane & 15, g = lane >> 4;
#pragma unroll
    for (int ks = 0; ks < 4; ks++) {
        bf16x8 af[4], bfv[4];
#pragma unroll
        for (int f = 0; f < 4; f++) {
            int rowA = wh + f * 16 + r15;
            unsigned offA = (unsigned)(rowA * 256 + ks * 64 + g * 16)
                          ^ (((unsigned)(rowA & 7)) << 4);
            af[f] = *(const bf16x8*)((const char*)Als + offA);
            int rowB = wl + f * 16 + r15;
            unsigned offB = (unsigned)(rowB * 256 + ks * 64 + g * 16)
                          ^ (((unsigned)(rowB & 7)) << 4);
            bfv[f] = *(const bf16x8*)((const char*)Bls + offB);
        }
#pragma unroll
        for (int i = 0; i < 4; i++)
#pragma unroll
            for (int j = 0; j < 4; j++)
                acc[i][j] = __builtin_amdgcn_mfma_f32_16x16x32_bf16(
                    af[i], bfv[j], acc[i][j], 0, 0, 0);
    }

    if constexpr (PHASE == 0) {
        __syncthreads();
        unsigned* lhist = (unsigned*)Als;
        for (int i = tid; i < 8192; i += 256) lhist[i] = 0;
        __syncthreads();
        unsigned* myh = lhist + (tid & 1) * 4096;
        float expsum = 0.f;
#pragma unroll
        for (int i = 0; i < 4; i++) {
#pragma unroll
            for (int r = 0; r < 4; r++) {
                const int h = h0 + wh + i * 16 + g * 4 + r;
                const float bv = bias[h];
#pragma unroll
                for (int j = 0; j < 4; j++) {
                    float v = acc[i][j][r] + bv;
                    expsum += expf(v);
                    atomicAdd(&myh[monoKey16(bf16r(v)) >> 4], 1u);
                }
            }
        }
#pragma unroll
        for (int m = 1; m < 64; m <<= 1) expsum += __shfl_xor(expsum, m);
        float* red = (float*)Bls;
        if (lane == 0) red[wid] = expsum;
        __syncthreads();
        for (int i = tid; i < 4096; i += 256) {
            unsigned s = lhist[i] + lhist[4096 + i];
            if (s) atomicAdd(&ghist[b * 4096 + i], s);
        }
        if (tid == 0) atomicAdd(&gsum[b], red[0] + red[1] + red[2] + red[3]);
    } else {
        const unsigned thr = thrv[b * 2];
#pragma unroll
        for (int i = 0; i < 4; i++) {
#pragma unroll
            for (int r = 0; r < 4; r++) {
                const int h = h0 + wh + i * 16 + g * 4 + r;
                const float bv = bias[h];
#pragma unroll
                for (int j = 0; j < 4; j++) {
                    float v = acc[i][j][r] + bv;
                    bool pr = monoKey16(bf16r(v)) >= thr;
                    unsigned long long m = __ballot(pr);
                    if (m) {
                        int leader = __ffsll((unsigned long long)m) - 1;
                        int cnt = __popcll(m);
                        unsigned basepos = 0;
                        if (lane == leader)
                            basepos = atomicAdd(&candcnt[b], (unsigned)cnt);
                        basepos = __shfl(basepos, leader);
                        if (pr) {
                            int rr = __popcll(m & ((1ull << lane) - 1ull));
                            unsigned pos = basepos + (unsigned)rr;
                            if (pos < CAP) {
                                int l = l0 + wl + j * 16 + r15;
                                candI[b * CAP + pos] = (unsigned)((h << 13) | l);
                            }
                        }
                    }
                }
            }
        }
    }
}

// ---------------------------------------------------------------------------
__global__ __launch_bounds__(256) void scan2_k(
    const unsigned* __restrict__ ghist, unsigned* __restrict__ thrv)
{
    const int b = blockIdx.x, tid = threadIdx.x;
    __shared__ unsigned part[256];
    unsigned s = 0;
#pragma unroll
    for (int i = 0; i < 16; i++) s += ghist[b * 4096 + tid * 16 + i];
    part[tid] = s;
    __syncthreads();
    if (tid == 0) {
        unsigned cum = 0; int ch;
        for (ch = 255; ch >= 0; ch--) {
            if (cum + part[ch] >= KSEL) break;
            cum += part[ch];
        }
        int bin = 0;
        if (ch >= 0) {
            for (bin = ch * 16 + 15; bin > ch * 16; bin--) {
                unsigned c = ghist[b * 4096 + bin];
                if (cum + c >= KSEL) break;
                cum += c;
            }
        }
        int bcol = bin > 0 ? bin - 1 : 0;
        thrv[b * 2] = (unsigned)bcol << 4;
    }
}

__global__ __launch_bounds__(128) void recompute_k(
    const unsigned* __restrict__ candcnt, const unsigned* __restrict__ candI,
    const float* __restrict__ xu, const float* __restrict__ W,
    const float* __restrict__ bias, unsigned* __restrict__ candK)
{
    const int b = blockIdx.y;
    const unsigned cnt = min(candcnt[b], (unsigned)CAP);
    const int t = threadIdx.x;
    __shared__ float wsum[2];
    for (unsigned k = blockIdx.x; k < cnt; k += 1024) {
        unsigned e = candI[b * CAP + k];
        int h = e >> 13, l = e & 8191;
        float prod = W[h * NC + t] * xu[(b * NC + t) * LFULL + l];
#pragma unroll
        for (int m = 1; m < 64; m <<= 1) prod += __shfl_xor(prod, m);
        if ((t & 63) == 0) wsum[t >> 6] = prod;
        __syncthreads();
        if (t == 0) candK[b * CAP + k] = monoKey(wsum[0] + wsum[1] + bias[h]);
        __syncthreads();
    }
}

__global__ __launch_bounds__(256) void select2_k(
    const unsigned* __restrict__ candcnt, const unsigned* __restrict__ candK,
    const unsigned* __restrict__ candI,
    uint2* __restrict__ selected, unsigned* __restrict__ selcnt)
{
    const int b = blockIdx.x, tid = threadIdx.x;
    __shared__ unsigned h1[4096];
    __shared__ unsigned l2k[2048], l2i[2048];
    __shared__ unsigned part[256];
    __shared__ unsigned sh[8];

    const unsigned Nc = min(candcnt[b], (unsigned)CAP);
    const unsigned* kk = candK + b * CAP;
    const unsigned* ii = candI + b * CAP;
    uint2* sel = selected + b * KSEL;

    for (int i = tid; i < 4096; i += 256) h1[i] = 0;
    if (tid < 8) sh[tid] = 0;
    __syncthreads();
    for (unsigned i = tid; i < Nc; i += 256) atomicAdd(&h1[kk[i] >> 20], 1u);
    __syncthreads();
    {
        unsigned s = 0;
#pragma unroll
        for (int i = 0; i < 16; i++) s += h1[tid * 16 + i];
        part[tid] = s;
        __syncthreads();
        if (tid == 0) {
            unsigned cum = 0; int ch;
            for (ch = 255; ch >= 0; ch--) { if (cum + part[ch] >= KSEL) break; cum += part[ch]; }
            int bin = 0;
            if (ch >= 0)
                for (bin = ch * 16 + 15; bin > ch * 16; bin--) {
                    unsigned c = h1[bin];
                    if (cum + c >= KSEL) break;
                    cum += c;
                }
            sh[2] = (unsigned)bin; sh[3] = KSEL - cum;
        }
    }
    __syncthreads();
    const unsigned b1 = sh[2], need1 = sh[3];
    for (int i = tid; i < 1024; i += 256) h1[i] = 0;
    __syncthreads();
    for (unsigned i = tid; i < Nc; i += 256) {
        unsigned k = kk[i], bin = k >> 20;
        if (bin > b1) {
            unsigned p = atomicAdd(&sh[0], 1u);
            if (p < KSEL) sel[p] = make_uint2(k, ii[i]);
        } else if (bin == b1) {
            atomicAdd(&h1[(k >> 10) & 1023], 1u);
        }
    }
    __syncthreads();
    {
        unsigned s = 0;
#pragma unroll
        for (int i = 0; i < 4; i++) s += h1[tid * 4 + i];
        part[tid] = s;
        __syncthreads();
        if (tid == 0) {
            unsigned cum = 0; int ch;
            for (ch = 255; ch >= 0; ch--) { if (cum + part[ch] >= need1) break; cum += part[ch]; }
            int bin = 0;
            if (ch >= 0)
                for (bin = ch * 4 + 3; bin > ch * 4; bin--) {
                    unsigned c = h1[bin];
                    if (cum + c >= need1) break;
                    cum += c;
                }
            sh[4] = (unsigned)bin; sh[5] = need1 - cum;
        }
    }
    __syncthreads();
    const unsigned b2 = sh[4], need2 = sh[5];
    for (int i = tid; i < 1024; i += 256) h1[i] = 0;
    __syncthreads();
    for (unsigned i = tid; i < Nc; i += 256) {
        unsigned k = kk[i];
        if ((k >> 20) != b1) continue;
        unsigned mb = (k >> 10) & 1023;
        if (mb > b2) {
            unsigned p = atomicAdd(&sh[0], 1u);
            if (p < KSEL) sel[p] = make_uint2(k, ii[i]);
        } else if (mb == b2) {
            unsigned j = atomicAdd(&sh[1], 1u);
            if (j < 2048) { l2k[j] = k; l2i[j] = ii[i]; atomicAdd(&h1[k & 1023], 1u); }
        }
    }
    __syncthreads();
    const unsigned m2 = min(sh[1], 2048u);
    {
        unsigned s = 0;
#pragma unroll
        for (int i = 0; i < 4; i++) s += h1[tid * 4 + i];
        part[tid] = s;
        __syncthreads();
        if (tid == 0) {
            unsigned cum = 0; int ch;
            for (ch = 255; ch >= 0; ch--) { if (cum + part[ch] >= need2) break; cum += part[ch]; }
            int bin = 0;
            if (ch >= 0)
                for (bin = ch * 4 + 3; bin > ch * 4; bin--) {
                    unsigned c = h1[bin];
                    if (cum + c >= need2) break;
                    cum += c;
                }
            sh[6] = (unsigned)bin; sh[7] = need2 - cum;
        }
    }
    __syncthreads();
    const unsigned b3 = sh[6], need3 = sh[7];
    if (tid == 0) sh[1] = 0;
    __syncthreads();
    for (unsigned i = tid; i < m2; i += 256) {
        unsigned k = l2k[i], lb = k & 1023;
        if (lb > b3) {
            unsigned p = atomicAdd(&sh[0], 1u);
            if (p < KSEL) sel[p] = make_uint2(k, l2i[i]);
        } else if (lb == b3) {
            unsigned t = atomicAdd(&sh[1], 1u);
            if (t < need3) {
                unsigned p = atomicAdd(&sh[0], 1u);
                if (p < KSEL) sel[p] = make_uint2(k, l2i[i]);
            }
        }
    }
    __syncthreads();
    if (tid == 0) selcnt[b] = min(sh[0], (unsigned)KSEL);
}

// ---------------------------------------------------------------------------
__global__ void inity_k(float* __restrict__ y, const float* __restrict__ bias)
{
    int i = blockIdx.x * 256 + threadIdx.x;
    float bv = bias[(i >> 11) & 127];
    ((float4*)y)[i] = make_float4(bv, bv, bv, bv);
}

__global__ __launch_bounds__(128) void scatter_k(
    const uint2* __restrict__ selected, const unsigned* __restrict__ selcnt,
    const float* __restrict__ gsum, const float* __restrict__ xu,
    const float* __restrict__ upw, const float* __restrict__ upb,
    const float* __restrict__ dww, float* __restrict__ y)
{
    const int b = blockIdx.y, kidx = blockIdx.x;
    if (kidx >= (int)selcnt[b]) return;
    const uint2 s = selected[b * KSEL + kidx];
    const float salv = keyToF(s.x);
    const unsigned idx = s.y;
    const int h = idx >> 13, l = idx & 8191;
    const int t = threadIdx.x;

    float prod = upw[h * NC + t] * xu[(b * NC + t) * LFULL + l];
#pragma unroll
    for (int m = 1; m < 64; m <<= 1) prod += __shfl_xor(prod, m);
    __shared__ float wsum[2];
    if ((t & 63) == 0) wsum[t >> 6] = prod;
    __syncthreads();
    const float sig = wsum[0] + wsum[1] + upb[h];
    const float val = expf(salv) / gsum[b];
    const float g = sig * val;
    atomicAdd(&y[(b * NC + t) * LFULL + l], dww[t * NH + h] * g);
}

__global__ void apply_k(const float* __restrict__ in, const float* __restrict__ stats,
                        const float* __restrict__ g, const float* __restrict__ bt,
                        float* __restrict__ out, float inv_n)
{
    int i = blockIdx.x * 256 + threadIdx.x;
    int c = (i >> 7) & 127;
    float m  = stats[c] * inv_n;
    float va = stats[NC + c] * inv_n - m * m;
    float sc = g[c] * rsqrtf(va + 1e-5f);
    out[i] = in[i] * sc + (bt[c] - m * sc);
}

// ---------------------------------------------------------------------------
extern "C" void kernel_launch(void* const* d_in, const int* in_sizes, int n_in,
                              void* d_out, int out_size, void* d_ws, size_t ws_size,
                              hipStream_t stream)
{
    const float* x        = (const float*)d_in[0];
    const float* up_w     = (const float*)d_in[1];
    const float* up_b     = (const float*)d_in[2];
    const float* up_g     = (const float*)d_in[3];
    const float* up_beta  = (const float*)d_in[4];
    const float* up_out_w = (const float*)d_in[5];
    const float* up_out_b = (const float*)d_in[6];
    const float* sb_up_w  = (const float*)d_in[7];
    const float* sb_up_b  = (const float*)d_in[8];
    const float* sal_w    = (const float*)d_in[9];
    const float* sal_b    = (const float*)d_in[10];
    const float* sb_dn_w  = (const float*)d_in[11];
    const float* sb_dn_b  = (const float*)d_in[12];
    const float* dn_w     = (const float*)d_in[13];
    const float* dn_b     = (const float*)d_in[14];
    const float* dn_g     = (const float*)d_in[15];
    const float* dn_beta  = (const float*)d_in[16];

    char* ws = (char*)d_ws;
    float*          stats    = (float*)(ws + 0);
    float*          gsum     = (float*)(ws + 16384);
    unsigned*       thrv     = (unsigned*)(ws + 16416);
    unsigned*       candcnt  = (unsigned*)(ws + 16480);
    unsigned*       selcnt   = (unsigned*)(ws + 16512);
    uint2*          selected = (uint2*)(ws + 16640);
    unsigned*       ghist    = (unsigned*)(ws + 49408);
    unsigned*       candK    = (unsigned*)(ws + 180480);
    unsigned*       candI    = (unsigned*)(ws + 1229056);
    unsigned short* Wbf      = (unsigned short*)(ws + 2277632);
    float*          wprep    = (float*)(ws + 2539776);
    float*          B0       = (float*)(ws + 5685504);
    float*          B1       = (float*)(ws + 39239936);
    unsigned short* xT       = (unsigned short*)(ws + 72794368);
    float*          y        = (float*)(ws + 72794368);
    unsigned short* Afrag    = (unsigned short*)(ws + 117440512);
    float*          partial  = (float*)(ws + 121634816);

    hipMemsetAsync(d_ws, 0, 16544, stream);
    hipMemsetAsync(ws + 49408, 0, 131072, stream);

    cvtW_k<<<64,256,0,stream>>>(sal_w, Wbf);
    prep_k<<<3072,256,0,stream>>>(up_w, up_out_w, dn_w, wprep);
    prepA_k<<<864,256,0,stream>>>(up_w, up_out_w, Afrag);

    // ---- ConvUpsample (MFMA, 8-wave blocks): 128 -> 8192 frames ----
    mconvU_k<0><<<dim3(2,NB),512,0,stream>>>(
        x, B0, Afrag, up_b, nullptr, nullptr, nullptr, 0.f, partial, 128);
    redstats_k<<<1,256,0,stream>>>(partial, 2*NB, stats);
    mconvU_k<2><<<dim3(4,NB),512,0,stream>>>(
        B0, B1, Afrag + 1*262144, up_b + NC,
        stats, up_g, up_beta, 1.f/(float)(NB*256), partial, 256);
    redstats_k<<<1,256,0,stream>>>(partial, 4*NB, stats + 256);
    mconvU_k<2><<<dim3(8,NB),512,0,stream>>>(
        B1, B0, Afrag + 2*262144, up_b + 2*NC,
        stats + 256, up_g + NC, up_beta + NC, 1.f/(float)(NB*512), partial, 512);
    redstats_k<<<1,256,0,stream>>>(partial, 8*NB, stats + 2*256);
    mconvU_k<2><<<dim3(16,NB),512,0,stream>>>(
        B0, B1, Afrag + 3*262144, up_b + 3*NC,
        stats + 2*256, up_g + 2*NC, up_beta + 2*NC, 1.f/(float)(NB*1024), partial, 1024);
    redstats_k<<<1,256,0,stream>>>(partial, 16*NB, stats + 3*256);
    mconvU_k<2><<<dim3(32,NB),512,0,stream>>>(
        B1, B0, Afrag + 4*262144, up_b + 4*NC,
        stats + 3*256, up_g + 3*NC, up_beta + 3*NC, 1.f/(float)(NB*2048), partial, 2048);
    redstats_k<<<1,256,0,stream>>>(partial, 32*NB, stats + 4*256);
    mconvU_k<2><<<dim3(64,NB),512,0,stream>>>(
        B0, B1, Afrag + 5*262144, up_b + 5*NC,
        stats + 4*256, up_g + 4*NC, up_beta + 4*NC, 1.f/(float)(NB*4096), partial, 4096);
    redstats_k<<<1,256,0,stream>>>(partial, 64*NB, stats + 5*256);
    // final k3 conv (MFMA): B1 -> B0 (f32 x_up) + xT (bf16 transposed)
    mconvF_k<<<dim3(64,NB),512,0,stream>>>(
        B1, B0, Afrag, up_out_b,
        stats + 5*256, up_g + 5*NC, up_beta + 5*NC, 1.f/(float)(NB*LFULL), xT);

    // ---- SparseBottleneck ----
    salM2_k<0><<<dim3(64,8,NB),256,0,stream>>>(xT, Wbf, sal_b, gsum, ghist,
                                               nullptr, nullptr, nullptr);
    scan2_k<<<NB,256,0,stream>>>(ghist, thrv);
    salM2_k<1><<<dim3(64,8,NB),256,0,stream>>>(xT, Wbf, sal_b, nullptr, nullptr,
                                               thrv, candcnt, candI);
    recompute_k<<<dim3(1024,NB),128,0,stream>>>(candcnt, candI, B0, sal_w, sal_b, candK);
    select2_k<<<NB,256,0,stream>>>(candcnt, candK, candI, selected, selcnt);
    inity_k<<<(NB*NC*LFULL/4)/256,256,0,stream>>>(y, sb_dn_b);
    scatter_k<<<dim3(KSEL,NB),128,0,stream>>>(selected, selcnt, gsum, B0,
                                              sb_up_w, sb_up_b, sb_dn_w, y);

    // ---- down stack (VALU, swizzled): 8192 -> 128 ----
    conv7_k<7,4,3,false,0,true,true,2,false><<<dim3(16,4,NB),256,0,stream>>>(
        y, B1, wprep + 442368, dn_b, nullptr, nullptr, nullptr, 0.f,
        stats + 6*256, nullptr, 8192, 2048);
    conv7_k<7,4,3,false,1,true,true,2,false><<<dim3(4,4,NB),256,0,stream>>>(
        B1, B0, wprep + 442368 + 114688, dn_b + NC,
        stats + 6*256, dn_g, dn_beta, 1.f/(float)(NB*2048),
        stats + 7*256, nullptr, 2048, 512);
    conv7_k<7,4,3,false,1,true,true,1,false><<<dim3(2,4,NB),256,0,stream>>>(
        B0, B1, wprep + 442368 + 2*114688, dn_b + 2*NC,
        stats + 7*256, dn_g + NC, dn_beta + NC, 1.f/(float)(NB*512),
        stats + 8*256, nullptr, 512, 128);

    apply_k<<<(out_size + 255)/256,256,0,stream>>>(
        B1, stats + 8*256, dn_g + 2*NC, dn_beta + 2*NC, (float*)d_out,
        1.f/(float)(NB*128));
}

// Round 16
// 741.488 us; speedup vs baseline: 1.3602x; 1.2950x over previous
//
#include <hip/hip_runtime.h>
#include <hip/hip_bf16.h>

// ---------------------------------------------------------------------------
// ExpandAndContractBottleneck.  R16: R15 with redstats_k parallelized
// (16 blocks x 4-way MLP + per-block atomicAdd) -- the 1-block serial
// reduction was ~230us of wall (560cy dependent-load chain per element).
// ---------------------------------------------------------------------------

#define DEV_INLINE __device__ __forceinline__

constexpr int NB   = 8;
constexpr int NC   = 128;
constexpr int NH   = 1024;
constexpr int LFULL= 8192;
constexpr int KSEL = 512;
constexpr int CAP  = 32768;

typedef __attribute__((ext_vector_type(4))) float f32x4;
typedef __attribute__((ext_vector_type(8))) short bf16x8;

DEV_INLINE unsigned monoKey(float f) {
    unsigned u = __float_as_uint(f);
    return (u & 0x80000000u) ? ~u : (u | 0x80000000u);
}
DEV_INLINE float keyToF(unsigned k) {
    unsigned u = (k & 0x80000000u) ? (k ^ 0x80000000u) : ~k;
    return __uint_as_float(u);
}
DEV_INLINE unsigned monoKey16(unsigned u) {
    return (u & 0x8000u) ? ((~u) & 0xFFFFu) : (u | 0x8000u);
}
DEV_INLINE unsigned bf16r(float f) {
    unsigned u = __float_as_uint(f);
    return (u + 0x7FFFu + ((u >> 16) & 1u)) >> 16;
}
DEV_INLINE float lrelu(float v) { return v >= 0.f ? v : 0.2f * v; }
DEV_INLINE float f4c(const float4& v, int k) {
    return k == 0 ? v.x : k == 1 ? v.y : k == 2 ? v.z : v.w;
}
DEV_INLINE int swz4(int p) { return p ^ ((p >> 3) & 7); }

DEV_INLINE void loadg4(const float* __restrict__ rowp, int g0, int L, float* e) {
    if (g0 >= 0 && g0 + 4 <= L) {
        float4 v = *(const float4*)(rowp + g0);
        e[0] = v.x; e[1] = v.y; e[2] = v.z; e[3] = v.w;
    } else {
#pragma unroll
        for (int t = 0; t < 4; t++) {
            int g = g0 + t;
            e[t] = (g >= 0 && g < L) ? rowp[g] : 0.f;
        }
    }
}

// ---------------------------------------------------------------------------
// prep_k: VALU dn weights [c][tap][128 oc].
// ---------------------------------------------------------------------------
__global__ __launch_bounds__(256) void prep_k(
    const float* __restrict__ up_w, const float* __restrict__ up_out_w,
    const float* __restrict__ dn_w, float* __restrict__ wprep)
{
    int idx = blockIdx.x * 256 + threadIdx.x;
    if (idx < 393216) {
        int layer = idx >> 16;
        int r0 = idx & 65535;
        int c = r0 >> 9, r = (r0 >> 7) & 3, o = r0 & 127;
        const float* wsrc = up_w + ((size_t)layer * 128 + o) * 384 + c * 3;
        float w0 = wsrc[0], w1 = wsrc[1], w2 = wsrc[2];
        wprep[idx] = (r == 0) ? w0 : (r == 1) ? (w1 + w2) : (r == 2) ? (w0 + w1) : w2;
    } else if (idx < 442368) {
        int r0 = idx - 393216;
        int c = r0 / 384, k = (r0 / 128) % 3, o = r0 & 127;
        wprep[idx] = up_out_w[((size_t)o * 128 + c) * 3 + k];
    } else {
        int r0 = idx - 442368;
        int layer = r0 / 114688;
        int r1 = r0 - layer * 114688;
        int c = r1 / 896, k = (r1 / 128) % 7, o = r1 & 127;
        wprep[idx] = dn_w[((size_t)layer * 128 + o) * 896 + c * 7 + k];
    }
}

// ---------------------------------------------------------------------------
// prepA_k: MFMA A-operand fragment records (unchanged).
// ---------------------------------------------------------------------------
__global__ __launch_bounds__(256) void prepA_k(
    const float* __restrict__ up_w, const float* __restrict__ up_out_w,
    unsigned short* __restrict__ afrag)
{
    int idx = blockIdx.x * 256 + threadIdx.x;
    if (idx >= 221184) return;
    int rid = idx >> 6, lane = idx & 63;
    const int r15 = lane & 15, g = lane >> 4;
    unsigned short vals[8];
    if (rid < 3072) {
        int L  = rid >> 9;
        int r0 = rid & 511;
        int f = r0 & 3, ks = (r0 >> 2) & 1, cc = (r0 >> 3) & 1;
        int wo = (r0 >> 4) & 1, half = (r0 >> 5) & 1, ptap = (r0 >> 6) & 3;
        int o = wo * 64 + f * 16 + r15;
        int cb = cc * 64 + ks * 32 + g * 8;
#pragma unroll
        for (int e = 0; e < 8; e++) {
            const float* ws = up_w + (((size_t)L * 128 + o) * 128 + (cb + e)) * 3;
            float w0 = ws[0], w1 = ws[1], w2 = ws[2];
            float v = (ptap == 0) ? w0 : (ptap == 1) ? (w1 + w2)
                    : (ptap == 2) ? (w0 + w1) : w2;
            unsigned hi = bf16r(v);
            if (half == 0) vals[e] = (unsigned short)hi;
            else vals[e] = (unsigned short)bf16r(v - __uint_as_float(hi << 16));
        }
    } else {
        int r2 = rid - 3072;
        int f = r2 & 3, ks = (r2 >> 2) & 1, cc = (r2 >> 3) & 1;
        int wo = (r2 >> 4) & 1, half = (r2 >> 5) & 1, tap = r2 >> 6;
        int o = wo * 64 + f * 16 + r15;
        int cb = cc * 64 + ks * 32 + g * 8;
#pragma unroll
        for (int e = 0; e < 8; e++) {
            float v = up_out_w[((size_t)o * 128 + (cb + e)) * 3 + tap];
            unsigned hi = bf16r(v);
            if (half == 0) vals[e] = (unsigned short)hi;
            else vals[e] = (unsigned short)bf16r(v - __uint_as_float(hi << 16));
        }
    }
    unsigned pk[4];
#pragma unroll
    for (int q = 0; q < 4; q++)
        pk[q] = (unsigned)vals[2*q] | ((unsigned)vals[2*q+1] << 16);
    *(uint4*)(afrag + (size_t)rid * 512 + lane * 8) = make_uint4(pk[0], pk[1], pk[2], pk[3]);
}

// ---------------------------------------------------------------------------
// redstats_k: PARALLEL reduce of per-block partials [nb][256] -> stats[256].
// grid=16 blocks; 4 independent accumulators per thread; atomicAdd finish.
// stats region must be zeroed before the layer sequence (host memset does).
// ---------------------------------------------------------------------------
__global__ __launch_bounds__(256) void redstats_k(
    const float* __restrict__ partial, int nb, float* __restrict__ stats)
{
    const int c = threadIdx.x;
    float s0 = 0.f, s1 = 0.f, s2 = 0.f, s3 = 0.f;
    for (int i = blockIdx.x * 4; i < nb; i += gridDim.x * 4) {
        s0 += partial[(size_t)(i + 0) * 256 + c];
        s1 += partial[(size_t)(i + 1) * 256 + c];
        s2 += partial[(size_t)(i + 2) * 256 + c];
        s3 += partial[(size_t)(i + 3) * 256 + c];
    }
    float s = (s0 + s1) + (s2 + s3);
    if (s != 0.f || blockIdx.x == 0) atomicAdd(&stats[c], s);
}

// ---------------------------------------------------------------------------
// mconvU_k: UPS MFMA conv, 512 threads / 8 waves (unchanged from R15).
// ---------------------------------------------------------------------------
template<int INMODE>
__global__ __launch_bounds__(512) void mconvU_k(
    const float* __restrict__ in, float* __restrict__ out,
    const unsigned short* __restrict__ afrag, const float* __restrict__ bias,
    const float* __restrict__ stp, const float* __restrict__ gp,
    const float* __restrict__ btp, float inv_n,
    float* __restrict__ partial, int L_in)
{
    __shared__ unsigned short Xh[66 * 64], Xl[66 * 64];
    __shared__ float scs[NC], shs[NC];
    __shared__ float sstat[256];

    const int b = blockIdx.y, tile0 = blockIdx.x * 64, tid = threadIdx.x;
    const int lane = tid & 63, wid = tid >> 6;
    const int wo = wid >> 2, par = (wid >> 1) & 1, jh = wid & 1;
    const int r15 = lane & 15, g = lane >> 4;
    const int bid = b * gridDim.x + blockIdx.x;

    if (tid < 256) sstat[tid] = 0.f;
    if (INMODE > 0) {
        for (int c = tid; c < NC; c += 512) {
            float m  = stp[c] * inv_n;
            float va = stp[NC + c] * inv_n - m * m;
            float sc = gp[c] * rsqrtf(va + 1e-5f);
            scs[c] = sc;
            shs[c] = btp[c] - m * sc;
        }
    }

    f32x4 acc[4][2];
#pragma unroll
    for (int i = 0; i < 4; i++)
#pragma unroll
        for (int j = 0; j < 2; j++) acc[i][j] = (f32x4)(0.f);

    for (int cc = 0; cc < 2; cc++) {
        __syncthreads();
        {
            int r = tid & 63;
            int l = tile0 - 1 + r;
            for (int c0 = (tid >> 6); c0 < 64; c0 += 8) {
                int c = cc * 64 + c0;
                float v = 0.f;
                if (l >= 0 && l < L_in) {
                    v = in[((size_t)b * NC + c) * L_in + l];
                    if (INMODE > 0) v = lrelu(v * scs[c] + shs[c]);
                }
                unsigned hi = bf16r(v);
                unsigned lo = bf16r(v - __uint_as_float(hi << 16));
                unsigned bo = ((unsigned)(r * 128 + c0 * 2)) ^ (((unsigned)(r & 7)) << 4);
                *(unsigned short*)((char*)Xh + bo) = (unsigned short)hi;
                *(unsigned short*)((char*)Xl + bo) = (unsigned short)lo;
            }
            if (tid < 128) {
                int r2 = 64 + (tid >> 6);
                int l2 = tile0 - 1 + r2;
                int c0 = tid & 63;
                int c = cc * 64 + c0;
                float v = 0.f;
                if (l2 >= 0 && l2 < L_in) {
                    v = in[((size_t)b * NC + c) * L_in + l2];
                    if (INMODE > 0) v = lrelu(v * scs[c] + shs[c]);
                }
                unsigned hi = bf16r(v);
                unsigned lo = bf16r(v - __uint_as_float(hi << 16));
                unsigned bo = ((unsigned)(r2 * 128 + c0 * 2)) ^ (((unsigned)(r2 & 7)) << 4);
                *(unsigned short*)((char*)Xh + bo) = (unsigned short)hi;
                *(unsigned short*)((char*)Xl + bo) = (unsigned short)lo;
            }
        }
        __syncthreads();
#pragma unroll
        for (int pt = 0; pt < 2; pt++) {
            const int ptap = par * 2 + pt;
            const int roff = (ptap == 0) ? 0 : (ptap == 3) ? 2 : 1;
#pragma unroll
            for (int combo = 0; combo < 3; combo++) {
                const int ah = (combo == 2) ? 1 : 0;
                const unsigned short* Xs = (combo == 1) ? Xl : Xh;
                bf16x8 af[8];
#pragma unroll
                for (int ks = 0; ks < 2; ks++)
#pragma unroll
                    for (int f = 0; f < 4; f++) {
                        int rec = ((((ptap * 2 + ah) * 2 + wo) * 2 + cc) * 2 + ks) * 4 + f;
                        af[ks * 4 + f] = *(const bf16x8*)(afrag + (size_t)rec * 512 + lane * 8);
                    }
#pragma unroll
                for (int ks = 0; ks < 2; ks++) {
                    bf16x8 bf_[2];
#pragma unroll
                    for (int j = 0; j < 2; j++) {
                        int row = (jh * 2 + j) * 16 + r15 + roff;
                        unsigned bo = ((unsigned)(row * 128 + ks * 64 + g * 16))
                                    ^ (((unsigned)(row & 7)) << 4);
                        bf_[j] = *(const bf16x8*)((const char*)Xs + bo);
                    }
#pragma unroll
                    for (int i = 0; i < 4; i++)
#pragma unroll
                        for (int j = 0; j < 2; j++)
                            acc[i][j] = __builtin_amdgcn_mfma_f32_16x16x32_bf16(
                                af[ks * 4 + i], bf_[j], acc[i][j], 0, 0, 0);
                }
            }
        }
    }

    const int L_out = 2 * L_in;
#pragma unroll
    for (int i = 0; i < 4; i++) {
#pragma unroll
        for (int r = 0; r < 4; r++) {
            const int o = wo * 64 + i * 16 + g * 4 + r;
            const float bv = bias[o];
            float s1 = 0.f, s2 = 0.f;
#pragma unroll
            for (int j = 0; j < 2; j++) {
                float v = acc[i][j][r] + bv;
                int lout = 2 * (tile0 + (jh * 2 + j) * 16 + r15) + par;
                out[((size_t)b * NC + o) * L_out + lout] = v;
                s1 += v; s2 += v * v;
            }
#pragma unroll
            for (int m = 1; m < 16; m <<= 1) {
                s1 += __shfl_xor(s1, m);
                s2 += __shfl_xor(s2, m);
            }
            if (r15 == 0) {
                atomicAdd(&sstat[o], s1);
                atomicAdd(&sstat[NC + o], s2);
            }
        }
    }
    __syncthreads();
    if (tid < 256) partial[(size_t)bid * 256 + tid] = sstat[tid];
}

// ---------------------------------------------------------------------------
// mconvF_k: final k3 conv as MFMA, 512 threads / 8 waves (unchanged).
// ---------------------------------------------------------------------------
__global__ __launch_bounds__(512) void mconvF_k(
    const float* __restrict__ in, float* __restrict__ out,
    const unsigned short* __restrict__ afrag, const float* __restrict__ bias,
    const float* __restrict__ stp, const float* __restrict__ gp,
    const float* __restrict__ btp, float inv_n,
    unsigned short* __restrict__ xtout)
{
    __shared__ unsigned short Xh[130 * 64], Xl[130 * 64];
    __shared__ float scs[NC], shs[NC];

    const int b = blockIdx.y, l0 = blockIdx.x * 128, tid = threadIdx.x;
    const int lane = tid & 63, wid = tid >> 6;
    const int wo = wid >> 2, wl = (wid & 3) * 32;
    const int r15 = lane & 15, g = lane >> 4;

    for (int c = tid; c < NC; c += 512) {
        float m  = stp[c] * inv_n;
        float va = stp[NC + c] * inv_n - m * m;
        float sc = gp[c] * rsqrtf(va + 1e-5f);
        scs[c] = sc;
        shs[c] = btp[c] - m * sc;
    }

    f32x4 acc[4][2];
#pragma unroll
    for (int i = 0; i < 4; i++)
#pragma unroll
        for (int j = 0; j < 2; j++) acc[i][j] = (f32x4)(0.f);

    for (int cc = 0; cc < 2; cc++) {
        __syncthreads();
        {
            int r = tid & 127;
            int l = l0 - 1 + r;
            for (int c0 = (tid >> 7); c0 < 64; c0 += 4) {
                int c = cc * 64 + c0;
                float v = 0.f;
                if (l >= 0 && l < LFULL) {
                    v = in[((size_t)b * NC + c) * LFULL + l];
                    v = lrelu(v * scs[c] + shs[c]);
                }
                unsigned hi = bf16r(v);
                unsigned lo = bf16r(v - __uint_as_float(hi << 16));
                unsigned bo = ((unsigned)(r * 128 + c0 * 2)) ^ (((unsigned)(r & 7)) << 4);
                *(unsigned short*)((char*)Xh + bo) = (unsigned short)hi;
                *(unsigned short*)((char*)Xl + bo) = (unsigned short)lo;
            }
            if (tid < 128) {
                int r2 = 128 + (tid >> 6);
                int l2 = l0 - 1 + r2;
                int c0 = tid & 63;
                int c = cc * 64 + c0;
                float v = 0.f;
                if (l2 >= 0 && l2 < LFULL) {
                    v = in[((size_t)b * NC + c) * LFULL + l2];
                    v = lrelu(v * scs[c] + shs[c]);
                }
                unsigned hi = bf16r(v);
                unsigned lo = bf16r(v - __uint_as_float(hi << 16));
                unsigned bo = ((unsigned)(r2 * 128 + c0 * 2)) ^ (((unsigned)(r2 & 7)) << 4);
                *(unsigned short*)((char*)Xh + bo) = (unsigned short)hi;
                *(unsigned short*)((char*)Xl + bo) = (unsigned short)lo;
            }
        }
        __syncthreads();
#pragma unroll
        for (int tap = 0; tap < 3; tap++) {
#pragma unroll
            for (int combo = 0; combo < 3; combo++) {
                const int ah = (combo == 2) ? 1 : 0;
                const unsigned short* Xs = (combo == 1) ? Xl : Xh;
                bf16x8 af[8];
#pragma unroll
                for (int ks = 0; ks < 2; ks++)
#pragma unroll
                    for (int f = 0; f < 4; f++) {
                        int rec = 3072 + ((((tap * 2 + ah) * 2 + wo) * 2 + cc) * 2 + ks) * 4 + f;
                        af[ks * 4 + f] = *(const bf16x8*)(afrag + (size_t)rec * 512 + lane * 8);
                    }
#pragma unroll
                for (int ks = 0; ks < 2; ks++) {
                    bf16x8 bf_[2];
#pragma unroll
                    for (int j = 0; j < 2; j++) {
                        int row = wl + j * 16 + r15 + tap;
                        unsigned bo = ((unsigned)(row * 128 + ks * 64 + g * 16))
                                    ^ (((unsigned)(row & 7)) << 4);
                        bf_[j] = *(const bf16x8*)((const char*)Xs + bo);
                    }
#pragma unroll
                    for (int i = 0; i < 4; i++)
#pragma unroll
                        for (int j = 0; j < 2; j++)
                            acc[i][j] = __builtin_amdgcn_mfma_f32_16x16x32_bf16(
                                af[ks * 4 + i], bf_[j], acc[i][j], 0, 0, 0);
                }
            }
        }
    }

#pragma unroll
    for (int i = 0; i < 4; i++) {
#pragma unroll
        for (int r = 0; r < 4; r++) {
            const int o = wo * 64 + i * 16 + g * 4 + r;
            const float bv = bias[o];
#pragma unroll
            for (int j = 0; j < 2; j++) {
                float v = acc[i][j][r] + bv;
                int l = l0 + wl + j * 16 + r15;
                out[((size_t)b * NC + o) * LFULL + l] = v;
                xtout[((size_t)b * LFULL + l) * NC + o] = (unsigned short)bf16r(v);
            }
        }
    }
}

// ---------------------------------------------------------------------------
// conv7: VALU conv for the dn stack, swizzled x tile (unchanged from R15).
// ---------------------------------------------------------------------------
template<int KW, int STRIDE, int PAD, bool UPS, int INMODE, bool OUTACT, bool STATS, int TT, bool XPOSE>
__global__ __launch_bounds__(256) void conv7_k(
    const float* __restrict__ in, float* __restrict__ out,
    const float* __restrict__ wp, const float* __restrict__ bias,
    const float* __restrict__ stp, const float* __restrict__ gp,
    const float* __restrict__ btp, float inv_n,
    float* __restrict__ stats, unsigned short* __restrict__ xtout,
    int L_in, int L_out)
{
    constexpr int CC    = (KW == 7) ? 8 : 16;
    constexpr int PT    = 64 * TT;
    constexpr int TTO   = UPS ? 2 * TT : TT;
    constexpr int NWR   = UPS ? 4 : KW;
    constexpr int SPAN  = UPS ? (PT + 2) : ((PT - 1) * STRIDE + KW);
    constexpr int NCH   = (SPAN + 3) / 4;
    constexpr int NCH8  = (NCH + 7) & ~7;
    constexpr int XROW  = 4 * NCH8 + 4;
    constexpr int NLD   = (CC * NCH + 255) / 256;
    constexpr int XSPAN = UPS ? (TT + 2) : ((TT - 1) * STRIDE + KW);
    constexpr int STEP  = UPS ? TT : TT * STRIDE;
    constexpr int NWQ   = CC * NWR * 8;
    static_assert((STEP & 3) == 0, "conv7 swizzle path requires STEP%4==0");

    __shared__ float xs[CC][XROW];
    __shared__ float wls[CC * NWR * 32];
    __shared__ float scs[NC], shs[NC];

    const int b = blockIdx.z, ocb = blockIdx.y, tid = threadIdx.x;
    const int t0 = blockIdx.x * PT, lane = tid & 63;
    const int wid = tid >> 6;
    const int oc0 = ocb * 32 + wid * 8;
    const int gb = UPS ? (t0 - 1) : (t0 * STRIDE - PAD);

    if (INMODE > 0) {
        for (int c = tid; c < NC; c += 256) {
            float m  = stp[c] * inv_n;
            float va = stp[NC + c] * inv_n - m * m;
            float sc = gp[c] * rsqrtf(va + 1e-5f);
            scs[c] = sc;
            shs[c] = btp[c] - m * sc;
        }
        __syncthreads();
    }

    float acc[8][TTO];
#pragma unroll
    for (int i = 0; i < 8; i++)
#pragma unroll
        for (int j = 0; j < TTO; j++) acc[i][j] = 0.f;

    float pre[NLD][4];

#define C7_STAGEW(CCBASE) do {                                              \
    for (int _u = tid; _u < NWQ; _u += 256) {                               \
        int _row = _u >> 3, _g8 = _u & 7;                                   \
        int _cl = _row / NWR, _t = _row % NWR;                              \
        ((float4*)wls)[_u] = *(const float4*)(wp +                          \
            ((size_t)((CCBASE) + _cl) * NWR + _t) * 128 + ocb * 32 + _g8 * 4); \
    }                                                                       \
} while (0)

#define C7_COMPCI(CI) do {                                                  \
    float _q[XSPAN];                                                        \
    const int _qb4 = lane * (STEP / 4);                                     \
    _Pragma("unroll")                                                       \
    for (int _u = 0; _u < XSPAN / 4; _u++) {                                \
        float4 _v = *(const float4*)&xs[CI][4 * swz4(_qb4 + _u)];           \
        _q[4*_u] = _v.x; _q[4*_u+1] = _v.y;                                 \
        _q[4*_u+2] = _v.z; _q[4*_u+3] = _v.w;                               \
    }                                                                       \
    if constexpr ((XSPAN & 3) != 0) {                                       \
        const int _pt = swz4(_qb4 + XSPAN / 4);                             \
        if constexpr ((XSPAN & 3) >= 2) {                                   \
            float2 _v = *(const float2*)&xs[CI][4 * _pt];                   \
            _q[(XSPAN & ~3)] = _v.x; _q[(XSPAN & ~3) + 1] = _v.y;           \
        }                                                                   \
        if constexpr ((XSPAN & 3) == 1)                                     \
            _q[XSPAN - 1] = xs[CI][4 * _pt];                                \
        else if constexpr ((XSPAN & 3) == 3)                                \
            _q[XSPAN - 1] = xs[CI][4 * _pt + 2];                            \
    }                                                                       \
    {                                                                       \
        _Pragma("unroll")                                                   \
        for (int _k = 0; _k < KW; _k++) {                                   \
            const float4 _w0 = *(const float4*)&wls[((CI) * NWR + _k) * 32 + wid * 8];     \
            const float4 _w1 = *(const float4*)&wls[((CI) * NWR + _k) * 32 + wid * 8 + 4]; \
            _Pragma("unroll")                                               \
            for (int _i = 0; _i < 8; _i++) {                                \
                float _wv = f4c(_i < 4 ? _w0 : _w1, _i & 3);                \
                _Pragma("unroll")                                           \
                for (int _j = 0; _j < TT; _j++)                             \
                    acc[_i][_j] = fmaf(_wv, _q[_j * STRIDE + _k], acc[_i][_j]); \
            }                                                               \
        }                                                                   \
    }                                                                       \
} while (0)

#pragma unroll
    for (int u = 0; u < NLD; u++) {
        int idx = tid + u * 256;
        if (idx < CC * NCH) {
            int cl = idx / NCH, q = idx - cl * NCH;
            loadg4(in + ((size_t)b * NC + cl) * L_in, gb + 4 * q, L_in, pre[u]);
        }
    }
#pragma unroll
    for (int u = 0; u < NLD; u++) {
        int idx = tid + u * 256;
        if (idx < CC * NCH) {
            int cl = idx / NCH, q = idx - cl * NCH;
            int g0 = gb + 4 * q;
            float e[4];
#pragma unroll
            for (int t = 0; t < 4; t++) {
                float v = pre[u][t];
                if (INMODE > 0) {
                    int gg = g0 + t;
                    if (gg >= 0 && gg < L_in) {
                        float s = v * scs[cl] + shs[cl];
                        v = (INMODE == 2) ? lrelu(s) : s;
                    }
                }
                e[t] = v;
            }
            *(float4*)&xs[cl][4 * swz4(q)] = make_float4(e[0], e[1], e[2], e[3]);
        }
    }
    C7_STAGEW(0);
    __syncthreads();

    for (int cc = 0; cc < NC; cc += CC) {
        if (cc + CC < NC) {
#pragma unroll
            for (int u = 0; u < NLD; u++) {
                int idx = tid + u * 256;
                if (idx < CC * NCH) {
                    int cl = idx / NCH, q = idx - cl * NCH;
                    loadg4(in + ((size_t)b * NC + cc + CC + cl) * L_in,
                           gb + 4 * q, L_in, pre[u]);
                }
            }
        }
#pragma unroll
        for (int ci = 0; ci < CC; ci++) {
            C7_COMPCI(ci);
        }
        __syncthreads();
        if (cc + CC < NC) {
#pragma unroll
            for (int u = 0; u < NLD; u++) {
                int idx = tid + u * 256;
                if (idx < CC * NCH) {
                    int cl = idx / NCH, q = idx - cl * NCH;
                    int g0 = gb + 4 * q;
                    int c = cc + CC + cl;
                    float e[4];
#pragma unroll
                    for (int t = 0; t < 4; t++) {
                        float v = pre[u][t];
                        if (INMODE > 0) {
                            int gg = g0 + t;
                            if (gg >= 0 && gg < L_in) {
                                float s = v * scs[c] + shs[c];
                                v = (INMODE == 2) ? lrelu(s) : s;
                            }
                        }
                        e[t] = v;
                    }
                    *(float4*)&xs[cl][4 * swz4(q)] = make_float4(e[0], e[1], e[2], e[3]);
                }
            }
            C7_STAGEW(cc + CC);
            __syncthreads();
        }
    }
#undef C7_STAGEW
#undef C7_COMPCI

    const int po = t0 + lane * TTO;
#pragma unroll
    for (int i = 0; i < 8; i++) {
        const int o = oc0 + i;
        const float bv = bias[o];
        float s1 = 0.f, s2 = 0.f;
        float tmpm[TTO];
#pragma unroll
        for (int j = 0; j < TTO; j++) {
            float v = acc[i][j] + bv;
            if (OUTACT) v = lrelu(v);
            tmpm[j] = v;
            if (STATS) { s1 += v; s2 += v * v; }
        }
        float* orow = out + ((size_t)b * NC + o) * L_out + po;
        if constexpr (TTO == 4)
            *(float4*)orow = make_float4(tmpm[0], tmpm[1], tmpm[2], tmpm[3]);
        else if constexpr (TTO == 2)
            *(float2*)orow = make_float2(tmpm[0], tmpm[1]);
        else
            orow[0] = tmpm[0];
        if (STATS) {
#pragma unroll
            for (int m = 1; m < 64; m <<= 1) {
                s1 += __shfl_xor(s1, m);
                s2 += __shfl_xor(s2, m);
            }
            if (lane == 0) {
                atomicAdd(&stats[o], s1);
                atomicAdd(&stats[NC + o], s2);
            }
        }
    }
}

// ---------------------------------------------------------------------------
__global__ __launch_bounds__(256) void cvtW_k(const float* __restrict__ W,
                                              unsigned short* __restrict__ Wbf)
{
    int i = blockIdx.x * 256 + threadIdx.x;
    const float4 a = *(const float4*)&W[i * 8];
    const float4 b = *(const float4*)&W[i * 8 + 4];
    unsigned pk[4];
    pk[0] = bf16r(a.x) | (bf16r(a.y) << 16);
    pk[1] = bf16r(a.z) | (bf16r(a.w) << 16);
    pk[2] = bf16r(b.x) | (bf16r(b.y) << 16);
    pk[3] = bf16r(b.z) | (bf16r(b.w) << 16);
    *(uint4*)&Wbf[i * 8] = make_uint4(pk[0], pk[1], pk[2], pk[3]);
}

// ---------------------------------------------------------------------------
// salM2: MFMA bf16 GEMM over (128h x 128l) tiles (unchanged).
// ---------------------------------------------------------------------------
template<int PHASE>
__global__ __launch_bounds__(256) void salM2_k(
    const unsigned short* __restrict__ xT, const unsigned short* __restrict__ Wbf,
    const float* __restrict__ bias, float* __restrict__ gsum,
    unsigned* __restrict__ ghist, const unsigned* __restrict__ thrv,
    unsigned* __restrict__ candcnt, unsigned* __restrict__ candI)
{
    __shared__ unsigned short Als[128 * 128];
    __shared__ unsigned short Bls[128 * 128];

    const int b  = blockIdx.z;
    const int h0 = blockIdx.y * 128;
    const int l0 = blockIdx.x * 128;
    const int tid = threadIdx.x;
    const int lane = tid & 63;
    const int wid = tid >> 6;
    const int wh = (wid >> 1) * 64;
    const int wl = (wid & 1) * 64;

    {
        const uint4* gA = (const uint4*)(Wbf + (size_t)h0 * NC);
        const uint4* gB = (const uint4*)(xT + ((size_t)b * LFULL + l0) * NC);
        char* cA = (char*)Als; char* cB = (char*)Bls;
        for (int i = tid; i < 2048; i += 256) {
            int row = i >> 4, q = i & 15;
            unsigned sw = (unsigned)(row * 256 + q * 16) ^ (((unsigned)(row & 7)) << 4);
            *(uint4*)(cA + sw) = gA[i];
        }
        for (int i = tid; i < 2048; i += 256) {
            int row = i >> 4, q = i & 15;
            unsigned sw = (unsigned)(row * 256 + q * 16) ^ (((unsigned)(row & 7)) << 4);
            *(uint4*)(cB + sw) = gB[i];
        }
    }
    __syncthreads();

    f32x4 acc[4][4];
#pragma unroll
    for (int i = 0; i < 4; i++)
#pragma unroll
        for (int j = 0; j < 4; j++) acc[i][j] = (f32x4)(0.f);

    const int r15 = lane & 15, g = lane >> 4;
#pragma unroll
    for (int ks = 0; ks < 4; ks++) {
        bf16x8 af[4], bfv[4];
#pragma unroll
        for (int f = 0; f < 4; f++) {
            int rowA = wh + f * 16 + r15;
            unsigned offA = (unsigned)(rowA * 256 + ks * 64 + g * 16)
                          ^ (((unsigned)(rowA & 7)) << 4);
            af[f] = *(const bf16x8*)((const char*)Als + offA);
            int rowB = wl + f * 16 + r15;
            unsigned offB = (unsigned)(rowB * 256 + ks * 64 + g * 16)
                          ^ (((unsigned)(rowB & 7)) << 4);
            bfv[f] = *(const bf16x8*)((const char*)Bls + offB);
        }
#pragma unroll
        for (int i = 0; i < 4; i++)
#pragma unroll
            for (int j = 0; j < 4; j++)
                acc[i][j] = __builtin_amdgcn_mfma_f32_16x16x32_bf16(
                    af[i], bfv[j], acc[i][j], 0, 0, 0);
    }

    if constexpr (PHASE == 0) {
        __syncthreads();
        unsigned* lhist = (unsigned*)Als;
        for (int i = tid; i < 8192; i += 256) lhist[i] = 0;
        __syncthreads();
        unsigned* myh = lhist + (tid & 1) * 4096;
        float expsum = 0.f;
#pragma unroll
        for (int i = 0; i < 4; i++) {
#pragma unroll
            for (int r = 0; r < 4; r++) {
                const int h = h0 + wh + i * 16 + g * 4 + r;
                const float bv = bias[h];
#pragma unroll
                for (int j = 0; j < 4; j++) {
                    float v = acc[i][j][r] + bv;
                    expsum += expf(v);
                    atomicAdd(&myh[monoKey16(bf16r(v)) >> 4], 1u);
                }
            }
        }
#pragma unroll
        for (int m = 1; m < 64; m <<= 1) expsum += __shfl_xor(expsum, m);
        float* red = (float*)Bls;
        if (lane == 0) red[wid] = expsum;
        __syncthreads();
        for (int i = tid; i < 4096; i += 256) {
            unsigned s = lhist[i] + lhist[4096 + i];
            if (s) atomicAdd(&ghist[b * 4096 + i], s);
        }
        if (tid == 0) atomicAdd(&gsum[b], red[0] + red[1] + red[2] + red[3]);
    } else {
        const unsigned thr = thrv[b * 2];
#pragma unroll
        for (int i = 0; i < 4; i++) {
#pragma unroll
            for (int r = 0; r < 4; r++) {
                const int h = h0 + wh + i * 16 + g * 4 + r;
                const float bv = bias[h];
#pragma unroll
                for (int j = 0; j < 4; j++) {
                    float v = acc[i][j][r] + bv;
                    bool pr = monoKey16(bf16r(v)) >= thr;
                    unsigned long long m = __ballot(pr);
                    if (m) {
                        int leader = __ffsll((unsigned long long)m) - 1;
                        int cnt = __popcll(m);
                        unsigned basepos = 0;
                        if (lane == leader)
                            basepos = atomicAdd(&candcnt[b], (unsigned)cnt);
                        basepos = __shfl(basepos, leader);
                        if (pr) {
                            int rr = __popcll(m & ((1ull << lane) - 1ull));
                            unsigned pos = basepos + (unsigned)rr;
                            if (pos < CAP) {
                                int l = l0 + wl + j * 16 + r15;
                                candI[b * CAP + pos] = (unsigned)((h << 13) | l);
                            }
                        }
                    }
                }
            }
        }
    }
}

// ---------------------------------------------------------------------------
__global__ __launch_bounds__(256) void scan2_k(
    const unsigned* __restrict__ ghist, unsigned* __restrict__ thrv)
{
    const int b = blockIdx.x, tid = threadIdx.x;
    __shared__ unsigned part[256];
    unsigned s = 0;
#pragma unroll
    for (int i = 0; i < 16; i++) s += ghist[b * 4096 + tid * 16 + i];
    part[tid] = s;
    __syncthreads();
    if (tid == 0) {
        unsigned cum = 0; int ch;
        for (ch = 255; ch >= 0; ch--) {
            if (cum + part[ch] >= KSEL) break;
            cum += part[ch];
        }
        int bin = 0;
        if (ch >= 0) {
            for (bin = ch * 16 + 15; bin > ch * 16; bin--) {
                unsigned c = ghist[b * 4096 + bin];
                if (cum + c >= KSEL) break;
                cum += c;
            }
        }
        int bcol = bin > 0 ? bin - 1 : 0;
        thrv[b * 2] = (unsigned)bcol << 4;
    }
}

__global__ __launch_bounds__(128) void recompute_k(
    const unsigned* __restrict__ candcnt, const unsigned* __restrict__ candI,
    const float* __restrict__ xu, const float* __restrict__ W,
    const float* __restrict__ bias, unsigned* __restrict__ candK)
{
    const int b = blockIdx.y;
    const unsigned cnt = min(candcnt[b], (unsigned)CAP);
    const int t = threadIdx.x;
    __shared__ float wsum[2];
    for (unsigned k = blockIdx.x; k < cnt; k += 1024) {
        unsigned e = candI[b * CAP + k];
        int h = e >> 13, l = e & 8191;
        float prod = W[h * NC + t] * xu[(b * NC + t) * LFULL + l];
#pragma unroll
        for (int m = 1; m < 64; m <<= 1) prod += __shfl_xor(prod, m);
        if ((t & 63) == 0) wsum[t >> 6] = prod;
        __syncthreads();
        if (t == 0) candK[b * CAP + k] = monoKey(wsum[0] + wsum[1] + bias[h]);
        __syncthreads();
    }
}

__global__ __launch_bounds__(256) void select2_k(
    const unsigned* __restrict__ candcnt, const unsigned* __restrict__ candK,
    const unsigned* __restrict__ candI,
    uint2* __restrict__ selected, unsigned* __restrict__ selcnt)
{
    const int b = blockIdx.x, tid = threadIdx.x;
    __shared__ unsigned h1[4096];
    __shared__ unsigned l2k[2048], l2i[2048];
    __shared__ unsigned part[256];
    __shared__ unsigned sh[8];

    const unsigned Nc = min(candcnt[b], (unsigned)CAP);
    const unsigned* kk = candK + b * CAP;
    const unsigned* ii = candI + b * CAP;
    uint2* sel = selected + b * KSEL;

    for (int i = tid; i < 4096; i += 256) h1[i] = 0;
    if (tid < 8) sh[tid] = 0;
    __syncthreads();
    for (unsigned i = tid; i < Nc; i += 256) atomicAdd(&h1[kk[i] >> 20], 1u);
    __syncthreads();
    {
        unsigned s = 0;
#pragma unroll
        for (int i = 0; i < 16; i++) s += h1[tid * 16 + i];
        part[tid] = s;
        __syncthreads();
        if (tid == 0) {
            unsigned cum = 0; int ch;
            for (ch = 255; ch >= 0; ch--) { if (cum + part[ch] >= KSEL) break; cum += part[ch]; }
            int bin = 0;
            if (ch >= 0)
                for (bin = ch * 16 + 15; bin > ch * 16; bin--) {
                    unsigned c = h1[bin];
                    if (cum + c >= KSEL) break;
                    cum += c;
                }
            sh[2] = (unsigned)bin; sh[3] = KSEL - cum;
        }
    }
    __syncthreads();
    const unsigned b1 = sh[2], need1 = sh[3];
    for (int i = tid; i < 1024; i += 256) h1[i] = 0;
    __syncthreads();
    for (unsigned i = tid; i < Nc; i += 256) {
        unsigned k = kk[i], bin = k >> 20;
        if (bin > b1) {
            unsigned p = atomicAdd(&sh[0], 1u);
            if (p < KSEL) sel[p] = make_uint2(k, ii[i]);
        } else if (bin == b1) {
            atomicAdd(&h1[(k >> 10) & 1023], 1u);
        }
    }
    __syncthreads();
    {
        unsigned s = 0;
#pragma unroll
        for (int i = 0; i < 4; i++) s += h1[tid * 4 + i];
        part[tid] = s;
        __syncthreads();
        if (tid == 0) {
            unsigned cum = 0; int ch;
            for (ch = 255; ch >= 0; ch--) { if (cum + part[ch] >= need1) break; cum += part[ch]; }
            int bin = 0;
            if (ch >= 0)
                for (bin = ch * 4 + 3; bin > ch * 4; bin--) {
                    unsigned c = h1[bin];
                    if (cum + c >= need1) break;
                    cum += c;
                }
            sh[4] = (unsigned)bin; sh[5] = need1 - cum;
        }
    }
    __syncthreads();
    const unsigned b2 = sh[4], need2 = sh[5];
    for (int i = tid; i < 1024; i += 256) h1[i] = 0;
    __syncthreads();
    for (unsigned i = tid; i < Nc; i += 256) {
        unsigned k = kk[i];
        if ((k >> 20) != b1) continue;
        unsigned mb = (k >> 10) & 1023;
        if (mb > b2) {
            unsigned p = atomicAdd(&sh[0], 1u);
            if (p < KSEL) sel[p] = make_uint2(k, ii[i]);
        } else if (mb == b2) {
            unsigned j = atomicAdd(&sh[1], 1u);
            if (j < 2048) { l2k[j] = k; l2i[j] = ii[i]; atomicAdd(&h1[k & 1023], 1u); }
        }
    }
    __syncthreads();
    const unsigned m2 = min(sh[1], 2048u);
    {
        unsigned s = 0;
#pragma unroll
        for (int i = 0; i < 4; i++) s += h1[tid * 4 + i];
        part[tid] = s;
        __syncthreads();
        if (tid == 0) {
            unsigned cum = 0; int ch;
            for (ch = 255; ch >= 0; ch--) { if (cum + part[ch] >= need2) break; cum += part[ch]; }
            int bin = 0;
            if (ch >= 0)
                for (bin = ch * 4 + 3; bin > ch * 4; bin--) {
                    unsigned c = h1[bin];
                    if (cum + c >= need2) break;
                    cum += c;
                }
            sh[6] = (unsigned)bin; sh[7] = need2 - cum;
        }
    }
    __syncthreads();
    const unsigned b3 = sh[6], need3 = sh[7];
    if (tid == 0) sh[1] = 0;
    __syncthreads();
    for (unsigned i = tid; i < m2; i += 256) {
        unsigned k = l2k[i], lb = k & 1023;
        if (lb > b3) {
            unsigned p = atomicAdd(&sh[0], 1u);
            if (p < KSEL) sel[p] = make_uint2(k, l2i[i]);
        } else if (lb == b3) {
            unsigned t = atomicAdd(&sh[1], 1u);
            if (t < need3) {
                unsigned p = atomicAdd(&sh[0], 1u);
                if (p < KSEL) sel[p] = make_uint2(k, l2i[i]);
            }
        }
    }
    __syncthreads();
    if (tid == 0) selcnt[b] = min(sh[0], (unsigned)KSEL);
}

// ---------------------------------------------------------------------------
__global__ void inity_k(float* __restrict__ y, const float* __restrict__ bias)
{
    int i = blockIdx.x * 256 + threadIdx.x;
    float bv = bias[(i >> 11) & 127];
    ((float4*)y)[i] = make_float4(bv, bv, bv, bv);
}

__global__ __launch_bounds__(128) void scatter_k(
    const uint2* __restrict__ selected, const unsigned* __restrict__ selcnt,
    const float* __restrict__ gsum, const float* __restrict__ xu,
    const float* __restrict__ upw, const float* __restrict__ upb,
    const float* __restrict__ dww, float* __restrict__ y)
{
    const int b = blockIdx.y, kidx = blockIdx.x;
    if (kidx >= (int)selcnt[b]) return;
    const uint2 s = selected[b * KSEL + kidx];
    const float salv = keyToF(s.x);
    const unsigned idx = s.y;
    const int h = idx >> 13, l = idx & 8191;
    const int t = threadIdx.x;

    float prod = upw[h * NC + t] * xu[(b * NC + t) * LFULL + l];
#pragma unroll
    for (int m = 1; m < 64; m <<= 1) prod += __shfl_xor(prod, m);
    __shared__ float wsum[2];
    if ((t & 63) == 0) wsum[t >> 6] = prod;
    __syncthreads();
    const float sig = wsum[0] + wsum[1] + upb[h];
    const float val = expf(salv) / gsum[b];
    const float g = sig * val;
    atomicAdd(&y[(b * NC + t) * LFULL + l], dww[t * NH + h] * g);
}

__global__ void apply_k(const float* __restrict__ in, const float* __restrict__ stats,
                        const float* __restrict__ g, const float* __restrict__ bt,
                        float* __restrict__ out, float inv_n)
{
    int i = blockIdx.x * 256 + threadIdx.x;
    int c = (i >> 7) & 127;
    float m  = stats[c] * inv_n;
    float va = stats[NC + c] * inv_n - m * m;
    float sc = g[c] * rsqrtf(va + 1e-5f);
    out[i] = in[i] * sc + (bt[c] - m * sc);
}

// ---------------------------------------------------------------------------
extern "C" void kernel_launch(void* const* d_in, const int* in_sizes, int n_in,
                              void* d_out, int out_size, void* d_ws, size_t ws_size,
                              hipStream_t stream)
{
    const float* x        = (const float*)d_in[0];
    const float* up_w     = (const float*)d_in[1];
    const float* up_b     = (const float*)d_in[2];
    const float* up_g     = (const float*)d_in[3];
    const float* up_beta  = (const float*)d_in[4];
    const float* up_out_w = (const float*)d_in[5];
    const float* up_out_b = (const float*)d_in[6];
    const float* sb_up_w  = (const float*)d_in[7];
    const float* sb_up_b  = (const float*)d_in[8];
    const float* sal_w    = (const float*)d_in[9];
    const float* sal_b    = (const float*)d_in[10];
    const float* sb_dn_w  = (const float*)d_in[11];
    const float* sb_dn_b  = (const float*)d_in[12];
    const float* dn_w     = (const float*)d_in[13];
    const float* dn_b     = (const float*)d_in[14];
    const float* dn_g     = (const float*)d_in[15];
    const float* dn_beta  = (const float*)d_in[16];

    char* ws = (char*)d_ws;
    float*          stats    = (float*)(ws + 0);
    float*          gsum     = (float*)(ws + 16384);
    unsigned*       thrv     = (unsigned*)(ws + 16416);
    unsigned*       candcnt  = (unsigned*)(ws + 16480);
    unsigned*       selcnt   = (unsigned*)(ws + 16512);
    uint2*          selected = (uint2*)(ws + 16640);
    unsigned*       ghist    = (unsigned*)(ws + 49408);
    unsigned*       candK    = (unsigned*)(ws + 180480);
    unsigned*       candI    = (unsigned*)(ws + 1229056);
    unsigned short* Wbf      = (unsigned short*)(ws + 2277632);
    float*          wprep    = (float*)(ws + 2539776);
    float*          B0       = (float*)(ws + 5685504);
    float*          B1       = (float*)(ws + 39239936);
    unsigned short* xT       = (unsigned short*)(ws + 72794368);
    float*          y        = (float*)(ws + 72794368);
    unsigned short* Afrag    = (unsigned short*)(ws + 117440512);
    float*          partial  = (float*)(ws + 121634816);

    hipMemsetAsync(d_ws, 0, 16544, stream);
    hipMemsetAsync(ws + 49408, 0, 131072, stream);

    cvtW_k<<<64,256,0,stream>>>(sal_w, Wbf);
    prep_k<<<3072,256,0,stream>>>(up_w, up_out_w, dn_w, wprep);
    prepA_k<<<864,256,0,stream>>>(up_w, up_out_w, Afrag);

    // ---- ConvUpsample (MFMA, 8-wave blocks): 128 -> 8192 frames ----
    mconvU_k<0><<<dim3(2,NB),512,0,stream>>>(
        x, B0, Afrag, up_b, nullptr, nullptr, nullptr, 0.f, partial, 128);
    redstats_k<<<16,256,0,stream>>>(partial, 2*NB, stats);
    mconvU_k<2><<<dim3(4,NB),512,0,stream>>>(
        B0, B1, Afrag + 1*262144, up_b + NC,
        stats, up_g, up_beta, 1.f/(float)(NB*256), partial, 256);
    redstats_k<<<16,256,0,stream>>>(partial, 4*NB, stats + 256);
    mconvU_k<2><<<dim3(8,NB),512,0,stream>>>(
        B1, B0, Afrag + 2*262144, up_b + 2*NC,
        stats + 256, up_g + NC, up_beta + NC, 1.f/(float)(NB*512), partial, 512);
    redstats_k<<<16,256,0,stream>>>(partial, 8*NB, stats + 2*256);
    mconvU_k<2><<<dim3(16,NB),512,0,stream>>>(
        B0, B1, Afrag + 3*262144, up_b + 3*NC,
        stats + 2*256, up_g + 2*NC, up_beta + 2*NC, 1.f/(float)(NB*1024), partial, 1024);
    redstats_k<<<16,256,0,stream>>>(partial, 16*NB, stats + 3*256);
    mconvU_k<2><<<dim3(32,NB),512,0,stream>>>(
        B1, B0, Afrag + 4*262144, up_b + 4*NC,
        stats + 3*256, up_g + 3*NC, up_beta + 3*NC, 1.f/(float)(NB*2048), partial, 2048);
    redstats_k<<<16,256,0,stream>>>(partial, 32*NB, stats + 4*256);
    mconvU_k<2><<<dim3(64,NB),512,0,stream>>>(
        B0, B1, Afrag + 5*262144, up_b + 5*NC,
        stats + 4*256, up_g + 4*NC, up_beta + 4*NC, 1.f/(float)(NB*4096), partial, 4096);
    redstats_k<<<16,256,0,stream>>>(partial, 64*NB, stats + 5*256);
    // final k3 conv (MFMA): B1 -> B0 (f32 x_up) + xT (bf16 transposed)
    mconvF_k<<<dim3(64,NB),512,0,stream>>>(
        B1, B0, Afrag, up_out_b,
        stats + 5*256, up_g + 5*NC, up_beta + 5*NC, 1.f/(float)(NB*LFULL), xT);

    // ---- SparseBottleneck ----
    salM2_k<0><<<dim3(64,8,NB),256,0,stream>>>(xT, Wbf, sal_b, gsum, ghist,
                                               nullptr, nullptr, nullptr);
    scan2_k<<<NB,256,0,stream>>>(ghist, thrv);
    salM2_k<1><<<dim3(64,8,NB),256,0,stream>>>(xT, Wbf, sal_b, nullptr, nullptr,
                                               thrv, candcnt, candI);
    recompute_k<<<dim3(1024,NB),128,0,stream>>>(candcnt, candI, B0, sal_w, sal_b, candK);
    select2_k<<<NB,256,0,stream>>>(candcnt, candK, candI, selected, selcnt);
    inity_k<<<(NB*NC*LFULL/4)/256,256,0,stream>>>(y, sb_dn_b);
    scatter_k<<<dim3(KSEL,NB),128,0,stream>>>(selected, selcnt, gsum, B0,
                                              sb_up_w, sb_up_b, sb_dn_w, y);

    // ---- down stack (VALU, swizzled): 8192 -> 128 ----
    conv7_k<7,4,3,false,0,true,true,2,false><<<dim3(16,4,NB),256,0,stream>>>(
        y, B1, wprep + 442368, dn_b, nullptr, nullptr, nullptr, 0.f,
        stats + 6*256, nullptr, 8192, 2048);
    conv7_k<7,4,3,false,1,true,true,2,false><<<dim3(4,4,NB),256,0,stream>>>(
        B1, B0, wprep + 442368 + 114688, dn_b + NC,
        stats + 6*256, dn_g, dn_beta, 1.f/(float)(NB*2048),
        stats + 7*256, nullptr, 2048, 512);
    conv7_k<7,4,3,false,1,true,true,1,false><<<dim3(2,4,NB),256,0,stream>>>(
        B0, B1, wprep + 442368 + 2*114688, dn_b + 2*NC,
        stats + 7*256, dn_g + NC, dn_beta + NC, 1.f/(float)(NB*512),
        stats + 8*256, nullptr, 512, 128);

    apply_k<<<(out_size + 255)/256,256,0,stream>>>(
        B1, stats + 8*256, dn_g + 2*NC, dn_beta + 2*NC, (float*)d_out,
        1.f/(float)(NB*128));
}

// Round 17
// 701.135 us; speedup vs baseline: 1.4385x; 1.0576x over previous
//
#include <hip/hip_runtime.h>
#include <hip/hip_bf16.h>

// ---------------------------------------------------------------------------
// ExpandAndContractBottleneck.  R17: conv7 gains an OCW (oc-per-wave) template
// param; dn stack runs at OCW=4 (16-oc blocks) to double grid/occupancy
// (dn0 1024 blocks = 4/CU vs 512 = 2/CU).  Everything else = R16.
// ---------------------------------------------------------------------------

#define DEV_INLINE __device__ __forceinline__

constexpr int NB   = 8;
constexpr int NC   = 128;
constexpr int NH   = 1024;
constexpr int LFULL= 8192;
constexpr int KSEL = 512;
constexpr int CAP  = 32768;

typedef __attribute__((ext_vector_type(4))) float f32x4;
typedef __attribute__((ext_vector_type(8))) short bf16x8;

DEV_INLINE unsigned monoKey(float f) {
    unsigned u = __float_as_uint(f);
    return (u & 0x80000000u) ? ~u : (u | 0x80000000u);
}
DEV_INLINE float keyToF(unsigned k) {
    unsigned u = (k & 0x80000000u) ? (k ^ 0x80000000u) : ~k;
    return __uint_as_float(u);
}
DEV_INLINE unsigned monoKey16(unsigned u) {
    return (u & 0x8000u) ? ((~u) & 0xFFFFu) : (u | 0x8000u);
}
DEV_INLINE unsigned bf16r(float f) {
    unsigned u = __float_as_uint(f);
    return (u + 0x7FFFu + ((u >> 16) & 1u)) >> 16;
}
DEV_INLINE float lrelu(float v) { return v >= 0.f ? v : 0.2f * v; }
DEV_INLINE float f4c(const float4& v, int k) {
    return k == 0 ? v.x : k == 1 ? v.y : k == 2 ? v.z : v.w;
}
DEV_INLINE int swz4(int p) { return p ^ ((p >> 3) & 7); }

DEV_INLINE void loadg4(const float* __restrict__ rowp, int g0, int L, float* e) {
    if (g0 >= 0 && g0 + 4 <= L) {
        float4 v = *(const float4*)(rowp + g0);
        e[0] = v.x; e[1] = v.y; e[2] = v.z; e[3] = v.w;
    } else {
#pragma unroll
        for (int t = 0; t < 4; t++) {
            int g = g0 + t;
            e[t] = (g >= 0 && g < L) ? rowp[g] : 0.f;
        }
    }
}

// ---------------------------------------------------------------------------
// prep_k: VALU dn weights [c][tap][128 oc].
// ---------------------------------------------------------------------------
__global__ __launch_bounds__(256) void prep_k(
    const float* __restrict__ up_w, const float* __restrict__ up_out_w,
    const float* __restrict__ dn_w, float* __restrict__ wprep)
{
    int idx = blockIdx.x * 256 + threadIdx.x;
    if (idx < 393216) {
        int layer = idx >> 16;
        int r0 = idx & 65535;
        int c = r0 >> 9, r = (r0 >> 7) & 3, o = r0 & 127;
        const float* wsrc = up_w + ((size_t)layer * 128 + o) * 384 + c * 3;
        float w0 = wsrc[0], w1 = wsrc[1], w2 = wsrc[2];
        wprep[idx] = (r == 0) ? w0 : (r == 1) ? (w1 + w2) : (r == 2) ? (w0 + w1) : w2;
    } else if (idx < 442368) {
        int r0 = idx - 393216;
        int c = r0 / 384, k = (r0 / 128) % 3, o = r0 & 127;
        wprep[idx] = up_out_w[((size_t)o * 128 + c) * 3 + k];
    } else {
        int r0 = idx - 442368;
        int layer = r0 / 114688;
        int r1 = r0 - layer * 114688;
        int c = r1 / 896, k = (r1 / 128) % 7, o = r1 & 127;
        wprep[idx] = dn_w[((size_t)layer * 128 + o) * 896 + c * 7 + k];
    }
}

// ---------------------------------------------------------------------------
// prepA_k: MFMA A-operand fragment records (unchanged).
// ---------------------------------------------------------------------------
__global__ __launch_bounds__(256) void prepA_k(
    const float* __restrict__ up_w, const float* __restrict__ up_out_w,
    unsigned short* __restrict__ afrag)
{
    int idx = blockIdx.x * 256 + threadIdx.x;
    if (idx >= 221184) return;
    int rid = idx >> 6, lane = idx & 63;
    const int r15 = lane & 15, g = lane >> 4;
    unsigned short vals[8];
    if (rid < 3072) {
        int L  = rid >> 9;
        int r0 = rid & 511;
        int f = r0 & 3, ks = (r0 >> 2) & 1, cc = (r0 >> 3) & 1;
        int wo = (r0 >> 4) & 1, half = (r0 >> 5) & 1, ptap = (r0 >> 6) & 3;
        int o = wo * 64 + f * 16 + r15;
        int cb = cc * 64 + ks * 32 + g * 8;
#pragma unroll
        for (int e = 0; e < 8; e++) {
            const float* ws = up_w + (((size_t)L * 128 + o) * 128 + (cb + e)) * 3;
            float w0 = ws[0], w1 = ws[1], w2 = ws[2];
            float v = (ptap == 0) ? w0 : (ptap == 1) ? (w1 + w2)
                    : (ptap == 2) ? (w0 + w1) : w2;
            unsigned hi = bf16r(v);
            if (half == 0) vals[e] = (unsigned short)hi;
            else vals[e] = (unsigned short)bf16r(v - __uint_as_float(hi << 16));
        }
    } else {
        int r2 = rid - 3072;
        int f = r2 & 3, ks = (r2 >> 2) & 1, cc = (r2 >> 3) & 1;
        int wo = (r2 >> 4) & 1, half = (r2 >> 5) & 1, tap = r2 >> 6;
        int o = wo * 64 + f * 16 + r15;
        int cb = cc * 64 + ks * 32 + g * 8;
#pragma unroll
        for (int e = 0; e < 8; e++) {
            float v = up_out_w[((size_t)o * 128 + (cb + e)) * 3 + tap];
            unsigned hi = bf16r(v);
            if (half == 0) vals[e] = (unsigned short)hi;
            else vals[e] = (unsigned short)bf16r(v - __uint_as_float(hi << 16));
        }
    }
    unsigned pk[4];
#pragma unroll
    for (int q = 0; q < 4; q++)
        pk[q] = (unsigned)vals[2*q] | ((unsigned)vals[2*q+1] << 16);
    *(uint4*)(afrag + (size_t)rid * 512 + lane * 8) = make_uint4(pk[0], pk[1], pk[2], pk[3]);
}

// ---------------------------------------------------------------------------
// redstats_k: PARALLEL reduce of per-block partials (unchanged from R16).
// ---------------------------------------------------------------------------
__global__ __launch_bounds__(256) void redstats_k(
    const float* __restrict__ partial, int nb, float* __restrict__ stats)
{
    const int c = threadIdx.x;
    float s0 = 0.f, s1 = 0.f, s2 = 0.f, s3 = 0.f;
    for (int i = blockIdx.x * 4; i < nb; i += gridDim.x * 4) {
        s0 += partial[(size_t)(i + 0) * 256 + c];
        s1 += partial[(size_t)(i + 1) * 256 + c];
        s2 += partial[(size_t)(i + 2) * 256 + c];
        s3 += partial[(size_t)(i + 3) * 256 + c];
    }
    float s = (s0 + s1) + (s2 + s3);
    if (s != 0.f || blockIdx.x == 0) atomicAdd(&stats[c], s);
}

// ---------------------------------------------------------------------------
// mconvU_k: UPS MFMA conv, 512 threads / 8 waves (unchanged).
// ---------------------------------------------------------------------------
template<int INMODE>
__global__ __launch_bounds__(512) void mconvU_k(
    const float* __restrict__ in, float* __restrict__ out,
    const unsigned short* __restrict__ afrag, const float* __restrict__ bias,
    const float* __restrict__ stp, const float* __restrict__ gp,
    const float* __restrict__ btp, float inv_n,
    float* __restrict__ partial, int L_in)
{
    __shared__ unsigned short Xh[66 * 64], Xl[66 * 64];
    __shared__ float scs[NC], shs[NC];
    __shared__ float sstat[256];

    const int b = blockIdx.y, tile0 = blockIdx.x * 64, tid = threadIdx.x;
    const int lane = tid & 63, wid = tid >> 6;
    const int wo = wid >> 2, par = (wid >> 1) & 1, jh = wid & 1;
    const int r15 = lane & 15, g = lane >> 4;
    const int bid = b * gridDim.x + blockIdx.x;

    if (tid < 256) sstat[tid] = 0.f;
    if (INMODE > 0) {
        for (int c = tid; c < NC; c += 512) {
            float m  = stp[c] * inv_n;
            float va = stp[NC + c] * inv_n - m * m;
            float sc = gp[c] * rsqrtf(va + 1e-5f);
            scs[c] = sc;
            shs[c] = btp[c] - m * sc;
        }
    }

    f32x4 acc[4][2];
#pragma unroll
    for (int i = 0; i < 4; i++)
#pragma unroll
        for (int j = 0; j < 2; j++) acc[i][j] = (f32x4)(0.f);

    for (int cc = 0; cc < 2; cc++) {
        __syncthreads();
        {
            int r = tid & 63;
            int l = tile0 - 1 + r;
            for (int c0 = (tid >> 6); c0 < 64; c0 += 8) {
                int c = cc * 64 + c0;
                float v = 0.f;
                if (l >= 0 && l < L_in) {
                    v = in[((size_t)b * NC + c) * L_in + l];
                    if (INMODE > 0) v = lrelu(v * scs[c] + shs[c]);
                }
                unsigned hi = bf16r(v);
                unsigned lo = bf16r(v - __uint_as_float(hi << 16));
                unsigned bo = ((unsigned)(r * 128 + c0 * 2)) ^ (((unsigned)(r & 7)) << 4);
                *(unsigned short*)((char*)Xh + bo) = (unsigned short)hi;
                *(unsigned short*)((char*)Xl + bo) = (unsigned short)lo;
            }
            if (tid < 128) {
                int r2 = 64 + (tid >> 6);
                int l2 = tile0 - 1 + r2;
                int c0 = tid & 63;
                int c = cc * 64 + c0;
                float v = 0.f;
                if (l2 >= 0 && l2 < L_in) {
                    v = in[((size_t)b * NC + c) * L_in + l2];
                    if (INMODE > 0) v = lrelu(v * scs[c] + shs[c]);
                }
                unsigned hi = bf16r(v);
                unsigned lo = bf16r(v - __uint_as_float(hi << 16));
                unsigned bo = ((unsigned)(r2 * 128 + c0 * 2)) ^ (((unsigned)(r2 & 7)) << 4);
                *(unsigned short*)((char*)Xh + bo) = (unsigned short)hi;
                *(unsigned short*)((char*)Xl + bo) = (unsigned short)lo;
            }
        }
        __syncthreads();
#pragma unroll
        for (int pt = 0; pt < 2; pt++) {
            const int ptap = par * 2 + pt;
            const int roff = (ptap == 0) ? 0 : (ptap == 3) ? 2 : 1;
#pragma unroll
            for (int combo = 0; combo < 3; combo++) {
                const int ah = (combo == 2) ? 1 : 0;
                const unsigned short* Xs = (combo == 1) ? Xl : Xh;
                bf16x8 af[8];
#pragma unroll
                for (int ks = 0; ks < 2; ks++)
#pragma unroll
                    for (int f = 0; f < 4; f++) {
                        int rec = ((((ptap * 2 + ah) * 2 + wo) * 2 + cc) * 2 + ks) * 4 + f;
                        af[ks * 4 + f] = *(const bf16x8*)(afrag + (size_t)rec * 512 + lane * 8);
                    }
#pragma unroll
                for (int ks = 0; ks < 2; ks++) {
                    bf16x8 bf_[2];
#pragma unroll
                    for (int j = 0; j < 2; j++) {
                        int row = (jh * 2 + j) * 16 + r15 + roff;
                        unsigned bo = ((unsigned)(row * 128 + ks * 64 + g * 16))
                                    ^ (((unsigned)(row & 7)) << 4);
                        bf_[j] = *(const bf16x8*)((const char*)Xs + bo);
                    }
#pragma unroll
                    for (int i = 0; i < 4; i++)
#pragma unroll
                        for (int j = 0; j < 2; j++)
                            acc[i][j] = __builtin_amdgcn_mfma_f32_16x16x32_bf16(
                                af[ks * 4 + i], bf_[j], acc[i][j], 0, 0, 0);
                }
            }
        }
    }

    const int L_out = 2 * L_in;
#pragma unroll
    for (int i = 0; i < 4; i++) {
#pragma unroll
        for (int r = 0; r < 4; r++) {
            const int o = wo * 64 + i * 16 + g * 4 + r;
            const float bv = bias[o];
            float s1 = 0.f, s2 = 0.f;
#pragma unroll
            for (int j = 0; j < 2; j++) {
                float v = acc[i][j][r] + bv;
                int lout = 2 * (tile0 + (jh * 2 + j) * 16 + r15) + par;
                out[((size_t)b * NC + o) * L_out + lout] = v;
                s1 += v; s2 += v * v;
            }
#pragma unroll
            for (int m = 1; m < 16; m <<= 1) {
                s1 += __shfl_xor(s1, m);
                s2 += __shfl_xor(s2, m);
            }
            if (r15 == 0) {
                atomicAdd(&sstat[o], s1);
                atomicAdd(&sstat[NC + o], s2);
            }
        }
    }
    __syncthreads();
    if (tid < 256) partial[(size_t)bid * 256 + tid] = sstat[tid];
}

// ---------------------------------------------------------------------------
// mconvF_k: final k3 conv as MFMA, 512 threads / 8 waves (unchanged).
// ---------------------------------------------------------------------------
__global__ __launch_bounds__(512) void mconvF_k(
    const float* __restrict__ in, float* __restrict__ out,
    const unsigned short* __restrict__ afrag, const float* __restrict__ bias,
    const float* __restrict__ stp, const float* __restrict__ gp,
    const float* __restrict__ btp, float inv_n,
    unsigned short* __restrict__ xtout)
{
    __shared__ unsigned short Xh[130 * 64], Xl[130 * 64];
    __shared__ float scs[NC], shs[NC];

    const int b = blockIdx.y, l0 = blockIdx.x * 128, tid = threadIdx.x;
    const int lane = tid & 63, wid = tid >> 6;
    const int wo = wid >> 2, wl = (wid & 3) * 32;
    const int r15 = lane & 15, g = lane >> 4;

    for (int c = tid; c < NC; c += 512) {
        float m  = stp[c] * inv_n;
        float va = stp[NC + c] * inv_n - m * m;
        float sc = gp[c] * rsqrtf(va + 1e-5f);
        scs[c] = sc;
        shs[c] = btp[c] - m * sc;
    }

    f32x4 acc[4][2];
#pragma unroll
    for (int i = 0; i < 4; i++)
#pragma unroll
        for (int j = 0; j < 2; j++) acc[i][j] = (f32x4)(0.f);

    for (int cc = 0; cc < 2; cc++) {
        __syncthreads();
        {
            int r = tid & 127;
            int l = l0 - 1 + r;
            for (int c0 = (tid >> 7); c0 < 64; c0 += 4) {
                int c = cc * 64 + c0;
                float v = 0.f;
                if (l >= 0 && l < LFULL) {
                    v = in[((size_t)b * NC + c) * LFULL + l];
                    v = lrelu(v * scs[c] + shs[c]);
                }
                unsigned hi = bf16r(v);
                unsigned lo = bf16r(v - __uint_as_float(hi << 16));
                unsigned bo = ((unsigned)(r * 128 + c0 * 2)) ^ (((unsigned)(r & 7)) << 4);
                *(unsigned short*)((char*)Xh + bo) = (unsigned short)hi;
                *(unsigned short*)((char*)Xl + bo) = (unsigned short)lo;
            }
            if (tid < 128) {
                int r2 = 128 + (tid >> 6);
                int l2 = l0 - 1 + r2;
                int c0 = tid & 63;
                int c = cc * 64 + c0;
                float v = 0.f;
                if (l2 >= 0 && l2 < LFULL) {
                    v = in[((size_t)b * NC + c) * LFULL + l2];
                    v = lrelu(v * scs[c] + shs[c]);
                }
                unsigned hi = bf16r(v);
                unsigned lo = bf16r(v - __uint_as_float(hi << 16));
                unsigned bo = ((unsigned)(r2 * 128 + c0 * 2)) ^ (((unsigned)(r2 & 7)) << 4);
                *(unsigned short*)((char*)Xh + bo) = (unsigned short)hi;
                *(unsigned short*)((char*)Xl + bo) = (unsigned short)lo;
            }
        }
        __syncthreads();
#pragma unroll
        for (int tap = 0; tap < 3; tap++) {
#pragma unroll
            for (int combo = 0; combo < 3; combo++) {
                const int ah = (combo == 2) ? 1 : 0;
                const unsigned short* Xs = (combo == 1) ? Xl : Xh;
                bf16x8 af[8];
#pragma unroll
                for (int ks = 0; ks < 2; ks++)
#pragma unroll
                    for (int f = 0; f < 4; f++) {
                        int rec = 3072 + ((((tap * 2 + ah) * 2 + wo) * 2 + cc) * 2 + ks) * 4 + f;
                        af[ks * 4 + f] = *(const bf16x8*)(afrag + (size_t)rec * 512 + lane * 8);
                    }
#pragma unroll
                for (int ks = 0; ks < 2; ks++) {
                    bf16x8 bf_[2];
#pragma unroll
                    for (int j = 0; j < 2; j++) {
                        int row = wl + j * 16 + r15 + tap;
                        unsigned bo = ((unsigned)(row * 128 + ks * 64 + g * 16))
                                    ^ (((unsigned)(row & 7)) << 4);
                        bf_[j] = *(const bf16x8*)((const char*)Xs + bo);
                    }
#pragma unroll
                    for (int i = 0; i < 4; i++)
#pragma unroll
                        for (int j = 0; j < 2; j++)
                            acc[i][j] = __builtin_amdgcn_mfma_f32_16x16x32_bf16(
                                af[ks * 4 + i], bf_[j], acc[i][j], 0, 0, 0);
                }
            }
        }
    }

#pragma unroll
    for (int i = 0; i < 4; i++) {
#pragma unroll
        for (int r = 0; r < 4; r++) {
            const int o = wo * 64 + i * 16 + g * 4 + r;
            const float bv = bias[o];
#pragma unroll
            for (int j = 0; j < 2; j++) {
                float v = acc[i][j][r] + bv;
                int l = l0 + wl + j * 16 + r15;
                out[((size_t)b * NC + o) * LFULL + l] = v;
                xtout[((size_t)b * LFULL + l) * NC + o] = (unsigned short)bf16r(v);
            }
        }
    }
}

// ---------------------------------------------------------------------------
// conv7: VALU conv for the dn stack, swizzled x tile, OCW oc per wave.
// Block covers 4*OCW oc x PT t; grid.y = NC/(4*OCW).
// ---------------------------------------------------------------------------
template<int KW, int STRIDE, int PAD, bool UPS, int INMODE, bool OUTACT, bool STATS, int TT, bool XPOSE, int OCW>
__global__ __launch_bounds__(256) void conv7_k(
    const float* __restrict__ in, float* __restrict__ out,
    const float* __restrict__ wp, const float* __restrict__ bias,
    const float* __restrict__ stp, const float* __restrict__ gp,
    const float* __restrict__ btp, float inv_n,
    float* __restrict__ stats, unsigned short* __restrict__ xtout,
    int L_in, int L_out)
{
    constexpr int CC    = (KW == 7) ? 8 : 16;
    constexpr int PT    = 64 * TT;
    constexpr int TTO   = UPS ? 2 * TT : TT;
    constexpr int NWR   = UPS ? 4 : KW;
    constexpr int OCB   = 4 * OCW;
    constexpr int SPAN  = UPS ? (PT + 2) : ((PT - 1) * STRIDE + KW);
    constexpr int NCH   = (SPAN + 3) / 4;
    constexpr int NCH8  = (NCH + 7) & ~7;
    constexpr int XROW  = 4 * NCH8 + 4;
    constexpr int NLD   = (CC * NCH + 255) / 256;
    constexpr int XSPAN = UPS ? (TT + 2) : ((TT - 1) * STRIDE + KW);
    constexpr int STEP  = UPS ? TT : TT * STRIDE;
    constexpr int NWQ   = CC * NWR * (OCB / 4);   // float4 count per chunk
    static_assert((STEP & 3) == 0, "conv7 swizzle path requires STEP%4==0");
    static_assert(OCW == 4 || OCW == 8, "OCW must be 4 or 8");

    __shared__ float xs[CC][XROW];
    __shared__ float wls[CC * NWR * OCB];
    __shared__ float scs[NC], shs[NC];

    const int b = blockIdx.z, ocb = blockIdx.y, tid = threadIdx.x;
    const int t0 = blockIdx.x * PT, lane = tid & 63;
    const int wid = tid >> 6;
    const int oc0 = ocb * OCB + wid * OCW;
    const int gb = UPS ? (t0 - 1) : (t0 * STRIDE - PAD);

    if (INMODE > 0) {
        for (int c = tid; c < NC; c += 256) {
            float m  = stp[c] * inv_n;
            float va = stp[NC + c] * inv_n - m * m;
            float sc = gp[c] * rsqrtf(va + 1e-5f);
            scs[c] = sc;
            shs[c] = btp[c] - m * sc;
        }
        __syncthreads();
    }

    float acc[OCW][TTO];
#pragma unroll
    for (int i = 0; i < OCW; i++)
#pragma unroll
        for (int j = 0; j < TTO; j++) acc[i][j] = 0.f;

    float pre[NLD][4];

#define C7_STAGEW(CCBASE) do {                                              \
    for (int _u = tid; _u < NWQ; _u += 256) {                               \
        int _row = _u / (OCB / 4), _g8 = _u % (OCB / 4);                    \
        int _cl = _row / NWR, _t = _row % NWR;                              \
        ((float4*)wls)[_u] = *(const float4*)(wp +                          \
            ((size_t)((CCBASE) + _cl) * NWR + _t) * 128 + ocb * OCB + _g8 * 4); \
    }                                                                       \
} while (0)

#define C7_COMPCI(CI) do {                                                  \
    float _q[XSPAN];                                                        \
    const int _qb4 = lane * (STEP / 4);                                     \
    _Pragma("unroll")                                                       \
    for (int _u = 0; _u < XSPAN / 4; _u++) {                                \
        float4 _v = *(const float4*)&xs[CI][4 * swz4(_qb4 + _u)];           \
        _q[4*_u] = _v.x; _q[4*_u+1] = _v.y;                                 \
        _q[4*_u+2] = _v.z; _q[4*_u+3] = _v.w;                               \
    }                                                                       \
    if constexpr ((XSPAN & 3) != 0) {                                       \
        const int _pt = swz4(_qb4 + XSPAN / 4);                             \
        if constexpr ((XSPAN & 3) >= 2) {                                   \
            float2 _v = *(const float2*)&xs[CI][4 * _pt];                   \
            _q[(XSPAN & ~3)] = _v.x; _q[(XSPAN & ~3) + 1] = _v.y;           \
        }                                                                   \
        if constexpr ((XSPAN & 3) == 1)                                     \
            _q[XSPAN - 1] = xs[CI][4 * _pt];                                \
        else if constexpr ((XSPAN & 3) == 3)                                \
            _q[XSPAN - 1] = xs[CI][4 * _pt + 2];                            \
    }                                                                       \
    {                                                                       \
        _Pragma("unroll")                                                   \
        for (int _k = 0; _k < KW; _k++) {                                   \
            if constexpr (OCW == 8) {                                       \
                const float4 _w0 = *(const float4*)&wls[((CI) * NWR + _k) * OCB + wid * 8];     \
                const float4 _w1 = *(const float4*)&wls[((CI) * NWR + _k) * OCB + wid * 8 + 4]; \
                _Pragma("unroll")                                           \
                for (int _i = 0; _i < 8; _i++) {                            \
                    float _wv = f4c(_i < 4 ? _w0 : _w1, _i & 3);            \
                    _Pragma("unroll")                                       \
                    for (int _j = 0; _j < TT; _j++)                         \
                        acc[_i][_j] = fmaf(_wv, _q[_j * STRIDE + _k], acc[_i][_j]); \
                }                                                           \
            } else {                                                        \
                const float4 _w0 = *(const float4*)&wls[((CI) * NWR + _k) * OCB + wid * 4];     \
                _Pragma("unroll")                                           \
                for (int _i = 0; _i < 4; _i++) {                            \
                    float _wv = f4c(_w0, _i);                               \
                    _Pragma("unroll")                                       \
                    for (int _j = 0; _j < TT; _j++)                         \
                        acc[_i][_j] = fmaf(_wv, _q[_j * STRIDE + _k], acc[_i][_j]); \
                }                                                           \
            }                                                               \
        }                                                                   \
    }                                                                       \
} while (0)

#pragma unroll
    for (int u = 0; u < NLD; u++) {
        int idx = tid + u * 256;
        if (idx < CC * NCH) {
            int cl = idx / NCH, q = idx - cl * NCH;
            loadg4(in + ((size_t)b * NC + cl) * L_in, gb + 4 * q, L_in, pre[u]);
        }
    }
#pragma unroll
    for (int u = 0; u < NLD; u++) {
        int idx = tid + u * 256;
        if (idx < CC * NCH) {
            int cl = idx / NCH, q = idx - cl * NCH;
            int g0 = gb + 4 * q;
            float e[4];
#pragma unroll
            for (int t = 0; t < 4; t++) {
                float v = pre[u][t];
                if (INMODE > 0) {
                    int gg = g0 + t;
                    if (gg >= 0 && gg < L_in) {
                        float s = v * scs[cl] + shs[cl];
                        v = (INMODE == 2) ? lrelu(s) : s;
                    }
                }
                e[t] = v;
            }
            *(float4*)&xs[cl][4 * swz4(q)] = make_float4(e[0], e[1], e[2], e[3]);
        }
    }
    C7_STAGEW(0);
    __syncthreads();

    for (int cc = 0; cc < NC; cc += CC) {
        if (cc + CC < NC) {
#pragma unroll
            for (int u = 0; u < NLD; u++) {
                int idx = tid + u * 256;
                if (idx < CC * NCH) {
                    int cl = idx / NCH, q = idx - cl * NCH;
                    loadg4(in + ((size_t)b * NC + cc + CC + cl) * L_in,
                           gb + 4 * q, L_in, pre[u]);
                }
            }
        }
#pragma unroll
        for (int ci = 0; ci < CC; ci++) {
            C7_COMPCI(ci);
        }
        __syncthreads();
        if (cc + CC < NC) {
#pragma unroll
            for (int u = 0; u < NLD; u++) {
                int idx = tid + u * 256;
                if (idx < CC * NCH) {
                    int cl = idx / NCH, q = idx - cl * NCH;
                    int g0 = gb + 4 * q;
                    int c = cc + CC + cl;
                    float e[4];
#pragma unroll
                    for (int t = 0; t < 4; t++) {
                        float v = pre[u][t];
                        if (INMODE > 0) {
                            int gg = g0 + t;
                            if (gg >= 0 && gg < L_in) {
                                float s = v * scs[c] + shs[c];
                                v = (INMODE == 2) ? lrelu(s) : s;
                            }
                        }
                        e[t] = v;
                    }
                    *(float4*)&xs[cl][4 * swz4(q)] = make_float4(e[0], e[1], e[2], e[3]);
                }
            }
            C7_STAGEW(cc + CC);
            __syncthreads();
        }
    }
#undef C7_STAGEW
#undef C7_COMPCI

    const int po = t0 + lane * TTO;
#pragma unroll
    for (int i = 0; i < OCW; i++) {
        const int o = oc0 + i;
        const float bv = bias[o];
        float s1 = 0.f, s2 = 0.f;
        float tmpm[TTO];
#pragma unroll
        for (int j = 0; j < TTO; j++) {
            float v = acc[i][j] + bv;
            if (OUTACT) v = lrelu(v);
            tmpm[j] = v;
            if (STATS) { s1 += v; s2 += v * v; }
        }
        float* orow = out + ((size_t)b * NC + o) * L_out + po;
        if constexpr (TTO == 4)
            *(float4*)orow = make_float4(tmpm[0], tmpm[1], tmpm[2], tmpm[3]);
        else if constexpr (TTO == 2)
            *(float2*)orow = make_float2(tmpm[0], tmpm[1]);
        else
            orow[0] = tmpm[0];
        if (STATS) {
#pragma unroll
            for (int m = 1; m < 64; m <<= 1) {
                s1 += __shfl_xor(s1, m);
                s2 += __shfl_xor(s2, m);
            }
            if (lane == 0) {
                atomicAdd(&stats[o], s1);
                atomicAdd(&stats[NC + o], s2);
            }
        }
    }
}

// ---------------------------------------------------------------------------
__global__ __launch_bounds__(256) void cvtW_k(const float* __restrict__ W,
                                              unsigned short* __restrict__ Wbf)
{
    int i = blockIdx.x * 256 + threadIdx.x;
    const float4 a = *(const float4*)&W[i * 8];
    const float4 b = *(const float4*)&W[i * 8 + 4];
    unsigned pk[4];
    pk[0] = bf16r(a.x) | (bf16r(a.y) << 16);
    pk[1] = bf16r(a.z) | (bf16r(a.w) << 16);
    pk[2] = bf16r(b.x) | (bf16r(b.y) << 16);
    pk[3] = bf16r(b.z) | (bf16r(b.w) << 16);
    *(uint4*)&Wbf[i * 8] = make_uint4(pk[0], pk[1], pk[2], pk[3]);
}

// ---------------------------------------------------------------------------
// salM2: MFMA bf16 GEMM over (128h x 128l) tiles (unchanged).
// ---------------------------------------------------------------------------
template<int PHASE>
__global__ __launch_bounds__(256) void salM2_k(
    const unsigned short* __restrict__ xT, const unsigned short* __restrict__ Wbf,
    const float* __restrict__ bias, float* __restrict__ gsum,
    unsigned* __restrict__ ghist, const unsigned* __restrict__ thrv,
    unsigned* __restrict__ candcnt, unsigned* __restrict__ candI)
{
    __shared__ unsigned short Als[128 * 128];
    __shared__ unsigned short Bls[128 * 128];

    const int b  = blockIdx.z;
    const int h0 = blockIdx.y * 128;
    const int l0 = blockIdx.x * 128;
    const int tid = threadIdx.x;
    const int lane = tid & 63;
    const int wid = tid >> 6;
    const int wh = (wid >> 1) * 64;
    const int wl = (wid & 1) * 64;

    {
        const uint4* gA = (const uint4*)(Wbf + (size_t)h0 * NC);
        const uint4* gB = (const uint4*)(xT + ((size_t)b * LFULL + l0) * NC);
        char* cA = (char*)Als; char* cB = (char*)Bls;
        for (int i = tid; i < 2048; i += 256) {
            int row = i >> 4, q = i & 15;
            unsigned sw = (unsigned)(row * 256 + q * 16) ^ (((unsigned)(row & 7)) << 4);
            *(uint4*)(cA + sw) = gA[i];
        }
        for (int i = tid; i < 2048; i += 256) {
            int row = i >> 4, q = i & 15;
            unsigned sw = (unsigned)(row * 256 + q * 16) ^ (((unsigned)(row & 7)) << 4);
            *(uint4*)(cB + sw) = gB[i];
        }
    }
    __syncthreads();

    f32x4 acc[4][4];
#pragma unroll
    for (int i = 0; i < 4; i++)
#pragma unroll
        for (int j = 0; j < 4; j++) acc[i][j] = (f32x4)(0.f);

    const int r15 = lane & 15, g = lane >> 4;
#pragma unroll
    for (int ks = 0; ks < 4; ks++) {
        bf16x8 af[4], bfv[4];
#pragma unroll
        for (int f = 0; f < 4; f++) {
            int rowA = wh + f * 16 + r15;
            unsigned offA = (unsigned)(rowA * 256 + ks * 64 + g * 16)
                          ^ (((unsigned)(rowA & 7)) << 4);
            af[f] = *(const bf16x8*)((const char*)Als + offA);
            int rowB = wl + f * 16 + r15;
            unsigned offB = (unsigned)(rowB * 256 + ks * 64 + g * 16)
                          ^ (((unsigned)(rowB & 7)) << 4);
            bfv[f] = *(const bf16x8*)((const char*)Bls + offB);
        }
#pragma unroll
        for (int i = 0; i < 4; i++)
#pragma unroll
            for (int j = 0; j < 4; j++)
                acc[i][j] = __builtin_amdgcn_mfma_f32_16x16x32_bf16(
                    af[i], bfv[j], acc[i][j], 0, 0, 0);
    }

    if constexpr (PHASE == 0) {
        __syncthreads();
        unsigned* lhist = (unsigned*)Als;
        for (int i = tid; i < 8192; i += 256) lhist[i] = 0;
        __syncthreads();
        unsigned* myh = lhist + (tid & 1) * 4096;
        float expsum = 0.f;
#pragma unroll
        for (int i = 0; i < 4; i++) {
#pragma unroll
            for (int r = 0; r < 4; r++) {
                const int h = h0 + wh + i * 16 + g * 4 + r;
                const float bv = bias[h];
#pragma unroll
                for (int j = 0; j < 4; j++) {
                    float v = acc[i][j][r] + bv;
                    expsum += expf(v);
                    atomicAdd(&myh[monoKey16(bf16r(v)) >> 4], 1u);
                }
            }
        }
#pragma unroll
        for (int m = 1; m < 64; m <<= 1) expsum += __shfl_xor(expsum, m);
        float* red = (float*)Bls;
        if (lane == 0) red[wid] = expsum;
        __syncthreads();
        for (int i = tid; i < 4096; i += 256) {
            unsigned s = lhist[i] + lhist[4096 + i];
            if (s) atomicAdd(&ghist[b * 4096 + i], s);
        }
        if (tid == 0) atomicAdd(&gsum[b], red[0] + red[1] + red[2] + red[3]);
    } else {
        const unsigned thr = thrv[b * 2];
#pragma unroll
        for (int i = 0; i < 4; i++) {
#pragma unroll
            for (int r = 0; r < 4; r++) {
                const int h = h0 + wh + i * 16 + g * 4 + r;
                const float bv = bias[h];
#pragma unroll
                for (int j = 0; j < 4; j++) {
                    float v = acc[i][j][r] + bv;
                    bool pr = monoKey16(bf16r(v)) >= thr;
                    unsigned long long m = __ballot(pr);
                    if (m) {
                        int leader = __ffsll((unsigned long long)m) - 1;
                        int cnt = __popcll(m);
                        unsigned basepos = 0;
                        if (lane == leader)
                            basepos = atomicAdd(&candcnt[b], (unsigned)cnt);
                        basepos = __shfl(basepos, leader);
                        if (pr) {
                            int rr = __popcll(m & ((1ull << lane) - 1ull));
                            unsigned pos = basepos + (unsigned)rr;
                            if (pos < CAP) {
                                int l = l0 + wl + j * 16 + r15;
                                candI[b * CAP + pos] = (unsigned)((h << 13) | l);
                            }
                        }
                    }
                }
            }
        }
    }
}

// ---------------------------------------------------------------------------
__global__ __launch_bounds__(256) void scan2_k(
    const unsigned* __restrict__ ghist, unsigned* __restrict__ thrv)
{
    const int b = blockIdx.x, tid = threadIdx.x;
    __shared__ unsigned part[256];
    unsigned s = 0;
#pragma unroll
    for (int i = 0; i < 16; i++) s += ghist[b * 4096 + tid * 16 + i];
    part[tid] = s;
    __syncthreads();
    if (tid == 0) {
        unsigned cum = 0; int ch;
        for (ch = 255; ch >= 0; ch--) {
            if (cum + part[ch] >= KSEL) break;
            cum += part[ch];
        }
        int bin = 0;
        if (ch >= 0) {
            for (bin = ch * 16 + 15; bin > ch * 16; bin--) {
                unsigned c = ghist[b * 4096 + bin];
                if (cum + c >= KSEL) break;
                cum += c;
            }
        }
        int bcol = bin > 0 ? bin - 1 : 0;
        thrv[b * 2] = (unsigned)bcol << 4;
    }
}

__global__ __launch_bounds__(128) void recompute_k(
    const unsigned* __restrict__ candcnt, const unsigned* __restrict__ candI,
    const float* __restrict__ xu, const float* __restrict__ W,
    const float* __restrict__ bias, unsigned* __restrict__ candK)
{
    const int b = blockIdx.y;
    const unsigned cnt = min(candcnt[b], (unsigned)CAP);
    const int t = threadIdx.x;
    __shared__ float wsum[2];
    for (unsigned k = blockIdx.x; k < cnt; k += 1024) {
        unsigned e = candI[b * CAP + k];
        int h = e >> 13, l = e & 8191;
        float prod = W[h * NC + t] * xu[(b * NC + t) * LFULL + l];
#pragma unroll
        for (int m = 1; m < 64; m <<= 1) prod += __shfl_xor(prod, m);
        if ((t & 63) == 0) wsum[t >> 6] = prod;
        __syncthreads();
        if (t == 0) candK[b * CAP + k] = monoKey(wsum[0] + wsum[1] + bias[h]);
        __syncthreads();
    }
}

__global__ __launch_bounds__(256) void select2_k(
    const unsigned* __restrict__ candcnt, const unsigned* __restrict__ candK,
    const unsigned* __restrict__ candI,
    uint2* __restrict__ selected, unsigned* __restrict__ selcnt)
{
    const int b = blockIdx.x, tid = threadIdx.x;
    __shared__ unsigned h1[4096];
    __shared__ unsigned l2k[2048], l2i[2048];
    __shared__ unsigned part[256];
    __shared__ unsigned sh[8];

    const unsigned Nc = min(candcnt[b], (unsigned)CAP);
    const unsigned* kk = candK + b * CAP;
    const unsigned* ii = candI + b * CAP;
    uint2* sel = selected + b * KSEL;

    for (int i = tid; i < 4096; i += 256) h1[i] = 0;
    if (tid < 8) sh[tid] = 0;
    __syncthreads();
    for (unsigned i = tid; i < Nc; i += 256) atomicAdd(&h1[kk[i] >> 20], 1u);
    __syncthreads();
    {
        unsigned s = 0;
#pragma unroll
        for (int i = 0; i < 16; i++) s += h1[tid * 16 + i];
        part[tid] = s;
        __syncthreads();
        if (tid == 0) {
            unsigned cum = 0; int ch;
            for (ch = 255; ch >= 0; ch--) { if (cum + part[ch] >= KSEL) break; cum += part[ch]; }
            int bin = 0;
            if (ch >= 0)
                for (bin = ch * 16 + 15; bin > ch * 16; bin--) {
                    unsigned c = h1[bin];
                    if (cum + c >= KSEL) break;
                    cum += c;
                }
            sh[2] = (unsigned)bin; sh[3] = KSEL - cum;
        }
    }
    __syncthreads();
    const unsigned b1 = sh[2], need1 = sh[3];
    for (int i = tid; i < 1024; i += 256) h1[i] = 0;
    __syncthreads();
    for (unsigned i = tid; i < Nc; i += 256) {
        unsigned k = kk[i], bin = k >> 20;
        if (bin > b1) {
            unsigned p = atomicAdd(&sh[0], 1u);
            if (p < KSEL) sel[p] = make_uint2(k, ii[i]);
        } else if (bin == b1) {
            atomicAdd(&h1[(k >> 10) & 1023], 1u);
        }
    }
    __syncthreads();
    {
        unsigned s = 0;
#pragma unroll
        for (int i = 0; i < 4; i++) s += h1[tid * 4 + i];
        part[tid] = s;
        __syncthreads();
        if (tid == 0) {
            unsigned cum = 0; int ch;
            for (ch = 255; ch >= 0; ch--) { if (cum + part[ch] >= need1) break; cum += part[ch]; }
            int bin = 0;
            if (ch >= 0)
                for (bin = ch * 4 + 3; bin > ch * 4; bin--) {
                    unsigned c = h1[bin];
                    if (cum + c >= need1) break;
                    cum += c;
                }
            sh[4] = (unsigned)bin; sh[5] = need1 - cum;
        }
    }
    __syncthreads();
    const unsigned b2 = sh[4], need2 = sh[5];
    for (int i = tid; i < 1024; i += 256) h1[i] = 0;
    __syncthreads();
    for (unsigned i = tid; i < Nc; i += 256) {
        unsigned k = kk[i];
        if ((k >> 20) != b1) continue;
        unsigned mb = (k >> 10) & 1023;
        if (mb > b2) {
            unsigned p = atomicAdd(&sh[0], 1u);
            if (p < KSEL) sel[p] = make_uint2(k, ii[i]);
        } else if (mb == b2) {
            unsigned j = atomicAdd(&sh[1], 1u);
            if (j < 2048) { l2k[j] = k; l2i[j] = ii[i]; atomicAdd(&h1[k & 1023], 1u); }
        }
    }
    __syncthreads();
    const unsigned m2 = min(sh[1], 2048u);
    {
        unsigned s = 0;
#pragma unroll
        for (int i = 0; i < 4; i++) s += h1[tid * 4 + i];
        part[tid] = s;
        __syncthreads();
        if (tid == 0) {
            unsigned cum = 0; int ch;
            for (ch = 255; ch >= 0; ch--) { if (cum + part[ch] >= need2) break; cum += part[ch]; }
            int bin = 0;
            if (ch >= 0)
                for (bin = ch * 4 + 3; bin > ch * 4; bin--) {
                    unsigned c = h1[bin];
                    if (cum + c >= need2) break;
                    cum += c;
                }
            sh[6] = (unsigned)bin; sh[7] = need2 - cum;
        }
    }
    __syncthreads();
    const unsigned b3 = sh[6], need3 = sh[7];
    if (tid == 0) sh[1] = 0;
    __syncthreads();
    for (unsigned i = tid; i < m2; i += 256) {
        unsigned k = l2k[i], lb = k & 1023;
        if (lb > b3) {
            unsigned p = atomicAdd(&sh[0], 1u);
            if (p < KSEL) sel[p] = make_uint2(k, l2i[i]);
        } else if (lb == b3) {
            unsigned t = atomicAdd(&sh[1], 1u);
            if (t < need3) {
                unsigned p = atomicAdd(&sh[0], 1u);
                if (p < KSEL) sel[p] = make_uint2(k, l2i[i]);
            }
        }
    }
    __syncthreads();
    if (tid == 0) selcnt[b] = min(sh[0], (unsigned)KSEL);
}

// ---------------------------------------------------------------------------
__global__ void inity_k(float* __restrict__ y, const float* __restrict__ bias)
{
    int i = blockIdx.x * 256 + threadIdx.x;
    float bv = bias[(i >> 11) & 127];
    ((float4*)y)[i] = make_float4(bv, bv, bv, bv);
}

__global__ __launch_bounds__(128) void scatter_k(
    const uint2* __restrict__ selected, const unsigned* __restrict__ selcnt,
    const float* __restrict__ gsum, const float* __restrict__ xu,
    const float* __restrict__ upw, const float* __restrict__ upb,
    const float* __restrict__ dww, float* __restrict__ y)
{
    const int b = blockIdx.y, kidx = blockIdx.x;
    if (kidx >= (int)selcnt[b]) return;
    const uint2 s = selected[b * KSEL + kidx];
    const float salv = keyToF(s.x);
    const unsigned idx = s.y;
    const int h = idx >> 13, l = idx & 8191;
    const int t = threadIdx.x;

    float prod = upw[h * NC + t] * xu[(b * NC + t) * LFULL + l];
#pragma unroll
    for (int m = 1; m < 64; m <<= 1) prod += __shfl_xor(prod, m);
    __shared__ float wsum[2];
    if ((t & 63) == 0) wsum[t >> 6] = prod;
    __syncthreads();
    const float sig = wsum[0] + wsum[1] + upb[h];
    const float val = expf(salv) / gsum[b];
    const float g = sig * val;
    atomicAdd(&y[(b * NC + t) * LFULL + l], dww[t * NH + h] * g);
}

__global__ void apply_k(const float* __restrict__ in, const float* __restrict__ stats,
                        const float* __restrict__ g, const float* __restrict__ bt,
                        float* __restrict__ out, float inv_n)
{
    int i = blockIdx.x * 256 + threadIdx.x;
    int c = (i >> 7) & 127;
    float m  = stats[c] * inv_n;
    float va = stats[NC + c] * inv_n - m * m;
    float sc = g[c] * rsqrtf(va + 1e-5f);
    out[i] = in[i] * sc + (bt[c] - m * sc);
}

// ---------------------------------------------------------------------------
extern "C" void kernel_launch(void* const* d_in, const int* in_sizes, int n_in,
                              void* d_out, int out_size, void* d_ws, size_t ws_size,
                              hipStream_t stream)
{
    const float* x        = (const float*)d_in[0];
    const float* up_w     = (const float*)d_in[1];
    const float* up_b     = (const float*)d_in[2];
    const float* up_g     = (const float*)d_in[3];
    const float* up_beta  = (const float*)d_in[4];
    const float* up_out_w = (const float*)d_in[5];
    const float* up_out_b = (const float*)d_in[6];
    const float* sb_up_w  = (const float*)d_in[7];
    const float* sb_up_b  = (const float*)d_in[8];
    const float* sal_w    = (const float*)d_in[9];
    const float* sal_b    = (const float*)d_in[10];
    const float* sb_dn_w  = (const float*)d_in[11];
    const float* sb_dn_b  = (const float*)d_in[12];
    const float* dn_w     = (const float*)d_in[13];
    const float* dn_b     = (const float*)d_in[14];
    const float* dn_g     = (const float*)d_in[15];
    const float* dn_beta  = (const float*)d_in[16];

    char* ws = (char*)d_ws;
    float*          stats    = (float*)(ws + 0);
    float*          gsum     = (float*)(ws + 16384);
    unsigned*       thrv     = (unsigned*)(ws + 16416);
    unsigned*       candcnt  = (unsigned*)(ws + 16480);
    unsigned*       selcnt   = (unsigned*)(ws + 16512);
    uint2*          selected = (uint2*)(ws + 16640);
    unsigned*       ghist    = (unsigned*)(ws + 49408);
    unsigned*       candK    = (unsigned*)(ws + 180480);
    unsigned*       candI    = (unsigned*)(ws + 1229056);
    unsigned short* Wbf      = (unsigned short*)(ws + 2277632);
    float*          wprep    = (float*)(ws + 2539776);
    float*          B0       = (float*)(ws + 5685504);
    float*          B1       = (float*)(ws + 39239936);
    unsigned short* xT       = (unsigned short*)(ws + 72794368);
    float*          y        = (float*)(ws + 72794368);
    unsigned short* Afrag    = (unsigned short*)(ws + 117440512);
    float*          partial  = (float*)(ws + 121634816);

    hipMemsetAsync(d_ws, 0, 16544, stream);
    hipMemsetAsync(ws + 49408, 0, 131072, stream);

    cvtW_k<<<64,256,0,stream>>>(sal_w, Wbf);
    prep_k<<<3072,256,0,stream>>>(up_w, up_out_w, dn_w, wprep);
    prepA_k<<<864,256,0,stream>>>(up_w, up_out_w, Afrag);

    // ---- ConvUpsample (MFMA, 8-wave blocks): 128 -> 8192 frames ----
    mconvU_k<0><<<dim3(2,NB),512,0,stream>>>(
        x, B0, Afrag, up_b, nullptr, nullptr, nullptr, 0.f, partial, 128);
    redstats_k<<<16,256,0,stream>>>(partial, 2*NB, stats);
    mconvU_k<2><<<dim3(4,NB),512,0,stream>>>(
        B0, B1, Afrag + 1*262144, up_b + NC,
        stats, up_g, up_beta, 1.f/(float)(NB*256), partial, 256);
    redstats_k<<<16,256,0,stream>>>(partial, 4*NB, stats + 256);
    mconvU_k<2><<<dim3(8,NB),512,0,stream>>>(
        B1, B0, Afrag + 2*262144, up_b + 2*NC,
        stats + 256, up_g + NC, up_beta + NC, 1.f/(float)(NB*512), partial, 512);
    redstats_k<<<16,256,0,stream>>>(partial, 8*NB, stats + 2*256);
    mconvU_k<2><<<dim3(16,NB),512,0,stream>>>(
        B0, B1, Afrag + 3*262144, up_b + 3*NC,
        stats + 2*256, up_g + 2*NC, up_beta + 2*NC, 1.f/(float)(NB*1024), partial, 1024);
    redstats_k<<<16,256,0,stream>>>(partial, 16*NB, stats + 3*256);
    mconvU_k<2><<<dim3(32,NB),512,0,stream>>>(
        B1, B0, Afrag + 4*262144, up_b + 4*NC,
        stats + 3*256, up_g + 3*NC, up_beta + 3*NC, 1.f/(float)(NB*2048), partial, 2048);
    redstats_k<<<16,256,0,stream>>>(partial, 32*NB, stats + 4*256);
    mconvU_k<2><<<dim3(64,NB),512,0,stream>>>(
        B0, B1, Afrag + 5*262144, up_b + 5*NC,
        stats + 4*256, up_g + 4*NC, up_beta + 4*NC, 1.f/(float)(NB*4096), partial, 4096);
    redstats_k<<<16,256,0,stream>>>(partial, 64*NB, stats + 5*256);
    // final k3 conv (MFMA): B1 -> B0 (f32 x_up) + xT (bf16 transposed)
    mconvF_k<<<dim3(64,NB),512,0,stream>>>(
        B1, B0, Afrag, up_out_b,
        stats + 5*256, up_g + 5*NC, up_beta + 5*NC, 1.f/(float)(NB*LFULL), xT);

    // ---- SparseBottleneck ----
    salM2_k<0><<<dim3(64,8,NB),256,0,stream>>>(xT, Wbf, sal_b, gsum, ghist,
                                               nullptr, nullptr, nullptr);
    scan2_k<<<NB,256,0,stream>>>(ghist, thrv);
    salM2_k<1><<<dim3(64,8,NB),256,0,stream>>>(xT, Wbf, sal_b, nullptr, nullptr,
                                               thrv, candcnt, candI);
    recompute_k<<<dim3(1024,NB),128,0,stream>>>(candcnt, candI, B0, sal_w, sal_b, candK);
    select2_k<<<NB,256,0,stream>>>(candcnt, candK, candI, selected, selcnt);
    inity_k<<<(NB*NC*LFULL/4)/256,256,0,stream>>>(y, sb_dn_b);
    scatter_k<<<dim3(KSEL,NB),128,0,stream>>>(selected, selcnt, gsum, B0,
                                              sb_up_w, sb_up_b, sb_dn_w, y);

    // ---- down stack (VALU, swizzled, OCW4 16-oc blocks): 8192 -> 128 ----
    conv7_k<7,4,3,false,0,true,true,2,false,4><<<dim3(16,8,NB),256,0,stream>>>(
        y, B1, wprep + 442368, dn_b, nullptr, nullptr, nullptr, 0.f,
        stats + 6*256, nullptr, 8192, 2048);
    conv7_k<7,4,3,false,1,true,true,1,false,4><<<dim3(8,8,NB),256,0,stream>>>(
        B1, B0, wprep + 442368 + 114688, dn_b + NC,
        stats + 6*256, dn_g, dn_beta, 1.f/(float)(NB*2048),
        stats + 7*256, nullptr, 2048, 512);
    conv7_k<7,4,3,false,1,true,true,1,false,4><<<dim3(2,8,NB),256,0,stream>>>(
        B0, B1, wprep + 442368 + 2*114688, dn_b + 2*NC,
        stats + 7*256, dn_g + NC, dn_beta + NC, 1.f/(float)(NB*512),
        stats + 8*256, nullptr, 512, 128);

    apply_k<<<(out_size + 255)/256,256,0,stream>>>(
        B1, stats + 8*256, dn_g + 2*NC, dn_beta + 2*NC, (float*)d_out,
        1.f/(float)(NB*128));
}

// Round 18
// 655.463 us; speedup vs baseline: 1.5388x; 1.0697x over previous
//
#include <hip/hip_runtime.h>
#include <hip/hip_bf16.h>

// ---------------------------------------------------------------------------
// ExpandAndContractBottleneck.  R18: dn0 replaced by its algebraic form --
// conv(bias-const + sparse) = analytic per-channel const (+t=0 edge) + <=2
// output positions per sparse column.  Deletes dense y buffer + inity +
// dense scatter + 1.9GFMA conv; adds tiny fill/corr/actstats kernels.
// ---------------------------------------------------------------------------

#define DEV_INLINE __device__ __forceinline__

constexpr int NB   = 8;
constexpr int NC   = 128;
constexpr int NH   = 1024;
constexpr int LFULL= 8192;
constexpr int KSEL = 512;
constexpr int CAP  = 32768;

typedef __attribute__((ext_vector_type(4))) float f32x4;
typedef __attribute__((ext_vector_type(8))) short bf16x8;

DEV_INLINE unsigned monoKey(float f) {
    unsigned u = __float_as_uint(f);
    return (u & 0x80000000u) ? ~u : (u | 0x80000000u);
}
DEV_INLINE float keyToF(unsigned k) {
    unsigned u = (k & 0x80000000u) ? (k ^ 0x80000000u) : ~k;
    return __uint_as_float(u);
}
DEV_INLINE unsigned monoKey16(unsigned u) {
    return (u & 0x8000u) ? ((~u) & 0xFFFFu) : (u | 0x8000u);
}
DEV_INLINE unsigned bf16r(float f) {
    unsigned u = __float_as_uint(f);
    return (u + 0x7FFFu + ((u >> 16) & 1u)) >> 16;
}
DEV_INLINE float lrelu(float v) { return v >= 0.f ? v : 0.2f * v; }
DEV_INLINE float f4c(const float4& v, int k) {
    return k == 0 ? v.x : k == 1 ? v.y : k == 2 ? v.z : v.w;
}
DEV_INLINE int swz4(int p) { return p ^ ((p >> 3) & 7); }

DEV_INLINE void loadg4(const float* __restrict__ rowp, int g0, int L, float* e) {
    if (g0 >= 0 && g0 + 4 <= L) {
        float4 v = *(const float4*)(rowp + g0);
        e[0] = v.x; e[1] = v.y; e[2] = v.z; e[3] = v.w;
    } else {
#pragma unroll
        for (int t = 0; t < 4; t++) {
            int g = g0 + t;
            e[t] = (g >= 0 && g < L) ? rowp[g] : 0.f;
        }
    }
}

// ---------------------------------------------------------------------------
// prep_k: VALU dn weights [c][tap][128 oc].
// ---------------------------------------------------------------------------
__global__ __launch_bounds__(256) void prep_k(
    const float* __restrict__ up_w, const float* __restrict__ up_out_w,
    const float* __restrict__ dn_w, float* __restrict__ wprep)
{
    int idx = blockIdx.x * 256 + threadIdx.x;
    if (idx < 393216) {
        int layer = idx >> 16;
        int r0 = idx & 65535;
        int c = r0 >> 9, r = (r0 >> 7) & 3, o = r0 & 127;
        const float* wsrc = up_w + ((size_t)layer * 128 + o) * 384 + c * 3;
        float w0 = wsrc[0], w1 = wsrc[1], w2 = wsrc[2];
        wprep[idx] = (r == 0) ? w0 : (r == 1) ? (w1 + w2) : (r == 2) ? (w0 + w1) : w2;
    } else if (idx < 442368) {
        int r0 = idx - 393216;
        int c = r0 / 384, k = (r0 / 128) % 3, o = r0 & 127;
        wprep[idx] = up_out_w[((size_t)o * 128 + c) * 3 + k];
    } else {
        int r0 = idx - 442368;
        int layer = r0 / 114688;
        int r1 = r0 - layer * 114688;
        int c = r1 / 896, k = (r1 / 128) % 7, o = r1 & 127;
        wprep[idx] = dn_w[((size_t)layer * 128 + o) * 896 + c * 7 + k];
    }
}

// ---------------------------------------------------------------------------
// prepA_k: MFMA A-operand fragment records (unchanged).
// ---------------------------------------------------------------------------
__global__ __launch_bounds__(256) void prepA_k(
    const float* __restrict__ up_w, const float* __restrict__ up_out_w,
    unsigned short* __restrict__ afrag)
{
    int idx = blockIdx.x * 256 + threadIdx.x;
    if (idx >= 221184) return;
    int rid = idx >> 6, lane = idx & 63;
    const int r15 = lane & 15, g = lane >> 4;
    unsigned short vals[8];
    if (rid < 3072) {
        int L  = rid >> 9;
        int r0 = rid & 511;
        int f = r0 & 3, ks = (r0 >> 2) & 1, cc = (r0 >> 3) & 1;
        int wo = (r0 >> 4) & 1, half = (r0 >> 5) & 1, ptap = (r0 >> 6) & 3;
        int o = wo * 64 + f * 16 + r15;
        int cb = cc * 64 + ks * 32 + g * 8;
#pragma unroll
        for (int e = 0; e < 8; e++) {
            const float* ws = up_w + (((size_t)L * 128 + o) * 128 + (cb + e)) * 3;
            float w0 = ws[0], w1 = ws[1], w2 = ws[2];
            float v = (ptap == 0) ? w0 : (ptap == 1) ? (w1 + w2)
                    : (ptap == 2) ? (w0 + w1) : w2;
            unsigned hi = bf16r(v);
            if (half == 0) vals[e] = (unsigned short)hi;
            else vals[e] = (unsigned short)bf16r(v - __uint_as_float(hi << 16));
        }
    } else {
        int r2 = rid - 3072;
        int f = r2 & 3, ks = (r2 >> 2) & 1, cc = (r2 >> 3) & 1;
        int wo = (r2 >> 4) & 1, half = (r2 >> 5) & 1, tap = r2 >> 6;
        int o = wo * 64 + f * 16 + r15;
        int cb = cc * 64 + ks * 32 + g * 8;
#pragma unroll
        for (int e = 0; e < 8; e++) {
            float v = up_out_w[((size_t)o * 128 + (cb + e)) * 3 + tap];
            unsigned hi = bf16r(v);
            if (half == 0) vals[e] = (unsigned short)hi;
            else vals[e] = (unsigned short)bf16r(v - __uint_as_float(hi << 16));
        }
    }
    unsigned pk[4];
#pragma unroll
    for (int q = 0; q < 4; q++)
        pk[q] = (unsigned)vals[2*q] | ((unsigned)vals[2*q+1] << 16);
    *(uint4*)(afrag + (size_t)rid * 512 + lane * 8) = make_uint4(pk[0], pk[1], pk[2], pk[3]);
}

// ---------------------------------------------------------------------------
// redstats_k: PARALLEL reduce of per-block partials (unchanged from R16).
// ---------------------------------------------------------------------------
__global__ __launch_bounds__(256) void redstats_k(
    const float* __restrict__ partial, int nb, float* __restrict__ stats)
{
    const int c = threadIdx.x;
    float s0 = 0.f, s1 = 0.f, s2 = 0.f, s3 = 0.f;
    for (int i = blockIdx.x * 4; i < nb; i += gridDim.x * 4) {
        s0 += partial[(size_t)(i + 0) * 256 + c];
        s1 += partial[(size_t)(i + 1) * 256 + c];
        s2 += partial[(size_t)(i + 2) * 256 + c];
        s3 += partial[(size_t)(i + 3) * 256 + c];
    }
    float s = (s0 + s1) + (s2 + s3);
    if (s != 0.f || blockIdx.x == 0) atomicAdd(&stats[c], s);
}

// ---------------------------------------------------------------------------
// mconvU_k: UPS MFMA conv, 512 threads / 8 waves (unchanged).
// ---------------------------------------------------------------------------
template<int INMODE>
__global__ __launch_bounds__(512) void mconvU_k(
    const float* __restrict__ in, float* __restrict__ out,
    const unsigned short* __restrict__ afrag, const float* __restrict__ bias,
    const float* __restrict__ stp, const float* __restrict__ gp,
    const float* __restrict__ btp, float inv_n,
    float* __restrict__ partial, int L_in)
{
    __shared__ unsigned short Xh[66 * 64], Xl[66 * 64];
    __shared__ float scs[NC], shs[NC];
    __shared__ float sstat[256];

    const int b = blockIdx.y, tile0 = blockIdx.x * 64, tid = threadIdx.x;
    const int lane = tid & 63, wid = tid >> 6;
    const int wo = wid >> 2, par = (wid >> 1) & 1, jh = wid & 1;
    const int r15 = lane & 15, g = lane >> 4;
    const int bid = b * gridDim.x + blockIdx.x;

    if (tid < 256) sstat[tid] = 0.f;
    if (INMODE > 0) {
        for (int c = tid; c < NC; c += 512) {
            float m  = stp[c] * inv_n;
            float va = stp[NC + c] * inv_n - m * m;
            float sc = gp[c] * rsqrtf(va + 1e-5f);
            scs[c] = sc;
            shs[c] = btp[c] - m * sc;
        }
    }

    f32x4 acc[4][2];
#pragma unroll
    for (int i = 0; i < 4; i++)
#pragma unroll
        for (int j = 0; j < 2; j++) acc[i][j] = (f32x4)(0.f);

    for (int cc = 0; cc < 2; cc++) {
        __syncthreads();
        {
            int r = tid & 63;
            int l = tile0 - 1 + r;
            for (int c0 = (tid >> 6); c0 < 64; c0 += 8) {
                int c = cc * 64 + c0;
                float v = 0.f;
                if (l >= 0 && l < L_in) {
                    v = in[((size_t)b * NC + c) * L_in + l];
                    if (INMODE > 0) v = lrelu(v * scs[c] + shs[c]);
                }
                unsigned hi = bf16r(v);
                unsigned lo = bf16r(v - __uint_as_float(hi << 16));
                unsigned bo = ((unsigned)(r * 128 + c0 * 2)) ^ (((unsigned)(r & 7)) << 4);
                *(unsigned short*)((char*)Xh + bo) = (unsigned short)hi;
                *(unsigned short*)((char*)Xl + bo) = (unsigned short)lo;
            }
            if (tid < 128) {
                int r2 = 64 + (tid >> 6);
                int l2 = tile0 - 1 + r2;
                int c0 = tid & 63;
                int c = cc * 64 + c0;
                float v = 0.f;
                if (l2 >= 0 && l2 < L_in) {
                    v = in[((size_t)b * NC + c) * L_in + l2];
                    if (INMODE > 0) v = lrelu(v * scs[c] + shs[c]);
                }
                unsigned hi = bf16r(v);
                unsigned lo = bf16r(v - __uint_as_float(hi << 16));
                unsigned bo = ((unsigned)(r2 * 128 + c0 * 2)) ^ (((unsigned)(r2 & 7)) << 4);
                *(unsigned short*)((char*)Xh + bo) = (unsigned short)hi;
                *(unsigned short*)((char*)Xl + bo) = (unsigned short)lo;
            }
        }
        __syncthreads();
#pragma unroll
        for (int pt = 0; pt < 2; pt++) {
            const int ptap = par * 2 + pt;
            const int roff = (ptap == 0) ? 0 : (ptap == 3) ? 2 : 1;
#pragma unroll
            for (int combo = 0; combo < 3; combo++) {
                const int ah = (combo == 2) ? 1 : 0;
                const unsigned short* Xs = (combo == 1) ? Xl : Xh;
                bf16x8 af[8];
#pragma unroll
                for (int ks = 0; ks < 2; ks++)
#pragma unroll
                    for (int f = 0; f < 4; f++) {
                        int rec = ((((ptap * 2 + ah) * 2 + wo) * 2 + cc) * 2 + ks) * 4 + f;
                        af[ks * 4 + f] = *(const bf16x8*)(afrag + (size_t)rec * 512 + lane * 8);
                    }
#pragma unroll
                for (int ks = 0; ks < 2; ks++) {
                    bf16x8 bf_[2];
#pragma unroll
                    for (int j = 0; j < 2; j++) {
                        int row = (jh * 2 + j) * 16 + r15 + roff;
                        unsigned bo = ((unsigned)(row * 128 + ks * 64 + g * 16))
                                    ^ (((unsigned)(row & 7)) << 4);
                        bf_[j] = *(const bf16x8*)((const char*)Xs + bo);
                    }
#pragma unroll
                    for (int i = 0; i < 4; i++)
#pragma unroll
                        for (int j = 0; j < 2; j++)
                            acc[i][j] = __builtin_amdgcn_mfma_f32_16x16x32_bf16(
                                af[ks * 4 + i], bf_[j], acc[i][j], 0, 0, 0);
                }
            }
        }
    }

    const int L_out = 2 * L_in;
#pragma unroll
    for (int i = 0; i < 4; i++) {
#pragma unroll
        for (int r = 0; r < 4; r++) {
            const int o = wo * 64 + i * 16 + g * 4 + r;
            const float bv = bias[o];
            float s1 = 0.f, s2 = 0.f;
#pragma unroll
            for (int j = 0; j < 2; j++) {
                float v = acc[i][j][r] + bv;
                int lout = 2 * (tile0 + (jh * 2 + j) * 16 + r15) + par;
                out[((size_t)b * NC + o) * L_out + lout] = v;
                s1 += v; s2 += v * v;
            }
#pragma unroll
            for (int m = 1; m < 16; m <<= 1) {
                s1 += __shfl_xor(s1, m);
                s2 += __shfl_xor(s2, m);
            }
            if (r15 == 0) {
                atomicAdd(&sstat[o], s1);
                atomicAdd(&sstat[NC + o], s2);
            }
        }
    }
    __syncthreads();
    if (tid < 256) partial[(size_t)bid * 256 + tid] = sstat[tid];
}

// ---------------------------------------------------------------------------
// mconvF_k: final k3 conv as MFMA, 512 threads / 8 waves (unchanged).
// ---------------------------------------------------------------------------
__global__ __launch_bounds__(512) void mconvF_k(
    const float* __restrict__ in, float* __restrict__ out,
    const unsigned short* __restrict__ afrag, const float* __restrict__ bias,
    const float* __restrict__ stp, const float* __restrict__ gp,
    const float* __restrict__ btp, float inv_n,
    unsigned short* __restrict__ xtout)
{
    __shared__ unsigned short Xh[130 * 64], Xl[130 * 64];
    __shared__ float scs[NC], shs[NC];

    const int b = blockIdx.y, l0 = blockIdx.x * 128, tid = threadIdx.x;
    const int lane = tid & 63, wid = tid >> 6;
    const int wo = wid >> 2, wl = (wid & 3) * 32;
    const int r15 = lane & 15, g = lane >> 4;

    for (int c = tid; c < NC; c += 512) {
        float m  = stp[c] * inv_n;
        float va = stp[NC + c] * inv_n - m * m;
        float sc = gp[c] * rsqrtf(va + 1e-5f);
        scs[c] = sc;
        shs[c] = btp[c] - m * sc;
    }

    f32x4 acc[4][2];
#pragma unroll
    for (int i = 0; i < 4; i++)
#pragma unroll
        for (int j = 0; j < 2; j++) acc[i][j] = (f32x4)(0.f);

    for (int cc = 0; cc < 2; cc++) {
        __syncthreads();
        {
            int r = tid & 127;
            int l = l0 - 1 + r;
            for (int c0 = (tid >> 7); c0 < 64; c0 += 4) {
                int c = cc * 64 + c0;
                float v = 0.f;
                if (l >= 0 && l < LFULL) {
                    v = in[((size_t)b * NC + c) * LFULL + l];
                    v = lrelu(v * scs[c] + shs[c]);
                }
                unsigned hi = bf16r(v);
                unsigned lo = bf16r(v - __uint_as_float(hi << 16));
                unsigned bo = ((unsigned)(r * 128 + c0 * 2)) ^ (((unsigned)(r & 7)) << 4);
                *(unsigned short*)((char*)Xh + bo) = (unsigned short)hi;
                *(unsigned short*)((char*)Xl + bo) = (unsigned short)lo;
            }
            if (tid < 128) {
                int r2 = 128 + (tid >> 6);
                int l2 = l0 - 1 + r2;
                int c0 = tid & 63;
                int c = cc * 64 + c0;
                float v = 0.f;
                if (l2 >= 0 && l2 < LFULL) {
                    v = in[((size_t)b * NC + c) * LFULL + l2];
                    v = lrelu(v * scs[c] + shs[c]);
                }
                unsigned hi = bf16r(v);
                unsigned lo = bf16r(v - __uint_as_float(hi << 16));
                unsigned bo = ((unsigned)(r2 * 128 + c0 * 2)) ^ (((unsigned)(r2 & 7)) << 4);
                *(unsigned short*)((char*)Xh + bo) = (unsigned short)hi;
                *(unsigned short*)((char*)Xl + bo) = (unsigned short)lo;
            }
        }
        __syncthreads();
#pragma unroll
        for (int tap = 0; tap < 3; tap++) {
#pragma unroll
            for (int combo = 0; combo < 3; combo++) {
                const int ah = (combo == 2) ? 1 : 0;
                const unsigned short* Xs = (combo == 1) ? Xl : Xh;
                bf16x8 af[8];
#pragma unroll
                for (int ks = 0; ks < 2; ks++)
#pragma unroll
                    for (int f = 0; f < 4; f++) {
                        int rec = 3072 + ((((tap * 2 + ah) * 2 + wo) * 2 + cc) * 2 + ks) * 4 + f;
                        af[ks * 4 + f] = *(const bf16x8*)(afrag + (size_t)rec * 512 + lane * 8);
                    }
#pragma unroll
                for (int ks = 0; ks < 2; ks++) {
                    bf16x8 bf_[2];
#pragma unroll
                    for (int j = 0; j < 2; j++) {
                        int row = wl + j * 16 + r15 + tap;
                        unsigned bo = ((unsigned)(row * 128 + ks * 64 + g * 16))
                                    ^ (((unsigned)(row & 7)) << 4);
                        bf_[j] = *(const bf16x8*)((const char*)Xs + bo);
                    }
#pragma unroll
                    for (int i = 0; i < 4; i++)
#pragma unroll
                        for (int j = 0; j < 2; j++)
                            acc[i][j] = __builtin_amdgcn_mfma_f32_16x16x32_bf16(
                                af[ks * 4 + i], bf_[j], acc[i][j], 0, 0, 0);
                }
            }
        }
    }

#pragma unroll
    for (int i = 0; i < 4; i++) {
#pragma unroll
        for (int r = 0; r < 4; r++) {
            const int o = wo * 64 + i * 16 + g * 4 + r;
            const float bv = bias[o];
#pragma unroll
            for (int j = 0; j < 2; j++) {
                float v = acc[i][j][r] + bv;
                int l = l0 + wl + j * 16 + r15;
                out[((size_t)b * NC + o) * LFULL + l] = v;
                xtout[((size_t)b * LFULL + l) * NC + o] = (unsigned short)bf16r(v);
            }
        }
    }
}

// ---------------------------------------------------------------------------
// conv7: VALU conv (dn1/dn2 only now), swizzled x tile, OCW oc per wave.
// ---------------------------------------------------------------------------
template<int KW, int STRIDE, int PAD, bool UPS, int INMODE, bool OUTACT, bool STATS, int TT, bool XPOSE, int OCW>
__global__ __launch_bounds__(256) void conv7_k(
    const float* __restrict__ in, float* __restrict__ out,
    const float* __restrict__ wp, const float* __restrict__ bias,
    const float* __restrict__ stp, const float* __restrict__ gp,
    const float* __restrict__ btp, float inv_n,
    float* __restrict__ stats, unsigned short* __restrict__ xtout,
    int L_in, int L_out)
{
    constexpr int CC    = (KW == 7) ? 8 : 16;
    constexpr int PT    = 64 * TT;
    constexpr int TTO   = UPS ? 2 * TT : TT;
    constexpr int NWR   = UPS ? 4 : KW;
    constexpr int OCB   = 4 * OCW;
    constexpr int SPAN  = UPS ? (PT + 2) : ((PT - 1) * STRIDE + KW);
    constexpr int NCH   = (SPAN + 3) / 4;
    constexpr int NCH8  = (NCH + 7) & ~7;
    constexpr int XROW  = 4 * NCH8 + 4;
    constexpr int NLD   = (CC * NCH + 255) / 256;
    constexpr int XSPAN = UPS ? (TT + 2) : ((TT - 1) * STRIDE + KW);
    constexpr int STEP  = UPS ? TT : TT * STRIDE;
    constexpr int NWQ   = CC * NWR * (OCB / 4);
    static_assert((STEP & 3) == 0, "conv7 swizzle path requires STEP%4==0");
    static_assert(OCW == 4 || OCW == 8, "OCW must be 4 or 8");

    __shared__ float xs[CC][XROW];
    __shared__ float wls[CC * NWR * OCB];
    __shared__ float scs[NC], shs[NC];

    const int b = blockIdx.z, ocb = blockIdx.y, tid = threadIdx.x;
    const int t0 = blockIdx.x * PT, lane = tid & 63;
    const int wid = tid >> 6;
    const int oc0 = ocb * OCB + wid * OCW;
    const int gb = UPS ? (t0 - 1) : (t0 * STRIDE - PAD);

    if (INMODE > 0) {
        for (int c = tid; c < NC; c += 256) {
            float m  = stp[c] * inv_n;
            float va = stp[NC + c] * inv_n - m * m;
            float sc = gp[c] * rsqrtf(va + 1e-5f);
            scs[c] = sc;
            shs[c] = btp[c] - m * sc;
        }
        __syncthreads();
    }

    float acc[OCW][TTO];
#pragma unroll
    for (int i = 0; i < OCW; i++)
#pragma unroll
        for (int j = 0; j < TTO; j++) acc[i][j] = 0.f;

    float pre[NLD][4];

#define C7_STAGEW(CCBASE) do {                                              \
    for (int _u = tid; _u < NWQ; _u += 256) {                               \
        int _row = _u / (OCB / 4), _g8 = _u % (OCB / 4);                    \
        int _cl = _row / NWR, _t = _row % NWR;                              \
        ((float4*)wls)[_u] = *(const float4*)(wp +                          \
            ((size_t)((CCBASE) + _cl) * NWR + _t) * 128 + ocb * OCB + _g8 * 4); \
    }                                                                       \
} while (0)

#define C7_COMPCI(CI) do {                                                  \
    float _q[XSPAN];                                                        \
    const int _qb4 = lane * (STEP / 4);                                     \
    _Pragma("unroll")                                                       \
    for (int _u = 0; _u < XSPAN / 4; _u++) {                                \
        float4 _v = *(const float4*)&xs[CI][4 * swz4(_qb4 + _u)];           \
        _q[4*_u] = _v.x; _q[4*_u+1] = _v.y;                                 \
        _q[4*_u+2] = _v.z; _q[4*_u+3] = _v.w;                               \
    }                                                                       \
    if constexpr ((XSPAN & 3) != 0) {                                       \
        const int _pt = swz4(_qb4 + XSPAN / 4);                             \
        if constexpr ((XSPAN & 3) >= 2) {                                   \
            float2 _v = *(const float2*)&xs[CI][4 * _pt];                   \
            _q[(XSPAN & ~3)] = _v.x; _q[(XSPAN & ~3) + 1] = _v.y;           \
        }                                                                   \
        if constexpr ((XSPAN & 3) == 1)                                     \
            _q[XSPAN - 1] = xs[CI][4 * _pt];                                \
        else if constexpr ((XSPAN & 3) == 3)                                \
            _q[XSPAN - 1] = xs[CI][4 * _pt + 2];                            \
    }                                                                       \
    {                                                                       \
        _Pragma("unroll")                                                   \
        for (int _k = 0; _k < KW; _k++) {                                   \
            if constexpr (OCW == 8) {                                       \
                const float4 _w0 = *(const float4*)&wls[((CI) * NWR + _k) * OCB + wid * 8];     \
                const float4 _w1 = *(const float4*)&wls[((CI) * NWR + _k) * OCB + wid * 8 + 4]; \
                _Pragma("unroll")                                           \
                for (int _i = 0; _i < 8; _i++) {                            \
                    float _wv = f4c(_i < 4 ? _w0 : _w1, _i & 3);            \
                    _Pragma("unroll")                                       \
                    for (int _j = 0; _j < TT; _j++)                         \
                        acc[_i][_j] = fmaf(_wv, _q[_j * STRIDE + _k], acc[_i][_j]); \
                }                                                           \
            } else {                                                        \
                const float4 _w0 = *(const float4*)&wls[((CI) * NWR + _k) * OCB + wid * 4];     \
                _Pragma("unroll")                                           \
                for (int _i = 0; _i < 4; _i++) {                            \
                    float _wv = f4c(_w0, _i);                               \
                    _Pragma("unroll")                                       \
                    for (int _j = 0; _j < TT; _j++)                         \
                        acc[_i][_j] = fmaf(_wv, _q[_j * STRIDE + _k], acc[_i][_j]); \
                }                                                           \
            }                                                               \
        }                                                                   \
    }                                                                       \
} while (0)

#pragma unroll
    for (int u = 0; u < NLD; u++) {
        int idx = tid + u * 256;
        if (idx < CC * NCH) {
            int cl = idx / NCH, q = idx - cl * NCH;
            loadg4(in + ((size_t)b * NC + cl) * L_in, gb + 4 * q, L_in, pre[u]);
        }
    }
#pragma unroll
    for (int u = 0; u < NLD; u++) {
        int idx = tid + u * 256;
        if (idx < CC * NCH) {
            int cl = idx / NCH, q = idx - cl * NCH;
            int g0 = gb + 4 * q;
            float e[4];
#pragma unroll
            for (int t = 0; t < 4; t++) {
                float v = pre[u][t];
                if (INMODE > 0) {
                    int gg = g0 + t;
                    if (gg >= 0 && gg < L_in) {
                        float s = v * scs[cl] + shs[cl];
                        v = (INMODE == 2) ? lrelu(s) : s;
                    }
                }
                e[t] = v;
            }
            *(float4*)&xs[cl][4 * swz4(q)] = make_float4(e[0], e[1], e[2], e[3]);
        }
    }
    C7_STAGEW(0);
    __syncthreads();

    for (int cc = 0; cc < NC; cc += CC) {
        if (cc + CC < NC) {
#pragma unroll
            for (int u = 0; u < NLD; u++) {
                int idx = tid + u * 256;
                if (idx < CC * NCH) {
                    int cl = idx / NCH, q = idx - cl * NCH;
                    loadg4(in + ((size_t)b * NC + cc + CC + cl) * L_in,
                           gb + 4 * q, L_in, pre[u]);
                }
            }
        }
#pragma unroll
        for (int ci = 0; ci < CC; ci++) {
            C7_COMPCI(ci);
        }
        __syncthreads();
        if (cc + CC < NC) {
#pragma unroll
            for (int u = 0; u < NLD; u++) {
                int idx = tid + u * 256;
                if (idx < CC * NCH) {
                    int cl = idx / NCH, q = idx - cl * NCH;
                    int g0 = gb + 4 * q;
                    int c = cc + CC + cl;
                    float e[4];
#pragma unroll
                    for (int t = 0; t < 4; t++) {
                        float v = pre[u][t];
                        if (INMODE > 0) {
                            int gg = g0 + t;
                            if (gg >= 0 && gg < L_in) {
                                float s = v * scs[c] + shs[c];
                                v = (INMODE == 2) ? lrelu(s) : s;
                            }
                        }
                        e[t] = v;
                    }
                    *(float4*)&xs[cl][4 * swz4(q)] = make_float4(e[0], e[1], e[2], e[3]);
                }
            }
            C7_STAGEW(cc + CC);
            __syncthreads();
        }
    }
#undef C7_STAGEW
#undef C7_COMPCI

    const int po = t0 + lane * TTO;
#pragma unroll
    for (int i = 0; i < OCW; i++) {
        const int o = oc0 + i;
        const float bv = bias[o];
        float s1 = 0.f, s2 = 0.f;
        float tmpm[TTO];
#pragma unroll
        for (int j = 0; j < TTO; j++) {
            float v = acc[i][j] + bv;
            if (OUTACT) v = lrelu(v);
            tmpm[j] = v;
            if (STATS) { s1 += v; s2 += v * v; }
        }
        float* orow = out + ((size_t)b * NC + o) * L_out + po;
        if constexpr (TTO == 4)
            *(float4*)orow = make_float4(tmpm[0], tmpm[1], tmpm[2], tmpm[3]);
        else if constexpr (TTO == 2)
            *(float2*)orow = make_float2(tmpm[0], tmpm[1]);
        else
            orow[0] = tmpm[0];
        if (STATS) {
#pragma unroll
            for (int m = 1; m < 64; m <<= 1) {
                s1 += __shfl_xor(s1, m);
                s2 += __shfl_xor(s2, m);
            }
            if (lane == 0) {
                atomicAdd(&stats[o], s1);
                atomicAdd(&stats[NC + o], s2);
            }
        }
    }
}

// ---------------------------------------------------------------------------
__global__ __launch_bounds__(256) void cvtW_k(const float* __restrict__ W,
                                              unsigned short* __restrict__ Wbf)
{
    int i = blockIdx.x * 256 + threadIdx.x;
    const float4 a = *(const float4*)&W[i * 8];
    const float4 b = *(const float4*)&W[i * 8 + 4];
    unsigned pk[4];
    pk[0] = bf16r(a.x) | (bf16r(a.y) << 16);
    pk[1] = bf16r(a.z) | (bf16r(a.w) << 16);
    pk[2] = bf16r(b.x) | (bf16r(b.y) << 16);
    pk[3] = bf16r(b.z) | (bf16r(b.w) << 16);
    *(uint4*)&Wbf[i * 8] = make_uint4(pk[0], pk[1], pk[2], pk[3]);
}

// ---------------------------------------------------------------------------
// salM2: MFMA bf16 GEMM over (128h x 128l) tiles (unchanged).
// ---------------------------------------------------------------------------
template<int PHASE>
__global__ __launch_bounds__(256) void salM2_k(
    const unsigned short* __restrict__ xT, const unsigned short* __restrict__ Wbf,
    const float* __restrict__ bias, float* __restrict__ gsum,
    unsigned* __restrict__ ghist, const unsigned* __restrict__ thrv,
    unsigned* __restrict__ candcnt, unsigned* __restrict__ candI)
{
    __shared__ unsigned short Als[128 * 128];
    __shared__ unsigned short Bls[128 * 128];

    const int b  = blockIdx.z;
    const int h0 = blockIdx.y * 128;
    const int l0 = blockIdx.x * 128;
    const int tid = threadIdx.x;
    const int lane = tid & 63;
    const int wid = tid >> 6;
    const int wh = (wid >> 1) * 64;
    const int wl = (wid & 1) * 64;

    {
        const uint4* gA = (const uint4*)(Wbf + (size_t)h0 * NC);
        const uint4* gB = (const uint4*)(xT + ((size_t)b * LFULL + l0) * NC);
        char* cA = (char*)Als; char* cB = (char*)Bls;
        for (int i = tid; i < 2048; i += 256) {
            int row = i >> 4, q = i & 15;
            unsigned sw = (unsigned)(row * 256 + q * 16) ^ (((unsigned)(row & 7)) << 4);
            *(uint4*)(cA + sw) = gA[i];
        }
        for (int i = tid; i < 2048; i += 256) {
            int row = i >> 4, q = i & 15;
            unsigned sw = (unsigned)(row * 256 + q * 16) ^ (((unsigned)(row & 7)) << 4);
            *(uint4*)(cB + sw) = gB[i];
        }
    }
    __syncthreads();

    f32x4 acc[4][4];
#pragma unroll
    for (int i = 0; i < 4; i++)
#pragma unroll
        for (int j = 0; j < 4; j++) acc[i][j] = (f32x4)(0.f);

    const int r15 = lane & 15, g = lane >> 4;
#pragma unroll
    for (int ks = 0; ks < 4; ks++) {
        bf16x8 af[4], bfv[4];
#pragma unroll
        for (int f = 0; f < 4; f++) {
            int rowA = wh + f * 16 + r15;
            unsigned offA = (unsigned)(rowA * 256 + ks * 64 + g * 16)
                          ^ (((unsigned)(rowA & 7)) << 4);
            af[f] = *(const bf16x8*)((const char*)Als + offA);
            int rowB = wl + f * 16 + r15;
            unsigned offB = (unsigned)(rowB * 256 + ks * 64 + g * 16)
                          ^ (((unsigned)(rowB & 7)) << 4);
            bfv[f] = *(const bf16x8*)((const char*)Bls + offB);
        }
#pragma unroll
        for (int i = 0; i < 4; i++)
#pragma unroll
            for (int j = 0; j < 4; j++)
                acc[i][j] = __builtin_amdgcn_mfma_f32_16x16x32_bf16(
                    af[i], bfv[j], acc[i][j], 0, 0, 0);
    }

    if constexpr (PHASE == 0) {
        __syncthreads();
        unsigned* lhist = (unsigned*)Als;
        for (int i = tid; i < 8192; i += 256) lhist[i] = 0;
        __syncthreads();
        unsigned* myh = lhist + (tid & 1) * 4096;
        float expsum = 0.f;
#pragma unroll
        for (int i = 0; i < 4; i++) {
#pragma unroll
            for (int r = 0; r < 4; r++) {
                const int h = h0 + wh + i * 16 + g * 4 + r;
                const float bv = bias[h];
#pragma unroll
                for (int j = 0; j < 4; j++) {
                    float v = acc[i][j][r] + bv;
                    expsum += expf(v);
                    atomicAdd(&myh[monoKey16(bf16r(v)) >> 4], 1u);
                }
            }
        }
#pragma unroll
        for (int m = 1; m < 64; m <<= 1) expsum += __shfl_xor(expsum, m);
        float* red = (float*)Bls;
        if (lane == 0) red[wid] = expsum;
        __syncthreads();
        for (int i = tid; i < 4096; i += 256) {
            unsigned s = lhist[i] + lhist[4096 + i];
            if (s) atomicAdd(&ghist[b * 4096 + i], s);
        }
        if (tid == 0) atomicAdd(&gsum[b], red[0] + red[1] + red[2] + red[3]);
    } else {
        const unsigned thr = thrv[b * 2];
#pragma unroll
        for (int i = 0; i < 4; i++) {
#pragma unroll
            for (int r = 0; r < 4; r++) {
                const int h = h0 + wh + i * 16 + g * 4 + r;
                const float bv = bias[h];
#pragma unroll
                for (int j = 0; j < 4; j++) {
                    float v = acc[i][j][r] + bv;
                    bool pr = monoKey16(bf16r(v)) >= thr;
                    unsigned long long m = __ballot(pr);
                    if (m) {
                        int leader = __ffsll((unsigned long long)m) - 1;
                        int cnt = __popcll(m);
                        unsigned basepos = 0;
                        if (lane == leader)
                            basepos = atomicAdd(&candcnt[b], (unsigned)cnt);
                        basepos = __shfl(basepos, leader);
                        if (pr) {
                            int rr = __popcll(m & ((1ull << lane) - 1ull));
                            unsigned pos = basepos + (unsigned)rr;
                            if (pos < CAP) {
                                int l = l0 + wl + j * 16 + r15;
                                candI[b * CAP + pos] = (unsigned)((h << 13) | l);
                            }
                        }
                    }
                }
            }
        }
    }
}

// ---------------------------------------------------------------------------
__global__ __launch_bounds__(256) void scan2_k(
    const unsigned* __restrict__ ghist, unsigned* __restrict__ thrv)
{
    const int b = blockIdx.x, tid = threadIdx.x;
    __shared__ unsigned part[256];
    unsigned s = 0;
#pragma unroll
    for (int i = 0; i < 16; i++) s += ghist[b * 4096 + tid * 16 + i];
    part[tid] = s;
    __syncthreads();
    if (tid == 0) {
        unsigned cum = 0; int ch;
        for (ch = 255; ch >= 0; ch--) {
            if (cum + part[ch] >= KSEL) break;
            cum += part[ch];
        }
        int bin = 0;
        if (ch >= 0) {
            for (bin = ch * 16 + 15; bin > ch * 16; bin--) {
                unsigned c = ghist[b * 4096 + bin];
                if (cum + c >= KSEL) break;
                cum += c;
            }
        }
        int bcol = bin > 0 ? bin - 1 : 0;
        thrv[b * 2] = (unsigned)bcol << 4;
    }
}

__global__ __launch_bounds__(128) void recompute_k(
    const unsigned* __restrict__ candcnt, const unsigned* __restrict__ candI,
    const float* __restrict__ xu, const float* __restrict__ W,
    const float* __restrict__ bias, unsigned* __restrict__ candK)
{
    const int b = blockIdx.y;
    const unsigned cnt = min(candcnt[b], (unsigned)CAP);
    const int t = threadIdx.x;
    __shared__ float wsum[2];
    for (unsigned k = blockIdx.x; k < cnt; k += 1024) {
        unsigned e = candI[b * CAP + k];
        int h = e >> 13, l = e & 8191;
        float prod = W[h * NC + t] * xu[(b * NC + t) * LFULL + l];
#pragma unroll
        for (int m = 1; m < 64; m <<= 1) prod += __shfl_xor(prod, m);
        if ((t & 63) == 0) wsum[t >> 6] = prod;
        __syncthreads();
        if (t == 0) candK[b * CAP + k] = monoKey(wsum[0] + wsum[1] + bias[h]);
        __syncthreads();
    }
}

__global__ __launch_bounds__(256) void select2_k(
    const unsigned* __restrict__ candcnt, const unsigned* __restrict__ candK,
    const unsigned* __restrict__ candI,
    uint2* __restrict__ selected, unsigned* __restrict__ selcnt)
{
    const int b = blockIdx.x, tid = threadIdx.x;
    __shared__ unsigned h1[4096];
    __shared__ unsigned l2k[2048], l2i[2048];
    __shared__ unsigned part[256];
    __shared__ unsigned sh[8];

    const unsigned Nc = min(candcnt[b], (unsigned)CAP);
    const unsigned* kk = candK + b * CAP;
    const unsigned* ii = candI + b * CAP;
    uint2* sel = selected + b * KSEL;

    for (int i = tid; i < 4096; i += 256) h1[i] = 0;
    if (tid < 8) sh[tid] = 0;
    __syncthreads();
    for (unsigned i = tid; i < Nc; i += 256) atomicAdd(&h1[kk[i] >> 20], 1u);
    __syncthreads();
    {
        unsigned s = 0;
#pragma unroll
        for (int i = 0; i < 16; i++) s += h1[tid * 16 + i];
        part[tid] = s;
        __syncthreads();
        if (tid == 0) {
            unsigned cum = 0; int ch;
            for (ch = 255; ch >= 0; ch--) { if (cum + part[ch] >= KSEL) break; cum += part[ch]; }
            int bin = 0;
            if (ch >= 0)
                for (bin = ch * 16 + 15; bin > ch * 16; bin--) {
                    unsigned c = h1[bin];
                    if (cum + c >= KSEL) break;
                    cum += c;
                }
            sh[2] = (unsigned)bin; sh[3] = KSEL - cum;
        }
    }
    __syncthreads();
    const unsigned b1 = sh[2], need1 = sh[3];
    for (int i = tid; i < 1024; i += 256) h1[i] = 0;
    __syncthreads();
    for (unsigned i = tid; i < Nc; i += 256) {
        unsigned k = kk[i], bin = k >> 20;
        if (bin > b1) {
            unsigned p = atomicAdd(&sh[0], 1u);
            if (p < KSEL) sel[p] = make_uint2(k, ii[i]);
        } else if (bin == b1) {
            atomicAdd(&h1[(k >> 10) & 1023], 1u);
        }
    }
    __syncthreads();
    {
        unsigned s = 0;
#pragma unroll
        for (int i = 0; i < 4; i++) s += h1[tid * 4 + i];
        part[tid] = s;
        __syncthreads();
        if (tid == 0) {
            unsigned cum = 0; int ch;
            for (ch = 255; ch >= 0; ch--) { if (cum + part[ch] >= need1) break; cum += part[ch]; }
            int bin = 0;
            if (ch >= 0)
                for (bin = ch * 4 + 3; bin > ch * 4; bin--) {
                    unsigned c = h1[bin];
                    if (cum + c >= need1) break;
                    cum += c;
                }
            sh[4] = (unsigned)bin; sh[5] = need1 - cum;
        }
    }
    __syncthreads();
    const unsigned b2 = sh[4], need2 = sh[5];
    for (int i = tid; i < 1024; i += 256) h1[i] = 0;
    __syncthreads();
    for (unsigned i = tid; i < Nc; i += 256) {
        unsigned k = kk[i];
        if ((k >> 20) != b1) continue;
        unsigned mb = (k >> 10) & 1023;
        if (mb > b2) {
            unsigned p = atomicAdd(&sh[0], 1u);
            if (p < KSEL) sel[p] = make_uint2(k, ii[i]);
        } else if (mb == b2) {
            unsigned j = atomicAdd(&sh[1], 1u);
            if (j < 2048) { l2k[j] = k; l2i[j] = ii[i]; atomicAdd(&h1[k & 1023], 1u); }
        }
    }
    __syncthreads();
    const unsigned m2 = min(sh[1], 2048u);
    {
        unsigned s = 0;
#pragma unroll
        for (int i = 0; i < 4; i++) s += h1[tid * 4 + i];
        part[tid] = s;
        __syncthreads();
        if (tid == 0) {
            unsigned cum = 0; int ch;
            for (ch = 255; ch >= 0; ch--) { if (cum + part[ch] >= need2) break; cum += part[ch]; }
            int bin = 0;
            if (ch >= 0)
                for (bin = ch * 4 + 3; bin > ch * 4; bin--) {
                    unsigned c = h1[bin];
                    if (cum + c >= need2) break;
                    cum += c;
                }
            sh[6] = (unsigned)bin; sh[7] = need2 - cum;
        }
    }
    __syncthreads();
    const unsigned b3 = sh[6], need3 = sh[7];
    if (tid == 0) sh[1] = 0;
    __syncthreads();
    for (unsigned i = tid; i < m2; i += 256) {
        unsigned k = l2k[i], lb = k & 1023;
        if (lb > b3) {
            unsigned p = atomicAdd(&sh[0], 1u);
            if (p < KSEL) sel[p] = make_uint2(k, l2i[i]);
        } else if (lb == b3) {
            unsigned t = atomicAdd(&sh[1], 1u);
            if (t < need3) {
                unsigned p = atomicAdd(&sh[0], 1u);
                if (p < KSEL) sel[p] = make_uint2(k, l2i[i]);
            }
        }
    }
    __syncthreads();
    if (tid == 0) selcnt[b] = min(sh[0], (unsigned)KSEL);
}

// ---------------------------------------------------------------------------
// scatter2_k: compute g = sig * softmax_val per selection; store only g.
// ---------------------------------------------------------------------------
__global__ __launch_bounds__(128) void scatter2_k(
    const uint2* __restrict__ selected, const unsigned* __restrict__ selcnt,
    const float* __restrict__ gsum, const float* __restrict__ xu,
    const float* __restrict__ upw, const float* __restrict__ upb,
    float* __restrict__ gval)
{
    const int b = blockIdx.y, kidx = blockIdx.x;
    if (kidx >= (int)selcnt[b]) return;
    const uint2 s = selected[b * KSEL + kidx];
    const float salv = keyToF(s.x);
    const unsigned idx = s.y;
    const int h = idx >> 13, l = idx & 8191;
    const int t = threadIdx.x;

    float prod = upw[h * NC + t] * xu[(b * NC + t) * LFULL + l];
#pragma unroll
    for (int m = 1; m < 64; m <<= 1) prod += __shfl_xor(prod, m);
    __shared__ float wsum[2];
    if ((t & 63) == 0) wsum[t >> 6] = prod;
    __syncthreads();
    if (t == 0) {
        const float sig = wsum[0] + wsum[1] + upb[h];
        gval[b * KSEL + kidx] = sig * (expf(salv) / gsum[b]);
    }
}

// ---------------------------------------------------------------------------
// dnconst_k: per-channel analytic conv-of-bias constants for dn0.
//  cstI[o] = sum_c sum_{k=0..6} W0[o][c][k]*dnb[c] + dn_b0[o]   (interior)
//  cst0[o] = sum_c sum_{k=3..6} W0[o][c][k]*dnb[c] + dn_b0[o]   (t == 0)
// ---------------------------------------------------------------------------
__global__ __launch_bounds__(128) void dnconst_k(
    const float* __restrict__ dn_w, const float* __restrict__ dnb,
    const float* __restrict__ dn_b0, float* __restrict__ cst)
{
    const int o = threadIdx.x;
    float accA = 0.f, accE = 0.f;
    for (int c = 0; c < NC; c++) {
        const float bv = dnb[c];
        const float* wp = dn_w + ((size_t)o * NC + c) * 7;
#pragma unroll
        for (int k = 0; k < 7; k++) {
            float w = wp[k];
            accA += w * bv;
            if (k >= 3) accE += w * bv;
        }
    }
    cst[o]       = accA + dn_b0[o];   // interior pre-activation
    cst[NC + o]  = accE + dn_b0[o];   // t==0 pre-activation
}

// ---------------------------------------------------------------------------
// fillpre_k: fill dn0 pre-activation buffer [b][o][2048] with constants.
// ---------------------------------------------------------------------------
__global__ __launch_bounds__(256) void fillpre_k(
    const float* __restrict__ cst, float* __restrict__ pre)
{
    // one block per (b,o) row: 256 threads x 2 float4
    const int row = blockIdx.x;            // b*128 + o
    const int o = row & 127;
    const float vI = cst[o], v0 = cst[NC + o];
    float4* p = (float4*)(pre + (size_t)row * 2048);
#pragma unroll
    for (int u = 0; u < 2; u++) {
        int q = threadIdx.x + u * 256;     // f4 index 0..511
        float4 v = make_float4(vI, vI, vI, vI);
        if (q == 0) v.x = v0;
        p[q] = v;
    }
}

// ---------------------------------------------------------------------------
// corrdn_k: sparse corrections.  For selection (h,l,g): delta[c]=dww[c][h]*g;
// affected outputs t with k=l-4t+3 in [0,6]; corr[o] = sum_c W0p[c][k][o]*delta.
// W0p = wprep dn0 region, layout [c][k][128o].
// ---------------------------------------------------------------------------
__global__ __launch_bounds__(128) void corrdn_k(
    const uint2* __restrict__ selected, const unsigned* __restrict__ selcnt,
    const float* __restrict__ gval, const float* __restrict__ dww,
    const float* __restrict__ w0p, float* __restrict__ pre)
{
    const int b = blockIdx.y, kidx = blockIdx.x;
    if (kidx >= (int)selcnt[b]) return;
    const unsigned idx = selected[b * KSEL + kidx].y;
    const int h = idx >> 13, l = idx & 8191;
    const float g = gval[b * KSEL + kidx];
    const int o = threadIdx.x;

    __shared__ float dlt[NC];
    dlt[o] = dww[o * NH + h] * g;
    __syncthreads();

    const int tlo = (l <= 3) ? 0 : ((l - 3 + 3) >> 2);
    const int thi = min(2047, (l + 3) >> 2);
    for (int t = tlo; t <= thi; t++) {
        const int k = l - 4 * t + 3;     // in [0,6]
        float corr = 0.f;
#pragma unroll 4
        for (int c = 0; c < NC; c++)
            corr += w0p[(size_t)c * 896 + k * 128 + o] * dlt[c];
        atomicAdd(&pre[((size_t)b * NC + o) * 2048 + t], corr);
    }
}

// ---------------------------------------------------------------------------
// actstats_k: in-place lrelu on pre + per-channel sum/sumsq -> stats.
// One block per (b,o) row.
// ---------------------------------------------------------------------------
__global__ __launch_bounds__(256) void actstats_k(
    float* __restrict__ pre, float* __restrict__ stats)
{
    const int row = blockIdx.x;            // b*128 + o
    const int o = row & 127;
    float4* p = (float4*)(pre + (size_t)row * 2048);
    float s1 = 0.f, s2 = 0.f;
#pragma unroll
    for (int u = 0; u < 2; u++) {
        int q = threadIdx.x + u * 256;
        float4 v = p[q];
        float e[4] = {v.x, v.y, v.z, v.w};
#pragma unroll
        for (int t = 0; t < 4; t++) {
            float a = lrelu(e[t]);
            e[t] = a;
            s1 += a; s2 += a * a;
        }
        p[q] = make_float4(e[0], e[1], e[2], e[3]);
    }
#pragma unroll
    for (int m = 1; m < 64; m <<= 1) {
        s1 += __shfl_xor(s1, m);
        s2 += __shfl_xor(s2, m);
    }
    __shared__ float red[8];
    const int lane = threadIdx.x & 63, wid = threadIdx.x >> 6;
    if (lane == 0) { red[wid] = s1; red[4 + wid] = s2; }
    __syncthreads();
    if (threadIdx.x == 0) {
        atomicAdd(&stats[o],      red[0] + red[1] + red[2] + red[3]);
        atomicAdd(&stats[NC + o], red[4] + red[5] + red[6] + red[7]);
    }
}

// ---------------------------------------------------------------------------
__global__ void apply_k(const float* __restrict__ in, const float* __restrict__ stats,
                        const float* __restrict__ g, const float* __restrict__ bt,
                        float* __restrict__ out, float inv_n)
{
    int i = blockIdx.x * 256 + threadIdx.x;
    int c = (i >> 7) & 127;
    float m  = stats[c] * inv_n;
    float va = stats[NC + c] * inv_n - m * m;
    float sc = g[c] * rsqrtf(va + 1e-5f);
    out[i] = in[i] * sc + (bt[c] - m * sc);
}

// ---------------------------------------------------------------------------
extern "C" void kernel_launch(void* const* d_in, const int* in_sizes, int n_in,
                              void* d_out, int out_size, void* d_ws, size_t ws_size,
                              hipStream_t stream)
{
    const float* x        = (const float*)d_in[0];
    const float* up_w     = (const float*)d_in[1];
    const float* up_b     = (const float*)d_in[2];
    const float* up_g     = (const float*)d_in[3];
    const float* up_beta  = (const float*)d_in[4];
    const float* up_out_w = (const float*)d_in[5];
    const float* up_out_b = (const float*)d_in[6];
    const float* sb_up_w  = (const float*)d_in[7];
    const float* sb_up_b  = (const float*)d_in[8];
    const float* sal_w    = (const float*)d_in[9];
    const float* sal_b    = (const float*)d_in[10];
    const float* sb_dn_w  = (const float*)d_in[11];
    const float* sb_dn_b  = (const float*)d_in[12];
    const float* dn_w     = (const float*)d_in[13];
    const float* dn_b     = (const float*)d_in[14];
    const float* dn_g     = (const float*)d_in[15];
    const float* dn_beta  = (const float*)d_in[16];

    char* ws = (char*)d_ws;
    float*          stats    = (float*)(ws + 0);
    float*          gsum     = (float*)(ws + 16384);
    unsigned*       thrv     = (unsigned*)(ws + 16416);
    unsigned*       candcnt  = (unsigned*)(ws + 16480);
    unsigned*       selcnt   = (unsigned*)(ws + 16512);
    uint2*          selected = (uint2*)(ws + 16640);
    unsigned*       ghist    = (unsigned*)(ws + 49408);
    unsigned*       candK    = (unsigned*)(ws + 180480);
    unsigned*       candI    = (unsigned*)(ws + 1229056);
    unsigned short* Wbf      = (unsigned short*)(ws + 2277632);
    float*          wprep    = (float*)(ws + 2539776);
    float*          B0       = (float*)(ws + 5685504);
    float*          B1       = (float*)(ws + 39239936);
    unsigned short* xT       = (unsigned short*)(ws + 72794368);
    unsigned short* Afrag    = (unsigned short*)(ws + 117440512);
    float*          partial  = (float*)(ws + 121634816);
    float*          gval     = (float*)(ws + 122159104);  // 8x512 f32
    float*          cst      = (float*)(ws + 122175488);  // 256 f32

    hipMemsetAsync(d_ws, 0, 16544, stream);
    hipMemsetAsync(ws + 49408, 0, 131072, stream);

    cvtW_k<<<64,256,0,stream>>>(sal_w, Wbf);
    prep_k<<<3072,256,0,stream>>>(up_w, up_out_w, dn_w, wprep);
    prepA_k<<<864,256,0,stream>>>(up_w, up_out_w, Afrag);

    // ---- ConvUpsample (MFMA, 8-wave blocks): 128 -> 8192 frames ----
    mconvU_k<0><<<dim3(2,NB),512,0,stream>>>(
        x, B0, Afrag, up_b, nullptr, nullptr, nullptr, 0.f, partial, 128);
    redstats_k<<<16,256,0,stream>>>(partial, 2*NB, stats);
    mconvU_k<2><<<dim3(4,NB),512,0,stream>>>(
        B0, B1, Afrag + 1*262144, up_b + NC,
        stats, up_g, up_beta, 1.f/(float)(NB*256), partial, 256);
    redstats_k<<<16,256,0,stream>>>(partial, 4*NB, stats + 256);
    mconvU_k<2><<<dim3(8,NB),512,0,stream>>>(
        B1, B0, Afrag + 2*262144, up_b + 2*NC,
        stats + 256, up_g + NC, up_beta + NC, 1.f/(float)(NB*512), partial, 512);
    redstats_k<<<16,256,0,stream>>>(partial, 8*NB, stats + 2*256);
    mconvU_k<2><<<dim3(16,NB),512,0,stream>>>(
        B0, B1, Afrag + 3*262144, up_b + 3*NC,
        stats + 2*256, up_g + 2*NC, up_beta + 2*NC, 1.f/(float)(NB*1024), partial, 1024);
    redstats_k<<<16,256,0,stream>>>(partial, 16*NB, stats + 3*256);
    mconvU_k<2><<<dim3(32,NB),512,0,stream>>>(
        B1, B0, Afrag + 4*262144, up_b + 4*NC,
        stats + 3*256, up_g + 3*NC, up_beta + 3*NC, 1.f/(float)(NB*2048), partial, 2048);
    redstats_k<<<16,256,0,stream>>>(partial, 32*NB, stats + 4*256);
    mconvU_k<2><<<dim3(64,NB),512,0,stream>>>(
        B0, B1, Afrag + 5*262144, up_b + 5*NC,
        stats + 4*256, up_g + 4*NC, up_beta + 4*NC, 1.f/(float)(NB*4096), partial, 4096);
    redstats_k<<<16,256,0,stream>>>(partial, 64*NB, stats + 5*256);
    // final k3 conv (MFMA): B1 -> B0 (f32 x_up) + xT (bf16 transposed)
    mconvF_k<<<dim3(64,NB),512,0,stream>>>(
        B1, B0, Afrag, up_out_b,
        stats + 5*256, up_g + 5*NC, up_beta + 5*NC, 1.f/(float)(NB*LFULL), xT);

    // ---- SparseBottleneck ----
    salM2_k<0><<<dim3(64,8,NB),256,0,stream>>>(xT, Wbf, sal_b, gsum, ghist,
                                               nullptr, nullptr, nullptr);
    scan2_k<<<NB,256,0,stream>>>(ghist, thrv);
    salM2_k<1><<<dim3(64,8,NB),256,0,stream>>>(xT, Wbf, sal_b, nullptr, nullptr,
                                               thrv, candcnt, candI);
    recompute_k<<<dim3(1024,NB),128,0,stream>>>(candcnt, candI, B0, sal_w, sal_b, candK);
    select2_k<<<NB,256,0,stream>>>(candcnt, candK, candI, selected, selcnt);
    scatter2_k<<<dim3(KSEL,NB),128,0,stream>>>(selected, selcnt, gsum, B0,
                                               sb_up_w, sb_up_b, gval);

    // ---- dn0 (algebraic): const-fill + sparse corrections + act/stats ----
    dnconst_k<<<1,128,0,stream>>>(dn_w, sb_dn_b, dn_b, cst);
    fillpre_k<<<NB*NC,256,0,stream>>>(cst, B1);
    corrdn_k<<<dim3(KSEL,NB),128,0,stream>>>(selected, selcnt, gval, sb_dn_w,
                                             wprep + 442368, B1);
    actstats_k<<<NB*NC,256,0,stream>>>(B1, stats + 6*256);

    // ---- dn1/dn2 (VALU, swizzled, OCW4): 2048 -> 128 ----
    conv7_k<7,4,3,false,1,true,true,1,false,4><<<dim3(8,8,NB),256,0,stream>>>(
        B1, B0, wprep + 442368 + 114688, dn_b + NC,
        stats + 6*256, dn_g, dn_beta, 1.f/(float)(NB*2048),
        stats + 7*256, nullptr, 2048, 512);
    conv7_k<7,4,3,false,1,true,true,1,false,4><<<dim3(2,8,NB),256,0,stream>>>(
        B0, B1, wprep + 442368 + 2*114688, dn_b + 2*NC,
        stats + 7*256, dn_g + NC, dn_beta + NC, 1.f/(float)(NB*512),
        stats + 8*256, nullptr, 512, 128);

    apply_k<<<(out_size + 255)/256,256,0,stream>>>(
        B1, stats + 8*256, dn_g + 2*NC, dn_beta + 2*NC, (float*)d_out,
        1.f/(float)(NB*128));
}

// Round 19
// 642.033 us; speedup vs baseline: 1.5709x; 1.0209x over previous
//
#include <hip/hip_runtime.h>
#include <hip/hip_bf16.h>

// ---------------------------------------------------------------------------
// ExpandAndContractBottleneck.  R19: salM2 epilogues cut -- __expf (native),
// 4-replica LDS histogram, per-tile max-key lets phase 1 skip candidate-free
// tiles entirely (exact: skip iff tile max key < threshold).
// ---------------------------------------------------------------------------

#define DEV_INLINE __device__ __forceinline__

constexpr int NB   = 8;
constexpr int NC   = 128;
constexpr int NH   = 1024;
constexpr int LFULL= 8192;
constexpr int KSEL = 512;
constexpr int CAP  = 32768;

typedef __attribute__((ext_vector_type(4))) float f32x4;
typedef __attribute__((ext_vector_type(8))) short bf16x8;

DEV_INLINE unsigned monoKey(float f) {
    unsigned u = __float_as_uint(f);
    return (u & 0x80000000u) ? ~u : (u | 0x80000000u);
}
DEV_INLINE float keyToF(unsigned k) {
    unsigned u = (k & 0x80000000u) ? (k ^ 0x80000000u) : ~k;
    return __uint_as_float(u);
}
DEV_INLINE unsigned monoKey16(unsigned u) {
    return (u & 0x8000u) ? ((~u) & 0xFFFFu) : (u | 0x8000u);
}
DEV_INLINE unsigned bf16r(float f) {
    unsigned u = __float_as_uint(f);
    return (u + 0x7FFFu + ((u >> 16) & 1u)) >> 16;
}
DEV_INLINE float lrelu(float v) { return v >= 0.f ? v : 0.2f * v; }
DEV_INLINE float f4c(const float4& v, int k) {
    return k == 0 ? v.x : k == 1 ? v.y : k == 2 ? v.z : v.w;
}
DEV_INLINE int swz4(int p) { return p ^ ((p >> 3) & 7); }

DEV_INLINE void loadg4(const float* __restrict__ rowp, int g0, int L, float* e) {
    if (g0 >= 0 && g0 + 4 <= L) {
        float4 v = *(const float4*)(rowp + g0);
        e[0] = v.x; e[1] = v.y; e[2] = v.z; e[3] = v.w;
    } else {
#pragma unroll
        for (int t = 0; t < 4; t++) {
            int g = g0 + t;
            e[t] = (g >= 0 && g < L) ? rowp[g] : 0.f;
        }
    }
}

// ---------------------------------------------------------------------------
// prep_k: VALU dn weights [c][tap][128 oc].
// ---------------------------------------------------------------------------
__global__ __launch_bounds__(256) void prep_k(
    const float* __restrict__ up_w, const float* __restrict__ up_out_w,
    const float* __restrict__ dn_w, float* __restrict__ wprep)
{
    int idx = blockIdx.x * 256 + threadIdx.x;
    if (idx < 393216) {
        int layer = idx >> 16;
        int r0 = idx & 65535;
        int c = r0 >> 9, r = (r0 >> 7) & 3, o = r0 & 127;
        const float* wsrc = up_w + ((size_t)layer * 128 + o) * 384 + c * 3;
        float w0 = wsrc[0], w1 = wsrc[1], w2 = wsrc[2];
        wprep[idx] = (r == 0) ? w0 : (r == 1) ? (w1 + w2) : (r == 2) ? (w0 + w1) : w2;
    } else if (idx < 442368) {
        int r0 = idx - 393216;
        int c = r0 / 384, k = (r0 / 128) % 3, o = r0 & 127;
        wprep[idx] = up_out_w[((size_t)o * 128 + c) * 3 + k];
    } else {
        int r0 = idx - 442368;
        int layer = r0 / 114688;
        int r1 = r0 - layer * 114688;
        int c = r1 / 896, k = (r1 / 128) % 7, o = r1 & 127;
        wprep[idx] = dn_w[((size_t)layer * 128 + o) * 896 + c * 7 + k];
    }
}

// ---------------------------------------------------------------------------
// prepA_k: MFMA A-operand fragment records (unchanged).
// ---------------------------------------------------------------------------
__global__ __launch_bounds__(256) void prepA_k(
    const float* __restrict__ up_w, const float* __restrict__ up_out_w,
    unsigned short* __restrict__ afrag)
{
    int idx = blockIdx.x * 256 + threadIdx.x;
    if (idx >= 221184) return;
    int rid = idx >> 6, lane = idx & 63;
    const int r15 = lane & 15, g = lane >> 4;
    unsigned short vals[8];
    if (rid < 3072) {
        int L  = rid >> 9;
        int r0 = rid & 511;
        int f = r0 & 3, ks = (r0 >> 2) & 1, cc = (r0 >> 3) & 1;
        int wo = (r0 >> 4) & 1, half = (r0 >> 5) & 1, ptap = (r0 >> 6) & 3;
        int o = wo * 64 + f * 16 + r15;
        int cb = cc * 64 + ks * 32 + g * 8;
#pragma unroll
        for (int e = 0; e < 8; e++) {
            const float* ws = up_w + (((size_t)L * 128 + o) * 128 + (cb + e)) * 3;
            float w0 = ws[0], w1 = ws[1], w2 = ws[2];
            float v = (ptap == 0) ? w0 : (ptap == 1) ? (w1 + w2)
                    : (ptap == 2) ? (w0 + w1) : w2;
            unsigned hi = bf16r(v);
            if (half == 0) vals[e] = (unsigned short)hi;
            else vals[e] = (unsigned short)bf16r(v - __uint_as_float(hi << 16));
        }
    } else {
        int r2 = rid - 3072;
        int f = r2 & 3, ks = (r2 >> 2) & 1, cc = (r2 >> 3) & 1;
        int wo = (r2 >> 4) & 1, half = (r2 >> 5) & 1, tap = r2 >> 6;
        int o = wo * 64 + f * 16 + r15;
        int cb = cc * 64 + ks * 32 + g * 8;
#pragma unroll
        for (int e = 0; e < 8; e++) {
            float v = up_out_w[((size_t)o * 128 + (cb + e)) * 3 + tap];
            unsigned hi = bf16r(v);
            if (half == 0) vals[e] = (unsigned short)hi;
            else vals[e] = (unsigned short)bf16r(v - __uint_as_float(hi << 16));
        }
    }
    unsigned pk[4];
#pragma unroll
    for (int q = 0; q < 4; q++)
        pk[q] = (unsigned)vals[2*q] | ((unsigned)vals[2*q+1] << 16);
    *(uint4*)(afrag + (size_t)rid * 512 + lane * 8) = make_uint4(pk[0], pk[1], pk[2], pk[3]);
}

// ---------------------------------------------------------------------------
// redstats_k: PARALLEL reduce of per-block partials (unchanged).
// ---------------------------------------------------------------------------
__global__ __launch_bounds__(256) void redstats_k(
    const float* __restrict__ partial, int nb, float* __restrict__ stats)
{
    const int c = threadIdx.x;
    float s0 = 0.f, s1 = 0.f, s2 = 0.f, s3 = 0.f;
    for (int i = blockIdx.x * 4; i < nb; i += gridDim.x * 4) {
        s0 += partial[(size_t)(i + 0) * 256 + c];
        s1 += partial[(size_t)(i + 1) * 256 + c];
        s2 += partial[(size_t)(i + 2) * 256 + c];
        s3 += partial[(size_t)(i + 3) * 256 + c];
    }
    float s = (s0 + s1) + (s2 + s3);
    if (s != 0.f || blockIdx.x == 0) atomicAdd(&stats[c], s);
}

// ---------------------------------------------------------------------------
// mconvU_k: UPS MFMA conv, 512 threads / 8 waves (unchanged).
// ---------------------------------------------------------------------------
template<int INMODE>
__global__ __launch_bounds__(512) void mconvU_k(
    const float* __restrict__ in, float* __restrict__ out,
    const unsigned short* __restrict__ afrag, const float* __restrict__ bias,
    const float* __restrict__ stp, const float* __restrict__ gp,
    const float* __restrict__ btp, float inv_n,
    float* __restrict__ partial, int L_in)
{
    __shared__ unsigned short Xh[66 * 64], Xl[66 * 64];
    __shared__ float scs[NC], shs[NC];
    __shared__ float sstat[256];

    const int b = blockIdx.y, tile0 = blockIdx.x * 64, tid = threadIdx.x;
    const int lane = tid & 63, wid = tid >> 6;
    const int wo = wid >> 2, par = (wid >> 1) & 1, jh = wid & 1;
    const int r15 = lane & 15, g = lane >> 4;
    const int bid = b * gridDim.x + blockIdx.x;

    if (tid < 256) sstat[tid] = 0.f;
    if (INMODE > 0) {
        for (int c = tid; c < NC; c += 512) {
            float m  = stp[c] * inv_n;
            float va = stp[NC + c] * inv_n - m * m;
            float sc = gp[c] * rsqrtf(va + 1e-5f);
            scs[c] = sc;
            shs[c] = btp[c] - m * sc;
        }
    }

    f32x4 acc[4][2];
#pragma unroll
    for (int i = 0; i < 4; i++)
#pragma unroll
        for (int j = 0; j < 2; j++) acc[i][j] = (f32x4)(0.f);

    for (int cc = 0; cc < 2; cc++) {
        __syncthreads();
        {
            int r = tid & 63;
            int l = tile0 - 1 + r;
            for (int c0 = (tid >> 6); c0 < 64; c0 += 8) {
                int c = cc * 64 + c0;
                float v = 0.f;
                if (l >= 0 && l < L_in) {
                    v = in[((size_t)b * NC + c) * L_in + l];
                    if (INMODE > 0) v = lrelu(v * scs[c] + shs[c]);
                }
                unsigned hi = bf16r(v);
                unsigned lo = bf16r(v - __uint_as_float(hi << 16));
                unsigned bo = ((unsigned)(r * 128 + c0 * 2)) ^ (((unsigned)(r & 7)) << 4);
                *(unsigned short*)((char*)Xh + bo) = (unsigned short)hi;
                *(unsigned short*)((char*)Xl + bo) = (unsigned short)lo;
            }
            if (tid < 128) {
                int r2 = 64 + (tid >> 6);
                int l2 = tile0 - 1 + r2;
                int c0 = tid & 63;
                int c = cc * 64 + c0;
                float v = 0.f;
                if (l2 >= 0 && l2 < L_in) {
                    v = in[((size_t)b * NC + c) * L_in + l2];
                    if (INMODE > 0) v = lrelu(v * scs[c] + shs[c]);
                }
                unsigned hi = bf16r(v);
                unsigned lo = bf16r(v - __uint_as_float(hi << 16));
                unsigned bo = ((unsigned)(r2 * 128 + c0 * 2)) ^ (((unsigned)(r2 & 7)) << 4);
                *(unsigned short*)((char*)Xh + bo) = (unsigned short)hi;
                *(unsigned short*)((char*)Xl + bo) = (unsigned short)lo;
            }
        }
        __syncthreads();
#pragma unroll
        for (int pt = 0; pt < 2; pt++) {
            const int ptap = par * 2 + pt;
            const int roff = (ptap == 0) ? 0 : (ptap == 3) ? 2 : 1;
#pragma unroll
            for (int combo = 0; combo < 3; combo++) {
                const int ah = (combo == 2) ? 1 : 0;
                const unsigned short* Xs = (combo == 1) ? Xl : Xh;
                bf16x8 af[8];
#pragma unroll
                for (int ks = 0; ks < 2; ks++)
#pragma unroll
                    for (int f = 0; f < 4; f++) {
                        int rec = ((((ptap * 2 + ah) * 2 + wo) * 2 + cc) * 2 + ks) * 4 + f;
                        af[ks * 4 + f] = *(const bf16x8*)(afrag + (size_t)rec * 512 + lane * 8);
                    }
#pragma unroll
                for (int ks = 0; ks < 2; ks++) {
                    bf16x8 bf_[2];
#pragma unroll
                    for (int j = 0; j < 2; j++) {
                        int row = (jh * 2 + j) * 16 + r15 + roff;
                        unsigned bo = ((unsigned)(row * 128 + ks * 64 + g * 16))
                                    ^ (((unsigned)(row & 7)) << 4);
                        bf_[j] = *(const bf16x8*)((const char*)Xs + bo);
                    }
#pragma unroll
                    for (int i = 0; i < 4; i++)
#pragma unroll
                        for (int j = 0; j < 2; j++)
                            acc[i][j] = __builtin_amdgcn_mfma_f32_16x16x32_bf16(
                                af[ks * 4 + i], bf_[j], acc[i][j], 0, 0, 0);
                }
            }
        }
    }

    const int L_out = 2 * L_in;
#pragma unroll
    for (int i = 0; i < 4; i++) {
#pragma unroll
        for (int r = 0; r < 4; r++) {
            const int o = wo * 64 + i * 16 + g * 4 + r;
            const float bv = bias[o];
            float s1 = 0.f, s2 = 0.f;
#pragma unroll
            for (int j = 0; j < 2; j++) {
                float v = acc[i][j][r] + bv;
                int lout = 2 * (tile0 + (jh * 2 + j) * 16 + r15) + par;
                out[((size_t)b * NC + o) * L_out + lout] = v;
                s1 += v; s2 += v * v;
            }
#pragma unroll
            for (int m = 1; m < 16; m <<= 1) {
                s1 += __shfl_xor(s1, m);
                s2 += __shfl_xor(s2, m);
            }
            if (r15 == 0) {
                atomicAdd(&sstat[o], s1);
                atomicAdd(&sstat[NC + o], s2);
            }
        }
    }
    __syncthreads();
    if (tid < 256) partial[(size_t)bid * 256 + tid] = sstat[tid];
}

// ---------------------------------------------------------------------------
// mconvF_k: final k3 conv as MFMA, 512 threads / 8 waves (unchanged).
// ---------------------------------------------------------------------------
__global__ __launch_bounds__(512) void mconvF_k(
    const float* __restrict__ in, float* __restrict__ out,
    const unsigned short* __restrict__ afrag, const float* __restrict__ bias,
    const float* __restrict__ stp, const float* __restrict__ gp,
    const float* __restrict__ btp, float inv_n,
    unsigned short* __restrict__ xtout)
{
    __shared__ unsigned short Xh[130 * 64], Xl[130 * 64];
    __shared__ float scs[NC], shs[NC];

    const int b = blockIdx.y, l0 = blockIdx.x * 128, tid = threadIdx.x;
    const int lane = tid & 63, wid = tid >> 6;
    const int wo = wid >> 2, wl = (wid & 3) * 32;
    const int r15 = lane & 15, g = lane >> 4;

    for (int c = tid; c < NC; c += 512) {
        float m  = stp[c] * inv_n;
        float va = stp[NC + c] * inv_n - m * m;
        float sc = gp[c] * rsqrtf(va + 1e-5f);
        scs[c] = sc;
        shs[c] = btp[c] - m * sc;
    }

    f32x4 acc[4][2];
#pragma unroll
    for (int i = 0; i < 4; i++)
#pragma unroll
        for (int j = 0; j < 2; j++) acc[i][j] = (f32x4)(0.f);

    for (int cc = 0; cc < 2; cc++) {
        __syncthreads();
        {
            int r = tid & 127;
            int l = l0 - 1 + r;
            for (int c0 = (tid >> 7); c0 < 64; c0 += 4) {
                int c = cc * 64 + c0;
                float v = 0.f;
                if (l >= 0 && l < LFULL) {
                    v = in[((size_t)b * NC + c) * LFULL + l];
                    v = lrelu(v * scs[c] + shs[c]);
                }
                unsigned hi = bf16r(v);
                unsigned lo = bf16r(v - __uint_as_float(hi << 16));
                unsigned bo = ((unsigned)(r * 128 + c0 * 2)) ^ (((unsigned)(r & 7)) << 4);
                *(unsigned short*)((char*)Xh + bo) = (unsigned short)hi;
                *(unsigned short*)((char*)Xl + bo) = (unsigned short)lo;
            }
            if (tid < 128) {
                int r2 = 128 + (tid >> 6);
                int l2 = l0 - 1 + r2;
                int c0 = tid & 63;
                int c = cc * 64 + c0;
                float v = 0.f;
                if (l2 >= 0 && l2 < LFULL) {
                    v = in[((size_t)b * NC + c) * LFULL + l2];
                    v = lrelu(v * scs[c] + shs[c]);
                }
                unsigned hi = bf16r(v);
                unsigned lo = bf16r(v - __uint_as_float(hi << 16));
                unsigned bo = ((unsigned)(r2 * 128 + c0 * 2)) ^ (((unsigned)(r2 & 7)) << 4);
                *(unsigned short*)((char*)Xh + bo) = (unsigned short)hi;
                *(unsigned short*)((char*)Xl + bo) = (unsigned short)lo;
            }
        }
        __syncthreads();
#pragma unroll
        for (int tap = 0; tap < 3; tap++) {
#pragma unroll
            for (int combo = 0; combo < 3; combo++) {
                const int ah = (combo == 2) ? 1 : 0;
                const unsigned short* Xs = (combo == 1) ? Xl : Xh;
                bf16x8 af[8];
#pragma unroll
                for (int ks = 0; ks < 2; ks++)
#pragma unroll
                    for (int f = 0; f < 4; f++) {
                        int rec = 3072 + ((((tap * 2 + ah) * 2 + wo) * 2 + cc) * 2 + ks) * 4 + f;
                        af[ks * 4 + f] = *(const bf16x8*)(afrag + (size_t)rec * 512 + lane * 8);
                    }
#pragma unroll
                for (int ks = 0; ks < 2; ks++) {
                    bf16x8 bf_[2];
#pragma unroll
                    for (int j = 0; j < 2; j++) {
                        int row = wl + j * 16 + r15 + tap;
                        unsigned bo = ((unsigned)(row * 128 + ks * 64 + g * 16))
                                    ^ (((unsigned)(row & 7)) << 4);
                        bf_[j] = *(const bf16x8*)((const char*)Xs + bo);
                    }
#pragma unroll
                    for (int i = 0; i < 4; i++)
#pragma unroll
                        for (int j = 0; j < 2; j++)
                            acc[i][j] = __builtin_amdgcn_mfma_f32_16x16x32_bf16(
                                af[ks * 4 + i], bf_[j], acc[i][j], 0, 0, 0);
                }
            }
        }
    }

#pragma unroll
    for (int i = 0; i < 4; i++) {
#pragma unroll
        for (int r = 0; r < 4; r++) {
            const int o = wo * 64 + i * 16 + g * 4 + r;
            const float bv = bias[o];
#pragma unroll
            for (int j = 0; j < 2; j++) {
                float v = acc[i][j][r] + bv;
                int l = l0 + wl + j * 16 + r15;
                out[((size_t)b * NC + o) * LFULL + l] = v;
                xtout[((size_t)b * LFULL + l) * NC + o] = (unsigned short)bf16r(v);
            }
        }
    }
}

// ---------------------------------------------------------------------------
// conv7: VALU conv (dn1/dn2), swizzled x tile, OCW oc per wave (unchanged).
// ---------------------------------------------------------------------------
template<int KW, int STRIDE, int PAD, bool UPS, int INMODE, bool OUTACT, bool STATS, int TT, bool XPOSE, int OCW>
__global__ __launch_bounds__(256) void conv7_k(
    const float* __restrict__ in, float* __restrict__ out,
    const float* __restrict__ wp, const float* __restrict__ bias,
    const float* __restrict__ stp, const float* __restrict__ gp,
    const float* __restrict__ btp, float inv_n,
    float* __restrict__ stats, unsigned short* __restrict__ xtout,
    int L_in, int L_out)
{
    constexpr int CC    = (KW == 7) ? 8 : 16;
    constexpr int PT    = 64 * TT;
    constexpr int TTO   = UPS ? 2 * TT : TT;
    constexpr int NWR   = UPS ? 4 : KW;
    constexpr int OCB   = 4 * OCW;
    constexpr int SPAN  = UPS ? (PT + 2) : ((PT - 1) * STRIDE + KW);
    constexpr int NCH   = (SPAN + 3) / 4;
    constexpr int NCH8  = (NCH + 7) & ~7;
    constexpr int XROW  = 4 * NCH8 + 4;
    constexpr int NLD   = (CC * NCH + 255) / 256;
    constexpr int XSPAN = UPS ? (TT + 2) : ((TT - 1) * STRIDE + KW);
    constexpr int STEP  = UPS ? TT : TT * STRIDE;
    constexpr int NWQ   = CC * NWR * (OCB / 4);
    static_assert((STEP & 3) == 0, "conv7 swizzle path requires STEP%4==0");
    static_assert(OCW == 4 || OCW == 8, "OCW must be 4 or 8");

    __shared__ float xs[CC][XROW];
    __shared__ float wls[CC * NWR * OCB];
    __shared__ float scs[NC], shs[NC];

    const int b = blockIdx.z, ocb = blockIdx.y, tid = threadIdx.x;
    const int t0 = blockIdx.x * PT, lane = tid & 63;
    const int wid = tid >> 6;
    const int oc0 = ocb * OCB + wid * OCW;
    const int gb = UPS ? (t0 - 1) : (t0 * STRIDE - PAD);

    if (INMODE > 0) {
        for (int c = tid; c < NC; c += 256) {
            float m  = stp[c] * inv_n;
            float va = stp[NC + c] * inv_n - m * m;
            float sc = gp[c] * rsqrtf(va + 1e-5f);
            scs[c] = sc;
            shs[c] = btp[c] - m * sc;
        }
        __syncthreads();
    }

    float acc[OCW][TTO];
#pragma unroll
    for (int i = 0; i < OCW; i++)
#pragma unroll
        for (int j = 0; j < TTO; j++) acc[i][j] = 0.f;

    float pre[NLD][4];

#define C7_STAGEW(CCBASE) do {                                              \
    for (int _u = tid; _u < NWQ; _u += 256) {                               \
        int _row = _u / (OCB / 4), _g8 = _u % (OCB / 4);                    \
        int _cl = _row / NWR, _t = _row % NWR;                              \
        ((float4*)wls)[_u] = *(const float4*)(wp +                          \
            ((size_t)((CCBASE) + _cl) * NWR + _t) * 128 + ocb * OCB + _g8 * 4); \
    }                                                                       \
} while (0)

#define C7_COMPCI(CI) do {                                                  \
    float _q[XSPAN];                                                        \
    const int _qb4 = lane * (STEP / 4);                                     \
    _Pragma("unroll")                                                       \
    for (int _u = 0; _u < XSPAN / 4; _u++) {                                \
        float4 _v = *(const float4*)&xs[CI][4 * swz4(_qb4 + _u)];           \
        _q[4*_u] = _v.x; _q[4*_u+1] = _v.y;                                 \
        _q[4*_u+2] = _v.z; _q[4*_u+3] = _v.w;                               \
    }                                                                       \
    if constexpr ((XSPAN & 3) != 0) {                                       \
        const int _pt = swz4(_qb4 + XSPAN / 4);                             \
        if constexpr ((XSPAN & 3) >= 2) {                                   \
            float2 _v = *(const float2*)&xs[CI][4 * _pt];                   \
            _q[(XSPAN & ~3)] = _v.x; _q[(XSPAN & ~3) + 1] = _v.y;           \
        }                                                                   \
        if constexpr ((XSPAN & 3) == 1)                                     \
            _q[XSPAN - 1] = xs[CI][4 * _pt];                                \
        else if constexpr ((XSPAN & 3) == 3)                                \
            _q[XSPAN - 1] = xs[CI][4 * _pt + 2];                            \
    }                                                                       \
    {                                                                       \
        _Pragma("unroll")                                                   \
        for (int _k = 0; _k < KW; _k++) {                                   \
            if constexpr (OCW == 8) {                                       \
                const float4 _w0 = *(const float4*)&wls[((CI) * NWR + _k) * OCB + wid * 8];     \
                const float4 _w1 = *(const float4*)&wls[((CI) * NWR + _k) * OCB + wid * 8 + 4]; \
                _Pragma("unroll")                                           \
                for (int _i = 0; _i < 8; _i++) {                            \
                    float _wv = f4c(_i < 4 ? _w0 : _w1, _i & 3);            \
                    _Pragma("unroll")                                       \
                    for (int _j = 0; _j < TT; _j++)                         \
                        acc[_i][_j] = fmaf(_wv, _q[_j * STRIDE + _k], acc[_i][_j]); \
                }                                                           \
            } else {                                                        \
                const float4 _w0 = *(const float4*)&wls[((CI) * NWR + _k) * OCB + wid * 4];     \
                _Pragma("unroll")                                           \
                for (int _i = 0; _i < 4; _i++) {                            \
                    float _wv = f4c(_w0, _i);                               \
                    _Pragma("unroll")                                       \
                    for (int _j = 0; _j < TT; _j++)                         \
                        acc[_i][_j] = fmaf(_wv, _q[_j * STRIDE + _k], acc[_i][_j]); \
                }                                                           \
            }                                                               \
        }                                                                   \
    }                                                                       \
} while (0)

#pragma unroll
    for (int u = 0; u < NLD; u++) {
        int idx = tid + u * 256;
        if (idx < CC * NCH) {
            int cl = idx / NCH, q = idx - cl * NCH;
            loadg4(in + ((size_t)b * NC + cl) * L_in, gb + 4 * q, L_in, pre[u]);
        }
    }
#pragma unroll
    for (int u = 0; u < NLD; u++) {
        int idx = tid + u * 256;
        if (idx < CC * NCH) {
            int cl = idx / NCH, q = idx - cl * NCH;
            int g0 = gb + 4 * q;
            float e[4];
#pragma unroll
            for (int t = 0; t < 4; t++) {
                float v = pre[u][t];
                if (INMODE > 0) {
                    int gg = g0 + t;
                    if (gg >= 0 && gg < L_in) {
                        float s = v * scs[cl] + shs[cl];
                        v = (INMODE == 2) ? lrelu(s) : s;
                    }
                }
                e[t] = v;
            }
            *(float4*)&xs[cl][4 * swz4(q)] = make_float4(e[0], e[1], e[2], e[3]);
        }
    }
    C7_STAGEW(0);
    __syncthreads();

    for (int cc = 0; cc < NC; cc += CC) {
        if (cc + CC < NC) {
#pragma unroll
            for (int u = 0; u < NLD; u++) {
                int idx = tid + u * 256;
                if (idx < CC * NCH) {
                    int cl = idx / NCH, q = idx - cl * NCH;
                    loadg4(in + ((size_t)b * NC + cc + CC + cl) * L_in,
                           gb + 4 * q, L_in, pre[u]);
                }
            }
        }
#pragma unroll
        for (int ci = 0; ci < CC; ci++) {
            C7_COMPCI(ci);
        }
        __syncthreads();
        if (cc + CC < NC) {
#pragma unroll
            for (int u = 0; u < NLD; u++) {
                int idx = tid + u * 256;
                if (idx < CC * NCH) {
                    int cl = idx / NCH, q = idx - cl * NCH;
                    int g0 = gb + 4 * q;
                    int c = cc + CC + cl;
                    float e[4];
#pragma unroll
                    for (int t = 0; t < 4; t++) {
                        float v = pre[u][t];
                        if (INMODE > 0) {
                            int gg = g0 + t;
                            if (gg >= 0 && gg < L_in) {
                                float s = v * scs[c] + shs[c];
                                v = (INMODE == 2) ? lrelu(s) : s;
                            }
                        }
                        e[t] = v;
                    }
                    *(float4*)&xs[cl][4 * swz4(q)] = make_float4(e[0], e[1], e[2], e[3]);
                }
            }
            C7_STAGEW(cc + CC);
            __syncthreads();
        }
    }
#undef C7_STAGEW
#undef C7_COMPCI

    const int po = t0 + lane * TTO;
#pragma unroll
    for (int i = 0; i < OCW; i++) {
        const int o = oc0 + i;
        const float bv = bias[o];
        float s1 = 0.f, s2 = 0.f;
        float tmpm[TTO];
#pragma unroll
        for (int j = 0; j < TTO; j++) {
            float v = acc[i][j] + bv;
            if (OUTACT) v = lrelu(v);
            tmpm[j] = v;
            if (STATS) { s1 += v; s2 += v * v; }
        }
        float* orow = out + ((size_t)b * NC + o) * L_out + po;
        if constexpr (TTO == 4)
            *(float4*)orow = make_float4(tmpm[0], tmpm[1], tmpm[2], tmpm[3]);
        else if constexpr (TTO == 2)
            *(float2*)orow = make_float2(tmpm[0], tmpm[1]);
        else
            orow[0] = tmpm[0];
        if (STATS) {
#pragma unroll
            for (int m = 1; m < 64; m <<= 1) {
                s1 += __shfl_xor(s1, m);
                s2 += __shfl_xor(s2, m);
            }
            if (lane == 0) {
                atomicAdd(&stats[o], s1);
                atomicAdd(&stats[NC + o], s2);
            }
        }
    }
}

// ---------------------------------------------------------------------------
__global__ __launch_bounds__(256) void cvtW_k(const float* __restrict__ W,
                                              unsigned short* __restrict__ Wbf)
{
    int i = blockIdx.x * 256 + threadIdx.x;
    const float4 a = *(const float4*)&W[i * 8];
    const float4 b = *(const float4*)&W[i * 8 + 4];
    unsigned pk[4];
    pk[0] = bf16r(a.x) | (bf16r(a.y) << 16);
    pk[1] = bf16r(a.z) | (bf16r(a.w) << 16);
    pk[2] = bf16r(b.x) | (bf16r(b.y) << 16);
    pk[3] = bf16r(b.z) | (bf16r(b.w) << 16);
    *(uint4*)&Wbf[i * 8] = make_uint4(pk[0], pk[1], pk[2], pk[3]);
}

// ---------------------------------------------------------------------------
// salM2: MFMA bf16 GEMM over (128h x 128l) tiles.
//  PHASE 0: __expf sum + 4-replica bf16-key histogram + per-tile max key.
//  PHASE 1: tile skipped entirely if tilemax < threshold; else compact cands.
// ---------------------------------------------------------------------------
template<int PHASE>
__global__ __launch_bounds__(256) void salM2_k(
    const unsigned short* __restrict__ xT, const unsigned short* __restrict__ Wbf,
    const float* __restrict__ bias, float* __restrict__ gsum,
    unsigned* __restrict__ ghist, const unsigned* __restrict__ thrv,
    unsigned* __restrict__ candcnt, unsigned* __restrict__ candI,
    unsigned* __restrict__ tilemax)
{
    __shared__ unsigned short Als[128 * 128];
    __shared__ unsigned short Bls[128 * 128];
    __shared__ float redsm[4];
    __shared__ unsigned redmx[4];

    const int b  = blockIdx.z;
    const int h0 = blockIdx.y * 128;
    const int l0 = blockIdx.x * 128;
    const int tid = threadIdx.x;
    const int lane = tid & 63;
    const int wid = tid >> 6;
    const int wh = (wid >> 1) * 64;
    const int wl = (wid & 1) * 64;
    const int tileid = (b * 8 + blockIdx.y) * 64 + blockIdx.x;

    unsigned thr = 0;
    if (PHASE == 1) {
        thr = thrv[b * 2];
        if (tilemax[tileid] < thr) return;   // exact: no element >= thr
    }

    {
        const uint4* gA = (const uint4*)(Wbf + (size_t)h0 * NC);
        const uint4* gB = (const uint4*)(xT + ((size_t)b * LFULL + l0) * NC);
        char* cA = (char*)Als; char* cB = (char*)Bls;
        for (int i = tid; i < 2048; i += 256) {
            int row = i >> 4, q = i & 15;
            unsigned sw = (unsigned)(row * 256 + q * 16) ^ (((unsigned)(row & 7)) << 4);
            *(uint4*)(cA + sw) = gA[i];
        }
        for (int i = tid; i < 2048; i += 256) {
            int row = i >> 4, q = i & 15;
            unsigned sw = (unsigned)(row * 256 + q * 16) ^ (((unsigned)(row & 7)) << 4);
            *(uint4*)(cB + sw) = gB[i];
        }
    }
    __syncthreads();

    f32x4 acc[4][4];
#pragma unroll
    for (int i = 0; i < 4; i++)
#pragma unroll
        for (int j = 0; j < 4; j++) acc[i][j] = (f32x4)(0.f);

    const int r15 = lane & 15, g = lane >> 4;
#pragma unroll
    for (int ks = 0; ks < 4; ks++) {
        bf16x8 af[4], bfv[4];
#pragma unroll
        for (int f = 0; f < 4; f++) {
            int rowA = wh + f * 16 + r15;
            unsigned offA = (unsigned)(rowA * 256 + ks * 64 + g * 16)
                          ^ (((unsigned)(rowA & 7)) << 4);
            af[f] = *(const bf16x8*)((const char*)Als + offA);
            int rowB = wl + f * 16 + r15;
            unsigned offB = (unsigned)(rowB * 256 + ks * 64 + g * 16)
                          ^ (((unsigned)(rowB & 7)) << 4);
            bfv[f] = *(const bf16x8*)((const char*)Bls + offB);
        }
#pragma unroll
        for (int i = 0; i < 4; i++)
#pragma unroll
            for (int j = 0; j < 4; j++)
                acc[i][j] = __builtin_amdgcn_mfma_f32_16x16x32_bf16(
                    af[i], bfv[j], acc[i][j], 0, 0, 0);
    }

    if constexpr (PHASE == 0) {
        __syncthreads();                        // fragment reads done
        unsigned* hA = (unsigned*)Als;          // replicas 0,1 (8192 u32)
        unsigned* hB = (unsigned*)Bls;          // replicas 2,3 (8192 u32)
        for (int i = tid; i < 8192; i += 256) { hA[i] = 0; hB[i] = 0; }
        __syncthreads();
        unsigned* myh = ((tid & 2) ? hB : hA) + (tid & 1) * 4096;
        float expsum = 0.f;
        unsigned maxk = 0;
#pragma unroll
        for (int i = 0; i < 4; i++) {
#pragma unroll
            for (int r = 0; r < 4; r++) {
                const int h = h0 + wh + i * 16 + g * 4 + r;
                const float bv = bias[h];
#pragma unroll
                for (int j = 0; j < 4; j++) {
                    float v = acc[i][j][r] + bv;
                    expsum += __expf(v);
                    unsigned k16 = monoKey16(bf16r(v));
                    maxk = max(maxk, k16);
                    atomicAdd(&myh[k16 >> 4], 1u);
                }
            }
        }
#pragma unroll
        for (int m = 1; m < 64; m <<= 1) {
            expsum += __shfl_xor(expsum, m);
            maxk = max(maxk, (unsigned)__shfl_xor((int)maxk, m));
        }
        if (lane == 0) { redsm[wid] = expsum; redmx[wid] = maxk; }
        __syncthreads();
        for (int i = tid; i < 4096; i += 256) {
            unsigned s = hA[i] + hA[4096 + i] + hB[i] + hB[4096 + i];
            if (s) atomicAdd(&ghist[b * 4096 + i], s);
        }
        if (tid == 0) {
            atomicAdd(&gsum[b], redsm[0] + redsm[1] + redsm[2] + redsm[3]);
            unsigned mx = max(max(redmx[0], redmx[1]), max(redmx[2], redmx[3]));
            tilemax[tileid] = mx;
        }
    } else {
#pragma unroll
        for (int i = 0; i < 4; i++) {
#pragma unroll
            for (int r = 0; r < 4; r++) {
                const int h = h0 + wh + i * 16 + g * 4 + r;
                const float bv = bias[h];
#pragma unroll
                for (int j = 0; j < 4; j++) {
                    float v = acc[i][j][r] + bv;
                    bool pr = monoKey16(bf16r(v)) >= thr;
                    unsigned long long m = __ballot(pr);
                    if (m) {
                        int leader = __ffsll((unsigned long long)m) - 1;
                        int cnt = __popcll(m);
                        unsigned basepos = 0;
                        if (lane == leader)
                            basepos = atomicAdd(&candcnt[b], (unsigned)cnt);
                        basepos = __shfl(basepos, leader);
                        if (pr) {
                            int rr = __popcll(m & ((1ull << lane) - 1ull));
                            unsigned pos = basepos + (unsigned)rr;
                            if (pos < CAP) {
                                int l = l0 + wl + j * 16 + r15;
                                candI[b * CAP + pos] = (unsigned)((h << 13) | l);
                            }
                        }
                    }
                }
            }
        }
    }
}

// ---------------------------------------------------------------------------
__global__ __launch_bounds__(256) void scan2_k(
    const unsigned* __restrict__ ghist, unsigned* __restrict__ thrv)
{
    const int b = blockIdx.x, tid = threadIdx.x;
    __shared__ unsigned part[256];
    unsigned s = 0;
#pragma unroll
    for (int i = 0; i < 16; i++) s += ghist[b * 4096 + tid * 16 + i];
    part[tid] = s;
    __syncthreads();
    if (tid == 0) {
        unsigned cum = 0; int ch;
        for (ch = 255; ch >= 0; ch--) {
            if (cum + part[ch] >= KSEL) break;
            cum += part[ch];
        }
        int bin = 0;
        if (ch >= 0) {
            for (bin = ch * 16 + 15; bin > ch * 16; bin--) {
                unsigned c = ghist[b * 4096 + bin];
                if (cum + c >= KSEL) break;
                cum += c;
            }
        }
        int bcol = bin > 0 ? bin - 1 : 0;
        thrv[b * 2] = (unsigned)bcol << 4;
    }
}

__global__ __launch_bounds__(128) void recompute_k(
    const unsigned* __restrict__ candcnt, const unsigned* __restrict__ candI,
    const float* __restrict__ xu, const float* __restrict__ W,
    const float* __restrict__ bias, unsigned* __restrict__ candK)
{
    const int b = blockIdx.y;
    const unsigned cnt = min(candcnt[b], (unsigned)CAP);
    const int t = threadIdx.x;
    __shared__ float wsum[2];
    for (unsigned k = blockIdx.x; k < cnt; k += 1024) {
        unsigned e = candI[b * CAP + k];
        int h = e >> 13, l = e & 8191;
        float prod = W[h * NC + t] * xu[(b * NC + t) * LFULL + l];
#pragma unroll
        for (int m = 1; m < 64; m <<= 1) prod += __shfl_xor(prod, m);
        if ((t & 63) == 0) wsum[t >> 6] = prod;
        __syncthreads();
        if (t == 0) candK[b * CAP + k] = monoKey(wsum[0] + wsum[1] + bias[h]);
        __syncthreads();
    }
}

__global__ __launch_bounds__(256) void select2_k(
    const unsigned* __restrict__ candcnt, const unsigned* __restrict__ candK,
    const unsigned* __restrict__ candI,
    uint2* __restrict__ selected, unsigned* __restrict__ selcnt)
{
    const int b = blockIdx.x, tid = threadIdx.x;
    __shared__ unsigned h1[4096];
    __shared__ unsigned l2k[2048], l2i[2048];
    __shared__ unsigned part[256];
    __shared__ unsigned sh[8];

    const unsigned Nc = min(candcnt[b], (unsigned)CAP);
    const unsigned* kk = candK + b * CAP;
    const unsigned* ii = candI + b * CAP;
    uint2* sel = selected + b * KSEL;

    for (int i = tid; i < 4096; i += 256) h1[i] = 0;
    if (tid < 8) sh[tid] = 0;
    __syncthreads();
    for (unsigned i = tid; i < Nc; i += 256) atomicAdd(&h1[kk[i] >> 20], 1u);
    __syncthreads();
    {
        unsigned s = 0;
#pragma unroll
        for (int i = 0; i < 16; i++) s += h1[tid * 16 + i];
        part[tid] = s;
        __syncthreads();
        if (tid == 0) {
            unsigned cum = 0; int ch;
            for (ch = 255; ch >= 0; ch--) { if (cum + part[ch] >= KSEL) break; cum += part[ch]; }
            int bin = 0;
            if (ch >= 0)
                for (bin = ch * 16 + 15; bin > ch * 16; bin--) {
                    unsigned c = h1[bin];
                    if (cum + c >= KSEL) break;
                    cum += c;
                }
            sh[2] = (unsigned)bin; sh[3] = KSEL - cum;
        }
    }
    __syncthreads();
    const unsigned b1 = sh[2], need1 = sh[3];
    for (int i = tid; i < 1024; i += 256) h1[i] = 0;
    __syncthreads();
    for (unsigned i = tid; i < Nc; i += 256) {
        unsigned k = kk[i], bin = k >> 20;
        if (bin > b1) {
            unsigned p = atomicAdd(&sh[0], 1u);
            if (p < KSEL) sel[p] = make_uint2(k, ii[i]);
        } else if (bin == b1) {
            atomicAdd(&h1[(k >> 10) & 1023], 1u);
        }
    }
    __syncthreads();
    {
        unsigned s = 0;
#pragma unroll
        for (int i = 0; i < 4; i++) s += h1[tid * 4 + i];
        part[tid] = s;
        __syncthreads();
        if (tid == 0) {
            unsigned cum = 0; int ch;
            for (ch = 255; ch >= 0; ch--) { if (cum + part[ch] >= need1) break; cum += part[ch]; }
            int bin = 0;
            if (ch >= 0)
                for (bin = ch * 4 + 3; bin > ch * 4; bin--) {
                    unsigned c = h1[bin];
                    if (cum + c >= need1) break;
                    cum += c;
                }
            sh[4] = (unsigned)bin; sh[5] = need1 - cum;
        }
    }
    __syncthreads();
    const unsigned b2 = sh[4], need2 = sh[5];
    for (int i = tid; i < 1024; i += 256) h1[i] = 0;
    __syncthreads();
    for (unsigned i = tid; i < Nc; i += 256) {
        unsigned k = kk[i];
        if ((k >> 20) != b1) continue;
        unsigned mb = (k >> 10) & 1023;
        if (mb > b2) {
            unsigned p = atomicAdd(&sh[0], 1u);
            if (p < KSEL) sel[p] = make_uint2(k, ii[i]);
        } else if (mb == b2) {
            unsigned j = atomicAdd(&sh[1], 1u);
            if (j < 2048) { l2k[j] = k; l2i[j] = ii[i]; atomicAdd(&h1[k & 1023], 1u); }
        }
    }
    __syncthreads();
    const unsigned m2 = min(sh[1], 2048u);
    {
        unsigned s = 0;
#pragma unroll
        for (int i = 0; i < 4; i++) s += h1[tid * 4 + i];
        part[tid] = s;
        __syncthreads();
        if (tid == 0) {
            unsigned cum = 0; int ch;
            for (ch = 255; ch >= 0; ch--) { if (cum + part[ch] >= need2) break; cum += part[ch]; }
            int bin = 0;
            if (ch >= 0)
                for (bin = ch * 4 + 3; bin > ch * 4; bin--) {
                    unsigned c = h1[bin];
                    if (cum + c >= need2) break;
                    cum += c;
                }
            sh[6] = (unsigned)bin; sh[7] = need2 - cum;
        }
    }
    __syncthreads();
    const unsigned b3 = sh[6], need3 = sh[7];
    if (tid == 0) sh[1] = 0;
    __syncthreads();
    for (unsigned i = tid; i < m2; i += 256) {
        unsigned k = l2k[i], lb = k & 1023;
        if (lb > b3) {
            unsigned p = atomicAdd(&sh[0], 1u);
            if (p < KSEL) sel[p] = make_uint2(k, l2i[i]);
        } else if (lb == b3) {
            unsigned t = atomicAdd(&sh[1], 1u);
            if (t < need3) {
                unsigned p = atomicAdd(&sh[0], 1u);
                if (p < KSEL) sel[p] = make_uint2(k, l2i[i]);
            }
        }
    }
    __syncthreads();
    if (tid == 0) selcnt[b] = min(sh[0], (unsigned)KSEL);
}

// ---------------------------------------------------------------------------
// scatter2_k: compute g = sig * softmax_val per selection; store only g.
// ---------------------------------------------------------------------------
__global__ __launch_bounds__(128) void scatter2_k(
    const uint2* __restrict__ selected, const unsigned* __restrict__ selcnt,
    const float* __restrict__ gsum, const float* __restrict__ xu,
    const float* __restrict__ upw, const float* __restrict__ upb,
    float* __restrict__ gval)
{
    const int b = blockIdx.y, kidx = blockIdx.x;
    if (kidx >= (int)selcnt[b]) return;
    const uint2 s = selected[b * KSEL + kidx];
    const float salv = keyToF(s.x);
    const unsigned idx = s.y;
    const int h = idx >> 13, l = idx & 8191;
    const int t = threadIdx.x;

    float prod = upw[h * NC + t] * xu[(b * NC + t) * LFULL + l];
#pragma unroll
    for (int m = 1; m < 64; m <<= 1) prod += __shfl_xor(prod, m);
    __shared__ float wsum[2];
    if ((t & 63) == 0) wsum[t >> 6] = prod;
    __syncthreads();
    if (t == 0) {
        const float sig = wsum[0] + wsum[1] + upb[h];
        gval[b * KSEL + kidx] = sig * (__expf(salv) / gsum[b]);
    }
}

// ---------------------------------------------------------------------------
// dnconst_k / fillpre_k / corrdn_k / actstats_k (unchanged from R18).
// ---------------------------------------------------------------------------
__global__ __launch_bounds__(128) void dnconst_k(
    const float* __restrict__ dn_w, const float* __restrict__ dnb,
    const float* __restrict__ dn_b0, float* __restrict__ cst)
{
    const int o = threadIdx.x;
    float accA = 0.f, accE = 0.f;
    for (int c = 0; c < NC; c++) {
        const float bv = dnb[c];
        const float* wp = dn_w + ((size_t)o * NC + c) * 7;
#pragma unroll
        for (int k = 0; k < 7; k++) {
            float w = wp[k];
            accA += w * bv;
            if (k >= 3) accE += w * bv;
        }
    }
    cst[o]       = accA + dn_b0[o];
    cst[NC + o]  = accE + dn_b0[o];
}

__global__ __launch_bounds__(256) void fillpre_k(
    const float* __restrict__ cst, float* __restrict__ pre)
{
    const int row = blockIdx.x;
    const int o = row & 127;
    const float vI = cst[o], v0 = cst[NC + o];
    float4* p = (float4*)(pre + (size_t)row * 2048);
#pragma unroll
    for (int u = 0; u < 2; u++) {
        int q = threadIdx.x + u * 256;
        float4 v = make_float4(vI, vI, vI, vI);
        if (q == 0) v.x = v0;
        p[q] = v;
    }
}

__global__ __launch_bounds__(128) void corrdn_k(
    const uint2* __restrict__ selected, const unsigned* __restrict__ selcnt,
    const float* __restrict__ gval, const float* __restrict__ dww,
    const float* __restrict__ w0p, float* __restrict__ pre)
{
    const int b = blockIdx.y, kidx = blockIdx.x;
    if (kidx >= (int)selcnt[b]) return;
    const unsigned idx = selected[b * KSEL + kidx].y;
    const int h = idx >> 13, l = idx & 8191;
    const float g = gval[b * KSEL + kidx];
    const int o = threadIdx.x;

    __shared__ float dlt[NC];
    dlt[o] = dww[o * NH + h] * g;
    __syncthreads();

    const int tlo = (l <= 3) ? 0 : ((l - 3 + 3) >> 2);
    const int thi = min(2047, (l + 3) >> 2);
    for (int t = tlo; t <= thi; t++) {
        const int k = l - 4 * t + 3;
        float corr = 0.f;
#pragma unroll 4
        for (int c = 0; c < NC; c++)
            corr += w0p[(size_t)c * 896 + k * 128 + o] * dlt[c];
        atomicAdd(&pre[((size_t)b * NC + o) * 2048 + t], corr);
    }
}

__global__ __launch_bounds__(256) void actstats_k(
    float* __restrict__ pre, float* __restrict__ stats)
{
    const int row = blockIdx.x;
    const int o = row & 127;
    float4* p = (float4*)(pre + (size_t)row * 2048);
    float s1 = 0.f, s2 = 0.f;
#pragma unroll
    for (int u = 0; u < 2; u++) {
        int q = threadIdx.x + u * 256;
        float4 v = p[q];
        float e[4] = {v.x, v.y, v.z, v.w};
#pragma unroll
        for (int t = 0; t < 4; t++) {
            float a = lrelu(e[t]);
            e[t] = a;
            s1 += a; s2 += a * a;
        }
        p[q] = make_float4(e[0], e[1], e[2], e[3]);
    }
#pragma unroll
    for (int m = 1; m < 64; m <<= 1) {
        s1 += __shfl_xor(s1, m);
        s2 += __shfl_xor(s2, m);
    }
    __shared__ float red[8];
    const int lane = threadIdx.x & 63, wid = threadIdx.x >> 6;
    if (lane == 0) { red[wid] = s1; red[4 + wid] = s2; }
    __syncthreads();
    if (threadIdx.x == 0) {
        atomicAdd(&stats[o],      red[0] + red[1] + red[2] + red[3]);
        atomicAdd(&stats[NC + o], red[4] + red[5] + red[6] + red[7]);
    }
}

// ---------------------------------------------------------------------------
__global__ void apply_k(const float* __restrict__ in, const float* __restrict__ stats,
                        const float* __restrict__ g, const float* __restrict__ bt,
                        float* __restrict__ out, float inv_n)
{
    int i = blockIdx.x * 256 + threadIdx.x;
    int c = (i >> 7) & 127;
    float m  = stats[c] * inv_n;
    float va = stats[NC + c] * inv_n - m * m;
    float sc = g[c] * rsqrtf(va + 1e-5f);
    out[i] = in[i] * sc + (bt[c] - m * sc);
}

// ---------------------------------------------------------------------------
extern "C" void kernel_launch(void* const* d_in, const int* in_sizes, int n_in,
                              void* d_out, int out_size, void* d_ws, size_t ws_size,
                              hipStream_t stream)
{
    const float* x        = (const float*)d_in[0];
    const float* up_w     = (const float*)d_in[1];
    const float* up_b     = (const float*)d_in[2];
    const float* up_g     = (const float*)d_in[3];
    const float* up_beta  = (const float*)d_in[4];
    const float* up_out_w = (const float*)d_in[5];
    const float* up_out_b = (const float*)d_in[6];
    const float* sb_up_w  = (const float*)d_in[7];
    const float* sb_up_b  = (const float*)d_in[8];
    const float* sal_w    = (const float*)d_in[9];
    const float* sal_b    = (const float*)d_in[10];
    const float* sb_dn_w  = (const float*)d_in[11];
    const float* sb_dn_b  = (const float*)d_in[12];
    const float* dn_w     = (const float*)d_in[13];
    const float* dn_b     = (const float*)d_in[14];
    const float* dn_g     = (const float*)d_in[15];
    const float* dn_beta  = (const float*)d_in[16];

    char* ws = (char*)d_ws;
    float*          stats    = (float*)(ws + 0);
    float*          gsum     = (float*)(ws + 16384);
    unsigned*       thrv     = (unsigned*)(ws + 16416);
    unsigned*       candcnt  = (unsigned*)(ws + 16480);
    unsigned*       selcnt   = (unsigned*)(ws + 16512);
    uint2*          selected = (uint2*)(ws + 16640);
    unsigned*       ghist    = (unsigned*)(ws + 49408);
    unsigned*       candK    = (unsigned*)(ws + 180480);
    unsigned*       candI    = (unsigned*)(ws + 1229056);
    unsigned short* Wbf      = (unsigned short*)(ws + 2277632);
    float*          wprep    = (float*)(ws + 2539776);
    float*          B0       = (float*)(ws + 5685504);
    float*          B1       = (float*)(ws + 39239936);
    unsigned short* xT       = (unsigned short*)(ws + 72794368);
    unsigned short* Afrag    = (unsigned short*)(ws + 117440512);
    float*          partial  = (float*)(ws + 121634816);
    float*          gval     = (float*)(ws + 122159104);  // 8x512 f32
    float*          cst      = (float*)(ws + 122175488);  // 256 f32
    unsigned*       tilemax  = (unsigned*)(ws + 122176512); // 8x512 u32

    hipMemsetAsync(d_ws, 0, 16544, stream);
    hipMemsetAsync(ws + 49408, 0, 131072, stream);

    cvtW_k<<<64,256,0,stream>>>(sal_w, Wbf);
    prep_k<<<3072,256,0,stream>>>(up_w, up_out_w, dn_w, wprep);
    prepA_k<<<864,256,0,stream>>>(up_w, up_out_w, Afrag);

    // ---- ConvUpsample (MFMA, 8-wave blocks): 128 -> 8192 frames ----
    mconvU_k<0><<<dim3(2,NB),512,0,stream>>>(
        x, B0, Afrag, up_b, nullptr, nullptr, nullptr, 0.f, partial, 128);
    redstats_k<<<16,256,0,stream>>>(partial, 2*NB, stats);
    mconvU_k<2><<<dim3(4,NB),512,0,stream>>>(
        B0, B1, Afrag + 1*262144, up_b + NC,
        stats, up_g, up_beta, 1.f/(float)(NB*256), partial, 256);
    redstats_k<<<16,256,0,stream>>>(partial, 4*NB, stats + 256);
    mconvU_k<2><<<dim3(8,NB),512,0,stream>>>(
        B1, B0, Afrag + 2*262144, up_b + 2*NC,
        stats + 256, up_g + NC, up_beta + NC, 1.f/(float)(NB*512), partial, 512);
    redstats_k<<<16,256,0,stream>>>(partial, 8*NB, stats + 2*256);
    mconvU_k<2><<<dim3(16,NB),512,0,stream>>>(
        B0, B1, Afrag + 3*262144, up_b + 3*NC,
        stats + 2*256, up_g + 2*NC, up_beta + 2*NC, 1.f/(float)(NB*1024), partial, 1024);
    redstats_k<<<16,256,0,stream>>>(partial, 16*NB, stats + 3*256);
    mconvU_k<2><<<dim3(32,NB),512,0,stream>>>(
        B1, B0, Afrag + 4*262144, up_b + 4*NC,
        stats + 3*256, up_g + 3*NC, up_beta + 3*NC, 1.f/(float)(NB*2048), partial, 2048);
    redstats_k<<<16,256,0,stream>>>(partial, 32*NB, stats + 4*256);
    mconvU_k<2><<<dim3(64,NB),512,0,stream>>>(
        B0, B1, Afrag + 5*262144, up_b + 5*NC,
        stats + 4*256, up_g + 4*NC, up_beta + 4*NC, 1.f/(float)(NB*4096), partial, 4096);
    redstats_k<<<16,256,0,stream>>>(partial, 64*NB, stats + 5*256);
    // final k3 conv (MFMA): B1 -> B0 (f32 x_up) + xT (bf16 transposed)
    mconvF_k<<<dim3(64,NB),512,0,stream>>>(
        B1, B0, Afrag, up_out_b,
        stats + 5*256, up_g + 5*NC, up_beta + 5*NC, 1.f/(float)(NB*LFULL), xT);

    // ---- SparseBottleneck ----
    salM2_k<0><<<dim3(64,8,NB),256,0,stream>>>(xT, Wbf, sal_b, gsum, ghist,
                                               nullptr, nullptr, nullptr, tilemax);
    scan2_k<<<NB,256,0,stream>>>(ghist, thrv);
    salM2_k<1><<<dim3(64,8,NB),256,0,stream>>>(xT, Wbf, sal_b, nullptr, nullptr,
                                               thrv, candcnt, candI, tilemax);
    recompute_k<<<dim3(1024,NB),128,0,stream>>>(candcnt, candI, B0, sal_w, sal_b, candK);
    select2_k<<<NB,256,0,stream>>>(candcnt, candK, candI, selected, selcnt);
    scatter2_k<<<dim3(KSEL,NB),128,0,stream>>>(selected, selcnt, gsum, B0,
                                               sb_up_w, sb_up_b, gval);

    // ---- dn0 (algebraic): const-fill + sparse corrections + act/stats ----
    dnconst_k<<<1,128,0,stream>>>(dn_w, sb_dn_b, dn_b, cst);
    fillpre_k<<<NB*NC,256,0,stream>>>(cst, B1);
    corrdn_k<<<dim3(KSEL,NB),128,0,stream>>>(selected, selcnt, gval, sb_dn_w,
                                             wprep + 442368, B1);
    actstats_k<<<NB*NC,256,0,stream>>>(B1, stats + 6*256);

    // ---- dn1/dn2 (VALU, swizzled, OCW4): 2048 -> 128 ----
    conv7_k<7,4,3,false,1,true,true,1,false,4><<<dim3(8,8,NB),256,0,stream>>>(
        B1, B0, wprep + 442368 + 114688, dn_b + NC,
        stats + 6*256, dn_g, dn_beta, 1.f/(float)(NB*2048),
        stats + 7*256, nullptr, 2048, 512);
    conv7_k<7,4,3,false,1,true,true,1,false,4><<<dim3(2,8,NB),256,0,stream>>>(
        B0, B1, wprep + 442368 + 2*114688, dn_b + 2*NC,
        stats + 7*256, dn_g + NC, dn_beta + NC, 1.f/(float)(NB*512),
        stats + 8*256, nullptr, 512, 128);

    apply_k<<<(out_size + 255)/256,256,0,stream>>>(
        B1, stats + 8*256, dn_g + 2*NC, dn_beta + 2*NC, (float*)d_out,
        1.f/(float)(NB*128));
}